// Round 5
// baseline (1248.455 us; speedup 1.0000x reference)
//
#include <hip/hip_runtime.h>
#include <hip/hip_bf16.h>
#include <cstdint>
#include <cstddef>

#define N_NODES 10000
#define T_STEPS 6
#define F_IN    64
#define HID     64
#define HEADS   4
#define E_EDGES 160000
#define EP      (E_EDGES + N_NODES)   /* 170000 edges incl self-loops */
#define TN      (T_STEPS * N_NODES)   /* 60000 */
#define TEP     (T_STEPS * EP)        /* 1020000 */

typedef __hip_bfloat16 bf16;

__device__ __forceinline__ float b2f(bf16 v) { return __bfloat162float(v); }

/* ---------------- CSR build ---------------- */

__global__ void k_init(int* counts, int* fill) {
    int i = blockIdx.x * blockDim.x + threadIdx.x;
    if (i < N_NODES) { counts[i] = 0; fill[i] = 0; }
}

__global__ void k_count(const int* ei, int* counts) {
    int e = blockIdx.x * blockDim.x + threadIdx.x;
    if (e >= EP) return;
    int dst = (e < E_EDGES) ? ei[E_EDGES + e] : (e - E_EDGES);
    atomicAdd(&counts[dst], 1);
}

__global__ void k_scan(const int* counts, int* rowstart) {
    __shared__ int part[1024];
    int tid = threadIdx.x;
    const int chunk = (N_NODES + 1023) / 1024;  // 10
    int base = tid * chunk;
    int s = 0;
    for (int i = 0; i < chunk; i++) { int idx = base + i; if (idx < N_NODES) s += counts[idx]; }
    part[tid] = s;
    __syncthreads();
    for (int off = 1; off < 1024; off <<= 1) {
        int v = (tid >= off) ? part[tid - off] : 0;
        __syncthreads();
        part[tid] += v;
        __syncthreads();
    }
    int run = (tid == 0) ? 0 : part[tid - 1];
    for (int i = 0; i < chunk; i++) {
        int idx = base + i;
        if (idx < N_NODES) { rowstart[idx] = run; run += counts[idx]; }
    }
    if (tid == 0) rowstart[N_NODES] = EP;
}

__global__ void k_scatter(const int* ei, const int* rowstart, int* fill,
                          int* csr_src) {
    int e = blockIdx.x * blockDim.x + threadIdx.x;
    if (e >= EP) return;
    int src = (e < E_EDGES) ? ei[e] : (e - E_EDGES);
    int dst = (e < E_EDGES) ? ei[E_EDGES + e] : (e - E_EDGES);
    int pos = rowstart[dst] + atomicAdd(&fill[dst], 1);
    csr_src[pos] = src;
}

/* ---------------- prep: P-matrices for layer-1 logits + W1 bf16 copy ----- */

/* P1s[h][k] = sum_c W1[k, h*64+c] * a_src1[h,c]  (same for dst). One block. */
__global__ __launch_bounds__(256) void k_prep1(const float* __restrict__ W1,
                                               const float* __restrict__ a_src1,
                                               const float* __restrict__ a_dst1,
                                               float* __restrict__ P1s,
                                               float* __restrict__ P1d,
                                               bf16* __restrict__ W1b) {
    int tid = threadIdx.x;
    int h = tid >> 6, k = tid & 63;
    float ps = 0.f, pd = 0.f;
    for (int c = 0; c < 64; c++) {
        float wv = W1[k * 256 + h * 64 + c];
        ps += wv * a_src1[h * 64 + c];
        pd += wv * a_dst1[h * 64 + c];
    }
    P1s[h * 64 + k] = ps;
    P1d[h * 64 + k] = pd;
    for (int i = tid; i < 64 * 256; i += 256) W1b[i] = __float2bfloat16(W1[i]);
}

/* ---------------- GAT layer 0 ---------------- */

/* X[60000,64] @ W0[64,64] -> XW0 (bf16), + fused per-row attention logits
   (fp32 accumulator). 256 threads = 4 rows x 64 cols; one wave per row. */
__global__ __launch_bounds__(256) void k_gemm0(const float* __restrict__ x,
                                               const float* __restrict__ W0,
                                               const float* __restrict__ a_src0,
                                               const float* __restrict__ a_dst0,
                                               bf16* __restrict__ XW0b,
                                               float* __restrict__ ALS0,
                                               float* __restrict__ ALD0) {
    __shared__ float wl[64 * 64];
    __shared__ float xl[4][64];
    int tid = threadIdx.x;
    for (int i = tid; i < 4096; i += 256) wl[i] = W0[i];
    int r = tid >> 6, c = tid & 63;
    int row = blockIdx.x * 4 + r;            // row = t*N + n
    int t = row / N_NODES, n = row % N_NODES;
    xl[r][c] = x[(size_t)(n * T_STEPS + t) * F_IN + c];  // x is [N,T,F]
    __syncthreads();
    float acc = 0.f;
#pragma unroll
    for (int k = 0; k < 64; k++) acc += xl[r][k] * wl[k * 64 + c];
    XW0b[(size_t)row * 64 + c] = __float2bfloat16(acc);
    int h = c >> 4, cc = c & 15;
    float ps = acc * a_src0[h * 16 + cc];
    float pd = acc * a_dst0[h * 16 + cc];
#pragma unroll
    for (int o = 8; o; o >>= 1) { ps += __shfl_xor(ps, o, 64); pd += __shfl_xor(pd, o, 64); }
    if (cc == 0) { ALS0[row * 4 + h] = ps; ALD0[row * 4 + h] = pd; }
}

/* wave-parallel segment softmax + fused per-edge alpha write (CSR order).
   One wave per (t,n); lanes parallel over edges. */
__global__ __launch_bounds__(256) void k_softmax_wave(const int* __restrict__ rowstart,
                                                      const int* __restrict__ csr_src,
                                                      const float* __restrict__ ALS,
                                                      const float* __restrict__ ALD,
                                                      float* __restrict__ M,
                                                      float* __restrict__ SI,
                                                      float* __restrict__ ALPHA) {
    int wid = blockIdx.x * 4 + (threadIdx.x >> 6);
    int lane = threadIdx.x & 63;
    if (wid >= TN) return;
    int t = wid / N_NODES, n = wid % N_NODES;
    int rs = rowstart[n], re = rowstart[n + 1];
    int tb = t * N_NODES;
    size_t ab = (size_t)t * EP;
    float4 ad = *(const float4*)(ALD + (size_t)wid * 4);
    float m0 = -1e30f, m1 = -1e30f, m2 = -1e30f, m3 = -1e30f;
    for (int e = rs + lane; e < re; e += 64) {
        int src = csr_src[e];
        float4 as = *(const float4*)(ALS + (size_t)(tb + src) * 4);
        float l0 = as.x + ad.x; l0 = l0 > 0.f ? l0 : 0.2f * l0; m0 = fmaxf(m0, l0);
        float l1 = as.y + ad.y; l1 = l1 > 0.f ? l1 : 0.2f * l1; m1 = fmaxf(m1, l1);
        float l2 = as.z + ad.z; l2 = l2 > 0.f ? l2 : 0.2f * l2; m2 = fmaxf(m2, l2);
        float l3 = as.w + ad.w; l3 = l3 > 0.f ? l3 : 0.2f * l3; m3 = fmaxf(m3, l3);
    }
#pragma unroll
    for (int o = 32; o; o >>= 1) {
        m0 = fmaxf(m0, __shfl_xor(m0, o, 64));
        m1 = fmaxf(m1, __shfl_xor(m1, o, 64));
        m2 = fmaxf(m2, __shfl_xor(m2, o, 64));
        m3 = fmaxf(m3, __shfl_xor(m3, o, 64));
    }
    float s0 = 0.f, s1 = 0.f, s2 = 0.f, s3 = 0.f;
    for (int e = rs + lane; e < re; e += 64) {
        int src = csr_src[e];
        float4 as = *(const float4*)(ALS + (size_t)(tb + src) * 4);
        float l0 = as.x + ad.x; l0 = l0 > 0.f ? l0 : 0.2f * l0; s0 += __expf(l0 - m0);
        float l1 = as.y + ad.y; l1 = l1 > 0.f ? l1 : 0.2f * l1; s1 += __expf(l1 - m1);
        float l2 = as.z + ad.z; l2 = l2 > 0.f ? l2 : 0.2f * l2; s2 += __expf(l2 - m2);
        float l3 = as.w + ad.w; l3 = l3 > 0.f ? l3 : 0.2f * l3; s3 += __expf(l3 - m3);
    }
#pragma unroll
    for (int o = 32; o; o >>= 1) {
        s0 += __shfl_xor(s0, o, 64);
        s1 += __shfl_xor(s1, o, 64);
        s2 += __shfl_xor(s2, o, 64);
        s3 += __shfl_xor(s3, o, 64);
    }
    float i0 = 1.f / (s0 + 1e-16f), i1 = 1.f / (s1 + 1e-16f);
    float i2 = 1.f / (s2 + 1e-16f), i3 = 1.f / (s3 + 1e-16f);
    if (lane == 0) {
        float4 m4; m4.x = m0; m4.y = m1; m4.z = m2; m4.w = m3;
        float4 si; si.x = i0; si.y = i1; si.z = i2; si.w = i3;
        *(float4*)(M + (size_t)wid * 4) = m4;
        *(float4*)(SI + (size_t)wid * 4) = si;
    }
    /* third pass: write alpha for this segment's edges (coalesced float4) */
    for (int e = rs + lane; e < re; e += 64) {
        int src = csr_src[e];
        float4 as = *(const float4*)(ALS + (size_t)(tb + src) * 4);
        float l0 = as.x + ad.x; l0 = l0 > 0.f ? l0 : 0.2f * l0;
        float l1 = as.y + ad.y; l1 = l1 > 0.f ? l1 : 0.2f * l1;
        float l2 = as.z + ad.z; l2 = l2 > 0.f ? l2 : 0.2f * l2;
        float l3 = as.w + ad.w; l3 = l3 > 0.f ? l3 : 0.2f * l3;
        float4 o4;
        o4.x = __expf(l0 - m0) * i0;
        o4.y = __expf(l1 - m1) * i1;
        o4.z = __expf(l2 - m2) * i2;
        o4.w = __expf(l3 - m3) * i3;
        *(float4*)(ALPHA + (ab + e) * 4) = o4;
    }
}

/* one wave per (t,dst): alpha-weighted accumulate of XW0 rows, +bias, ELU */
__global__ __launch_bounds__(256) void k_accum0(const int* __restrict__ rowstart,
                                                const int* __restrict__ csr_src,
                                                const bf16* __restrict__ XW0b,
                                                const float* __restrict__ ALPHA0,
                                                const float* __restrict__ b0,
                                                bf16* __restrict__ H0b) {
    int wid = blockIdx.x * 4 + (threadIdx.x >> 6);
    int lane = threadIdx.x & 63;
    if (wid >= TN) return;
    int t = wid / N_NODES, n = wid % N_NODES;
    int h = lane >> 4;
    int rs = rowstart[n], re = rowstart[n + 1];
    int tb = t * N_NODES;
    size_t ab = (size_t)t * EP;
    float acc = 0.f;
    for (int e = rs; e < re; e++) {
        int src = csr_src[e];
        float a = ALPHA0[(ab + e) * 4 + h];
        acc += b2f(XW0b[(size_t)(tb + src) * 64 + lane]) * a;
    }
    float v = acc + b0[lane];
    v = v > 0.f ? v : (__expf(v) - 1.f);
    H0b[(size_t)wid * 64 + lane] = __float2bfloat16(v);
}

/* ---------------- GAT layer 1 (aggregation-first) ---------------- */

/* per-row logits via P: ALS1[row,h] = sum_k h0[row,k] * P1s[h,k]. One wave/row. */
__global__ __launch_bounds__(256) void k_logits1(const bf16* __restrict__ H0b,
                                                 const float* __restrict__ P1s,
                                                 const float* __restrict__ P1d,
                                                 float* __restrict__ ALS1,
                                                 float* __restrict__ ALD1) {
    int wid = blockIdx.x * 4 + (threadIdx.x >> 6);
    int lane = threadIdx.x & 63;
    if (wid >= TN) return;
    float xv = b2f(H0b[(size_t)wid * 64 + lane]);
    float s0 = xv * P1s[lane],       s1 = xv * P1s[64 + lane];
    float s2 = xv * P1s[128 + lane], s3 = xv * P1s[192 + lane];
    float d0 = xv * P1d[lane],       d1 = xv * P1d[64 + lane];
    float d2 = xv * P1d[128 + lane], d3 = xv * P1d[192 + lane];
#pragma unroll
    for (int o = 32; o; o >>= 1) {
        s0 += __shfl_xor(s0, o, 64); s1 += __shfl_xor(s1, o, 64);
        s2 += __shfl_xor(s2, o, 64); s3 += __shfl_xor(s3, o, 64);
        d0 += __shfl_xor(d0, o, 64); d1 += __shfl_xor(d1, o, 64);
        d2 += __shfl_xor(d2, o, 64); d3 += __shfl_xor(d3, o, 64);
    }
    if (lane == 0) {
        float4 s4; s4.x = s0; s4.y = s1; s4.z = s2; s4.w = s3;
        float4 d4; d4.x = d0; d4.y = d1; d4.z = d2; d4.w = d3;
        *(float4*)(ALS1 + (size_t)wid * 4) = s4;
        *(float4*)(ALD1 + (size_t)wid * 4) = d4;
    }
}

/* alpha output for t = T-1 only, in ORIGINAL edge order -> fp32 out */
__global__ void k_alpha_out(const int* __restrict__ ei,
                            const float* __restrict__ ALS1, const float* __restrict__ ALD1,
                            const float* __restrict__ M1, const float* __restrict__ SI1,
                            float* __restrict__ out_alpha) {
    int e = blockIdx.x * blockDim.x + threadIdx.x;
    if (e >= EP) return;
    int src = (e < E_EDGES) ? ei[e] : (e - E_EDGES);
    int dst = (e < E_EDGES) ? ei[E_EDGES + e] : (e - E_EDGES);
    const int tb = (T_STEPS - 1) * N_NODES;
    int sb = (tb + src) * 4, db = (tb + dst) * 4;
    float4 as = *(const float4*)(ALS1 + sb);
    float4 ad = *(const float4*)(ALD1 + db);
    float4 mm = *(const float4*)(M1 + db);
    float4 ss = *(const float4*)(SI1 + db);
    float l0 = as.x + ad.x; l0 = l0 > 0.f ? l0 : 0.2f * l0;
    float l1 = as.y + ad.y; l1 = l1 > 0.f ? l1 : 0.2f * l1;
    float l2 = as.z + ad.z; l2 = l2 > 0.f ? l2 : 0.2f * l2;
    float l3 = as.w + ad.w; l3 = l3 > 0.f ? l3 : 0.2f * l3;
    float4 o4;
    o4.x = __expf(l0 - mm.x) * ss.x;
    o4.y = __expf(l1 - mm.y) * ss.y;
    o4.z = __expf(l2 - mm.z) * ss.z;
    o4.w = __expf(l3 - mm.w) * ss.w;
    *(float4*)(out_alpha + (size_t)e * 4) = o4;
}

/* one wave per (t,dst): aggregate 64-dim H0 rows with per-head alpha.
   AGG[wid, h*64+c] = sum_e alpha[e,h] * h0[src_e, c]. */
__global__ __launch_bounds__(256) void k_accum1_agg(const int* __restrict__ rowstart,
                                                    const int* __restrict__ csr_src,
                                                    const bf16* __restrict__ H0b,
                                                    const float* __restrict__ ALPHA1,
                                                    bf16* __restrict__ AGG1b) {
    int wid = blockIdx.x * 4 + (threadIdx.x >> 6);
    int lane = threadIdx.x & 63;
    if (wid >= TN) return;
    int t = wid / N_NODES, n = wid % N_NODES;
    int rs = rowstart[n], re = rowstart[n + 1];
    int tb = t * N_NODES;
    size_t ab = (size_t)t * EP;
    float a0 = 0.f, a1 = 0.f, a2 = 0.f, a3 = 0.f;
    for (int e = rs; e < re; e++) {
        int src = csr_src[e];
        float4 al = *(const float4*)(ALPHA1 + (ab + e) * 4);
        float xv = b2f(H0b[(size_t)(tb + src) * 64 + lane]);
        a0 += al.x * xv; a1 += al.y * xv; a2 += al.z * xv; a3 += al.w * xv;
    }
    size_t ob = (size_t)wid * 256;
    AGG1b[ob +   0 + lane] = __float2bfloat16(a0);
    AGG1b[ob +  64 + lane] = __float2bfloat16(a1);
    AGG1b[ob + 128 + lane] = __float2bfloat16(a2);
    AGG1b[ob + 192 + lane] = __float2bfloat16(a3);
}

/* epilogue GEMM: HS[row,c] = LN(ELU(0.25*sum_h AGG[row,h,:]@W1[:,h*64+c] + b1)).
   W1 bf16 in LDS; AGG row distributed in lanes, broadcast via shfl.
   Block = 4 waves x 4 rows each = 16 rows. */
__global__ __launch_bounds__(256) void k_post1(const bf16* __restrict__ AGG1b,
                                               const bf16* __restrict__ W1b,
                                               const float* __restrict__ b1,
                                               const float* __restrict__ ln_g,
                                               const float* __restrict__ ln_b,
                                               float* __restrict__ HS) {
    __shared__ uint4 wl4[2048];          /* 64x256 bf16 = 32 KB */
    int tid = threadIdx.x;
    const uint4* w1v = (const uint4*)W1b;
    for (int i = tid; i < 2048; i += 256) wl4[i] = w1v[i];
    __syncthreads();
    const bf16* wl = (const bf16*)wl4;
    int w = tid >> 6, lane = tid & 63;
    float b1c = b1[lane], gg = ln_g[lane], bb = ln_b[lane];
    int rbase = blockIdx.x * 16;
    for (int rr = 0; rr < 4; rr++) {
        int row = rbase + rr * 4 + w;
        /* lane holds AGG elements 4*lane .. 4*lane+3 of this row */
        const ushort4* ar = (const ushort4*)(AGG1b + (size_t)row * 256);
        ushort4 u = ar[lane];
        float fx = __uint_as_float((unsigned)u.x << 16);
        float fy = __uint_as_float((unsigned)u.y << 16);
        float fz = __uint_as_float((unsigned)u.z << 16);
        float fw = __uint_as_float((unsigned)u.w << 16);
        float acc = 0.f;
#pragma unroll
        for (int h = 0; h < 4; h++) {
            int wb = h * 64 + lane;
#pragma unroll
            for (int kq = 0; kq < 16; kq++) {
                int sl = h * 16 + kq;   /* source lane holding AGG[h][4kq..4kq+3] */
                acc += __shfl(fx, sl, 64) * b2f(wl[(kq * 4 + 0) * 256 + wb]);
                acc += __shfl(fy, sl, 64) * b2f(wl[(kq * 4 + 1) * 256 + wb]);
                acc += __shfl(fz, sl, 64) * b2f(wl[(kq * 4 + 2) * 256 + wb]);
                acc += __shfl(fw, sl, 64) * b2f(wl[(kq * 4 + 3) * 256 + wb]);
            }
        }
        float v = acc * 0.25f + b1c;
        v = v > 0.f ? v : (__expf(v) - 1.f);
        float s = v;
#pragma unroll
        for (int o = 32; o; o >>= 1) s += __shfl_xor(s, o, 64);
        float mu = s * (1.f / 64.f);
        float d = v - mu;
        float q = d * d;
#pragma unroll
        for (int o = 32; o; o >>= 1) q += __shfl_xor(q, o, 64);
        float var = q * (1.f / 64.f);
        HS[(size_t)row * 64 + lane] = d * rsqrtf(var + 1e-5f) * gg + bb;
    }
}

/* ---------------- GRU ---------------- */

__global__ void k_zero(float* p, int nelem) {
    int i = blockIdx.x * blockDim.x + threadIdx.x;
    if (i < nelem) p[i] = 0.f;
}

/* non-recurrent half: GI[row,j] = b_ih[j] + dot(W_ih[j], HS[row]) for all rows.
   192 threads (one per gate-row), 48 rows/block; weights in VGPRs. */
__global__ __launch_bounds__(192) void k_gi(const float* __restrict__ HS,
                                            const float* __restrict__ W_ih,
                                            const float* __restrict__ b_ih,
                                            bf16* __restrict__ GIb) {
    __shared__ float xs[64];
    int j = threadIdx.x;
    float wi[64];
    const float4* wi4 = (const float4*)(W_ih) + (size_t)j * 16;
#pragma unroll
    for (int q = 0; q < 16; q++) {
        float4 a = wi4[q];
        wi[q * 4 + 0] = a.x; wi[q * 4 + 1] = a.y; wi[q * 4 + 2] = a.z; wi[q * 4 + 3] = a.w;
    }
    float bi = b_ih[j];
    for (int rr = 0; rr < 48; rr++) {
        int row = blockIdx.x * 48 + rr;
        if (j < 64) xs[j] = HS[(size_t)row * 64 + j];
        __syncthreads();
        float gi = bi;
#pragma unroll
        for (int k = 0; k < 64; k++) gi += wi[k] * xs[k];
        GIb[(size_t)row * 192 + j] = __float2bfloat16(gi);
        __syncthreads();
    }
}

/* recurrent half: gh = b_hh + W_hh@h, combine with precomputed GI. 40 rows/block. */
__global__ __launch_bounds__(192) void k_gru_step(int t,
                                                  const bf16* __restrict__ GIb,
                                                  const float* __restrict__ W_hh,
                                                  const float* __restrict__ b_hh,
                                                  const float* __restrict__ Hprev,
                                                  float* __restrict__ Hnew) {
    __shared__ float hsv[64], gis[192], ghs[192];
    int j = threadIdx.x;
    float wh[64];
    const float4* wh4 = (const float4*)(W_hh) + (size_t)j * 16;
#pragma unroll
    for (int q = 0; q < 16; q++) {
        float4 b = wh4[q];
        wh[q * 4 + 0] = b.x; wh[q * 4 + 1] = b.y; wh[q * 4 + 2] = b.z; wh[q * 4 + 3] = b.w;
    }
    float bh = b_hh[j];
    for (int rr = 0; rr < 40; rr++) {
        int n = blockIdx.x * 40 + rr;
        if (j < 64) hsv[j] = Hprev[(size_t)n * 64 + j];
        __syncthreads();
        float gh = bh;
#pragma unroll
        for (int k = 0; k < 64; k++) gh += wh[k] * hsv[k];
        gis[j] = b2f(GIb[((size_t)t * N_NODES + n) * 192 + j]);
        ghs[j] = gh;
        __syncthreads();
        if (j < 64) {
            float r = 1.f / (1.f + __expf(-(gis[j] + ghs[j])));
            float z = 1.f / (1.f + __expf(-(gis[64 + j] + ghs[64 + j])));
            float g = tanhf(gis[128 + j] + r * ghs[128 + j]);
            Hnew[(size_t)n * 64 + j] = (1.f - z) * g + z * hsv[j];
        }
        __syncthreads();
    }
}

/* ---------------- output writers (fp32) ---------------- */

__global__ void k_out_ei(const int* __restrict__ ei, float* __restrict__ out) {
    int i = blockIdx.x * blockDim.x + threadIdx.x;
    if (i >= 2 * EP) return;
    int v;
    if (i < EP) {
        v = (i < E_EDGES) ? ei[i] : (i - E_EDGES);                 // src row
    } else {
        int jj = i - EP;
        v = (jj < E_EDGES) ? ei[E_EDGES + jj] : (jj - E_EDGES);    // dst row
    }
    out[i] = (float)v;
}

/* ---------------- launch ---------------- */

extern "C" void kernel_launch(void* const* d_in, const int* in_sizes, int n_in,
                              void* d_out, int out_size, void* d_ws, size_t ws_size,
                              hipStream_t stream) {
    const float* x      = (const float*)d_in[0];
    const int*   ei     = (const int*)d_in[1];
    const float* W0     = (const float*)d_in[2];
    const float* a_src0 = (const float*)d_in[3];
    const float* a_dst0 = (const float*)d_in[4];
    const float* b0     = (const float*)d_in[5];
    const float* W1     = (const float*)d_in[6];
    const float* a_src1 = (const float*)d_in[7];
    const float* a_dst1 = (const float*)d_in[8];
    const float* b1     = (const float*)d_in[9];
    const float* ln_g   = (const float*)d_in[10];
    const float* ln_b   = (const float*)d_in[11];
    const float* W_ih   = (const float*)d_in[12];
    const float* W_hh   = (const float*)d_in[13];
    const float* b_ih   = (const float*)d_in[14];
    const float* b_hh   = (const float*)d_in[15];
    float* out = (float*)d_out;

    char* w = (char*)d_ws;
    size_t off = 0;
    auto take = [&](size_t bytes) -> void* {
        void* p = w + off;
        off = (off + bytes + 255) & ~(size_t)255;
        return p;
    };
    int*   counts  = (int*)take(N_NODES * 4);
    int*   fill    = (int*)take(N_NODES * 4);
    int*   rowst   = (int*)take((N_NODES + 1) * 4);
    int*   csr_src = (int*)take((size_t)EP * 4);
    bf16*  XW0b    = (bf16*)take((size_t)TN * 64 * 2);
    float* ALS0    = (float*)take((size_t)TN * 4 * 4);
    float* ALD0    = (float*)take((size_t)TN * 4 * 4);
    float* M0      = (float*)take((size_t)TN * 4 * 4);
    float* SI0     = (float*)take((size_t)TN * 4 * 4);
    float* ALPHA0  = (float*)take((size_t)TEP * 4 * 4);
    bf16*  H0b     = (bf16*)take((size_t)TN * 64 * 2);
    float* P1s     = (float*)take(256 * 4);
    float* P1d     = (float*)take(256 * 4);
    bf16*  W1b     = (bf16*)take(64 * 256 * 2);
    float* ALS1    = (float*)take((size_t)TN * 4 * 4);
    float* ALD1    = (float*)take((size_t)TN * 4 * 4);
    float* M1      = (float*)take((size_t)TN * 4 * 4);
    float* SI1     = (float*)take((size_t)TN * 4 * 4);
    float* ALPHA1  = (float*)take((size_t)TEP * 4 * 4);
    bf16*  AGG1b   = (bf16*)take((size_t)TN * 256 * 2);
    float* HS      = (float*)take((size_t)TN * 64 * 4);
    bf16*  GIb     = (bf16*)take((size_t)TN * 192 * 2);
    float* HA      = (float*)take((size_t)N_NODES * 64 * 4);
    float* HB      = (float*)take((size_t)N_NODES * 64 * 4);
    (void)ws_size; (void)in_sizes; (void)n_in; (void)out_size;

    const int B = 256;
    /* CSR build + prep (independent) */
    k_init<<<(N_NODES + B - 1) / B, B, 0, stream>>>(counts, fill);
    k_count<<<(EP + B - 1) / B, B, 0, stream>>>(ei, counts);
    k_scan<<<1, 1024, 0, stream>>>(counts, rowst);
    k_scatter<<<(EP + B - 1) / B, B, 0, stream>>>(ei, rowst, fill, csr_src);
    k_prep1<<<1, B, 0, stream>>>(W1, a_src1, a_dst1, P1s, P1d, W1b);

    /* GAT layer 0 (all t batched) */
    k_gemm0<<<TN / 4, B, 0, stream>>>(x, W0, a_src0, a_dst0, XW0b, ALS0, ALD0);
    k_softmax_wave<<<TN / 4, B, 0, stream>>>(rowst, csr_src, ALS0, ALD0, M0, SI0, ALPHA0);
    k_accum0<<<TN / 4, B, 0, stream>>>(rowst, csr_src, XW0b, ALPHA0, b0, H0b);

    /* GAT layer 1: logits via P, softmax+alpha, aggregate-then-GEMM */
    k_logits1<<<TN / 4, B, 0, stream>>>(H0b, P1s, P1d, ALS1, ALD1);
    k_softmax_wave<<<TN / 4, B, 0, stream>>>(rowst, csr_src, ALS1, ALD1, M1, SI1, ALPHA1);
    k_alpha_out<<<(EP + B - 1) / B, B, 0, stream>>>(ei, ALS1, ALD1, M1, SI1,
                                                    out + (size_t)N_NODES * HID);
    k_accum1_agg<<<TN / 4, B, 0, stream>>>(rowst, csr_src, H0b, ALPHA1, AGG1b);
    k_post1<<<TN / 16, B, 0, stream>>>(AGG1b, W1b, b1, ln_g, ln_b, HS);

    /* GRU: non-recurrent half batched over all t, then 6 sequential steps */
    k_gi<<<TN / 48, 192, 0, stream>>>(HS, W_ih, b_ih, GIb);
    k_zero<<<(N_NODES * 64 + B - 1) / B, B, 0, stream>>>(HA, N_NODES * 64);
    float* hbuf[2] = { HA, HB };
    for (int t = 0; t < T_STEPS; t++) {
        float* prev = hbuf[t & 1];
        float* next = (t == T_STEPS - 1) ? out : hbuf[1 - (t & 1)];
        k_gru_step<<<N_NODES / 40, 192, 0, stream>>>(t, GIb, W_hh, b_hh, prev, next);
    }

    /* outputs (fp32): [hT (640000)] [alpha_last (680000)] [edge_index (340000)] */
    k_out_ei<<<(2 * EP + B - 1) / B, B, 0, stream>>>(ei, out + (size_t)N_NODES * HID + (size_t)EP * HEADS);
}

// Round 6
// 762.231 us; speedup vs baseline: 1.6379x; 1.6379x over previous
//
#include <hip/hip_runtime.h>
#include <hip/hip_bf16.h>
#include <cstdint>
#include <cstddef>

#define N_NODES 10000
#define T_STEPS 6
#define F_IN    64
#define HID     64
#define HEADS   4
#define E_EDGES 160000
#define EP      (E_EDGES + N_NODES)   /* 170000 edges incl self-loops */
#define TN      (T_STEPS * N_NODES)   /* 60000 */
#define TEP     (T_STEPS * EP)        /* 1020000 */

typedef __hip_bfloat16 bf16;

__device__ __forceinline__ float b2f(bf16 v) { return __bfloat162float(v); }

/* ---------------- CSR build ---------------- */

__global__ void k_init(int* counts, int* fill) {
    int i = blockIdx.x * blockDim.x + threadIdx.x;
    if (i < N_NODES) { counts[i] = 0; fill[i] = 0; }
}

__global__ void k_count(const int* ei, int* counts) {
    int e = blockIdx.x * blockDim.x + threadIdx.x;
    if (e >= EP) return;
    int dst = (e < E_EDGES) ? ei[E_EDGES + e] : (e - E_EDGES);
    atomicAdd(&counts[dst], 1);
}

__global__ void k_scan(const int* counts, int* rowstart) {
    __shared__ int part[1024];
    int tid = threadIdx.x;
    const int chunk = (N_NODES + 1023) / 1024;  // 10
    int base = tid * chunk;
    int s = 0;
    for (int i = 0; i < chunk; i++) { int idx = base + i; if (idx < N_NODES) s += counts[idx]; }
    part[tid] = s;
    __syncthreads();
    for (int off = 1; off < 1024; off <<= 1) {
        int v = (tid >= off) ? part[tid - off] : 0;
        __syncthreads();
        part[tid] += v;
        __syncthreads();
    }
    int run = (tid == 0) ? 0 : part[tid - 1];
    for (int i = 0; i < chunk; i++) {
        int idx = base + i;
        if (idx < N_NODES) { rowstart[idx] = run; run += counts[idx]; }
    }
    if (tid == 0) rowstart[N_NODES] = EP;
}

__global__ void k_scatter(const int* ei, const int* rowstart, int* fill,
                          int* csr_src) {
    int e = blockIdx.x * blockDim.x + threadIdx.x;
    if (e >= EP) return;
    int src = (e < E_EDGES) ? ei[e] : (e - E_EDGES);
    int dst = (e < E_EDGES) ? ei[E_EDGES + e] : (e - E_EDGES);
    int pos = rowstart[dst] + atomicAdd(&fill[dst], 1);
    csr_src[pos] = src;
}

/* ---------------- prep: P-matrices for layer-1 logits ---------------- */

/* P1s[h][k] = sum_c W1[k, h*64+c] * a_src1[h,c]  (same for dst). One block. */
__global__ __launch_bounds__(256) void k_prep1(const float* __restrict__ W1,
                                               const float* __restrict__ a_src1,
                                               const float* __restrict__ a_dst1,
                                               float* __restrict__ P1s,
                                               float* __restrict__ P1d) {
    int tid = threadIdx.x;
    int h = tid >> 6, k = tid & 63;
    float ps = 0.f, pd = 0.f;
    for (int c = 0; c < 64; c++) {
        float wv = W1[k * 256 + h * 64 + c];
        ps += wv * a_src1[h * 64 + c];
        pd += wv * a_dst1[h * 64 + c];
    }
    P1s[h * 64 + k] = ps;
    P1d[h * 64 + k] = pd;
}

/* ---------------- GAT layer 0 ---------------- */

/* X[60000,64] @ W0[64,64] -> XW0 (bf16), + fused per-row attention logits
   (fp32 accumulator). 256 threads = 4 rows x 64 cols; one wave per row. */
__global__ __launch_bounds__(256) void k_gemm0(const float* __restrict__ x,
                                               const float* __restrict__ W0,
                                               const float* __restrict__ a_src0,
                                               const float* __restrict__ a_dst0,
                                               bf16* __restrict__ XW0b,
                                               float* __restrict__ ALS0,
                                               float* __restrict__ ALD0) {
    __shared__ float wl[64 * 64];
    __shared__ float xl[4][64];
    int tid = threadIdx.x;
    for (int i = tid; i < 4096; i += 256) wl[i] = W0[i];
    int r = tid >> 6, c = tid & 63;
    int row = blockIdx.x * 4 + r;            // row = t*N + n
    int t = row / N_NODES, n = row % N_NODES;
    xl[r][c] = x[(size_t)(n * T_STEPS + t) * F_IN + c];  // x is [N,T,F]
    __syncthreads();
    float acc = 0.f;
#pragma unroll
    for (int k = 0; k < 64; k++) acc += xl[r][k] * wl[k * 64 + c];
    XW0b[(size_t)row * 64 + c] = __float2bfloat16(acc);
    int h = c >> 4, cc = c & 15;
    float ps = acc * a_src0[h * 16 + cc];
    float pd = acc * a_dst0[h * 16 + cc];
#pragma unroll
    for (int o = 8; o; o >>= 1) { ps += __shfl_xor(ps, o, 64); pd += __shfl_xor(pd, o, 64); }
    if (cc == 0) { ALS0[row * 4 + h] = ps; ALD0[row * 4 + h] = pd; }
}

/* wave-parallel segment softmax + fused per-edge alpha write (CSR order).
   One wave per (t,n); lanes parallel over edges. */
__global__ __launch_bounds__(256) void k_softmax_wave(const int* __restrict__ rowstart,
                                                      const int* __restrict__ csr_src,
                                                      const float* __restrict__ ALS,
                                                      const float* __restrict__ ALD,
                                                      float* __restrict__ M,
                                                      float* __restrict__ SI,
                                                      float* __restrict__ ALPHA) {
    int wid = blockIdx.x * 4 + (threadIdx.x >> 6);
    int lane = threadIdx.x & 63;
    if (wid >= TN) return;
    int t = wid / N_NODES, n = wid % N_NODES;
    int rs = rowstart[n], re = rowstart[n + 1];
    int tb = t * N_NODES;
    size_t ab = (size_t)t * EP;
    float4 ad = *(const float4*)(ALD + (size_t)wid * 4);
    float m0 = -1e30f, m1 = -1e30f, m2 = -1e30f, m3 = -1e30f;
    for (int e = rs + lane; e < re; e += 64) {
        int src = csr_src[e];
        float4 as = *(const float4*)(ALS + (size_t)(tb + src) * 4);
        float l0 = as.x + ad.x; l0 = l0 > 0.f ? l0 : 0.2f * l0; m0 = fmaxf(m0, l0);
        float l1 = as.y + ad.y; l1 = l1 > 0.f ? l1 : 0.2f * l1; m1 = fmaxf(m1, l1);
        float l2 = as.z + ad.z; l2 = l2 > 0.f ? l2 : 0.2f * l2; m2 = fmaxf(m2, l2);
        float l3 = as.w + ad.w; l3 = l3 > 0.f ? l3 : 0.2f * l3; m3 = fmaxf(m3, l3);
    }
#pragma unroll
    for (int o = 32; o; o >>= 1) {
        m0 = fmaxf(m0, __shfl_xor(m0, o, 64));
        m1 = fmaxf(m1, __shfl_xor(m1, o, 64));
        m2 = fmaxf(m2, __shfl_xor(m2, o, 64));
        m3 = fmaxf(m3, __shfl_xor(m3, o, 64));
    }
    float s0 = 0.f, s1 = 0.f, s2 = 0.f, s3 = 0.f;
    for (int e = rs + lane; e < re; e += 64) {
        int src = csr_src[e];
        float4 as = *(const float4*)(ALS + (size_t)(tb + src) * 4);
        float l0 = as.x + ad.x; l0 = l0 > 0.f ? l0 : 0.2f * l0; s0 += __expf(l0 - m0);
        float l1 = as.y + ad.y; l1 = l1 > 0.f ? l1 : 0.2f * l1; s1 += __expf(l1 - m1);
        float l2 = as.z + ad.z; l2 = l2 > 0.f ? l2 : 0.2f * l2; s2 += __expf(l2 - m2);
        float l3 = as.w + ad.w; l3 = l3 > 0.f ? l3 : 0.2f * l3; s3 += __expf(l3 - m3);
    }
#pragma unroll
    for (int o = 32; o; o >>= 1) {
        s0 += __shfl_xor(s0, o, 64);
        s1 += __shfl_xor(s1, o, 64);
        s2 += __shfl_xor(s2, o, 64);
        s3 += __shfl_xor(s3, o, 64);
    }
    float i0 = 1.f / (s0 + 1e-16f), i1 = 1.f / (s1 + 1e-16f);
    float i2 = 1.f / (s2 + 1e-16f), i3 = 1.f / (s3 + 1e-16f);
    if (lane == 0) {
        float4 m4; m4.x = m0; m4.y = m1; m4.z = m2; m4.w = m3;
        float4 si; si.x = i0; si.y = i1; si.z = i2; si.w = i3;
        *(float4*)(M + (size_t)wid * 4) = m4;
        *(float4*)(SI + (size_t)wid * 4) = si;
    }
    /* third pass: write alpha for this segment's edges (coalesced float4) */
    for (int e = rs + lane; e < re; e += 64) {
        int src = csr_src[e];
        float4 as = *(const float4*)(ALS + (size_t)(tb + src) * 4);
        float l0 = as.x + ad.x; l0 = l0 > 0.f ? l0 : 0.2f * l0;
        float l1 = as.y + ad.y; l1 = l1 > 0.f ? l1 : 0.2f * l1;
        float l2 = as.z + ad.z; l2 = l2 > 0.f ? l2 : 0.2f * l2;
        float l3 = as.w + ad.w; l3 = l3 > 0.f ? l3 : 0.2f * l3;
        float4 o4;
        o4.x = __expf(l0 - m0) * i0;
        o4.y = __expf(l1 - m1) * i1;
        o4.z = __expf(l2 - m2) * i2;
        o4.w = __expf(l3 - m3) * i3;
        *(float4*)(ALPHA + (ab + e) * 4) = o4;
    }
}

/* one wave per (t,dst): alpha-weighted accumulate of XW0 rows, +bias, ELU */
__global__ __launch_bounds__(256) void k_accum0(const int* __restrict__ rowstart,
                                                const int* __restrict__ csr_src,
                                                const bf16* __restrict__ XW0b,
                                                const float* __restrict__ ALPHA0,
                                                const float* __restrict__ b0,
                                                bf16* __restrict__ H0b) {
    int wid = blockIdx.x * 4 + (threadIdx.x >> 6);
    int lane = threadIdx.x & 63;
    if (wid >= TN) return;
    int t = wid / N_NODES, n = wid % N_NODES;
    int h = lane >> 4;
    int rs = rowstart[n], re = rowstart[n + 1];
    int tb = t * N_NODES;
    size_t ab = (size_t)t * EP;
    float acc = 0.f;
    for (int e = rs; e < re; e++) {
        int src = csr_src[e];
        float a = ALPHA0[(ab + e) * 4 + h];
        acc += b2f(XW0b[(size_t)(tb + src) * 64 + lane]) * a;
    }
    float v = acc + b0[lane];
    v = v > 0.f ? v : (__expf(v) - 1.f);
    H0b[(size_t)wid * 64 + lane] = __float2bfloat16(v);
}

/* ---------------- GAT layer 1 (aggregation-first) ---------------- */

/* per-row logits via P: ALS1[row,h] = sum_k h0[row,k] * P1s[h,k]. One wave/row. */
__global__ __launch_bounds__(256) void k_logits1(const bf16* __restrict__ H0b,
                                                 const float* __restrict__ P1s,
                                                 const float* __restrict__ P1d,
                                                 float* __restrict__ ALS1,
                                                 float* __restrict__ ALD1) {
    int wid = blockIdx.x * 4 + (threadIdx.x >> 6);
    int lane = threadIdx.x & 63;
    if (wid >= TN) return;
    float xv = b2f(H0b[(size_t)wid * 64 + lane]);
    float s0 = xv * P1s[lane],       s1 = xv * P1s[64 + lane];
    float s2 = xv * P1s[128 + lane], s3 = xv * P1s[192 + lane];
    float d0 = xv * P1d[lane],       d1 = xv * P1d[64 + lane];
    float d2 = xv * P1d[128 + lane], d3 = xv * P1d[192 + lane];
#pragma unroll
    for (int o = 32; o; o >>= 1) {
        s0 += __shfl_xor(s0, o, 64); s1 += __shfl_xor(s1, o, 64);
        s2 += __shfl_xor(s2, o, 64); s3 += __shfl_xor(s3, o, 64);
        d0 += __shfl_xor(d0, o, 64); d1 += __shfl_xor(d1, o, 64);
        d2 += __shfl_xor(d2, o, 64); d3 += __shfl_xor(d3, o, 64);
    }
    if (lane == 0) {
        float4 s4; s4.x = s0; s4.y = s1; s4.z = s2; s4.w = s3;
        float4 d4; d4.x = d0; d4.y = d1; d4.z = d2; d4.w = d3;
        *(float4*)(ALS1 + (size_t)wid * 4) = s4;
        *(float4*)(ALD1 + (size_t)wid * 4) = d4;
    }
}

/* alpha output for t = T-1 only, in ORIGINAL edge order -> fp32 out */
__global__ void k_alpha_out(const int* __restrict__ ei,
                            const float* __restrict__ ALS1, const float* __restrict__ ALD1,
                            const float* __restrict__ M1, const float* __restrict__ SI1,
                            float* __restrict__ out_alpha) {
    int e = blockIdx.x * blockDim.x + threadIdx.x;
    if (e >= EP) return;
    int src = (e < E_EDGES) ? ei[e] : (e - E_EDGES);
    int dst = (e < E_EDGES) ? ei[E_EDGES + e] : (e - E_EDGES);
    const int tb = (T_STEPS - 1) * N_NODES;
    int sb = (tb + src) * 4, db = (tb + dst) * 4;
    float4 as = *(const float4*)(ALS1 + sb);
    float4 ad = *(const float4*)(ALD1 + db);
    float4 mm = *(const float4*)(M1 + db);
    float4 ss = *(const float4*)(SI1 + db);
    float l0 = as.x + ad.x; l0 = l0 > 0.f ? l0 : 0.2f * l0;
    float l1 = as.y + ad.y; l1 = l1 > 0.f ? l1 : 0.2f * l1;
    float l2 = as.z + ad.z; l2 = l2 > 0.f ? l2 : 0.2f * l2;
    float l3 = as.w + ad.w; l3 = l3 > 0.f ? l3 : 0.2f * l3;
    float4 o4;
    o4.x = __expf(l0 - mm.x) * ss.x;
    o4.y = __expf(l1 - mm.y) * ss.y;
    o4.z = __expf(l2 - mm.z) * ss.z;
    o4.w = __expf(l3 - mm.w) * ss.w;
    *(float4*)(out_alpha + (size_t)e * 4) = o4;
}

/* one wave per (t,dst): aggregate 64-dim H0 rows with per-head alpha.
   AGG[wid, h*64+c] = sum_e alpha[e,h] * h0[src_e, c]. */
__global__ __launch_bounds__(256) void k_accum1_agg(const int* __restrict__ rowstart,
                                                    const int* __restrict__ csr_src,
                                                    const bf16* __restrict__ H0b,
                                                    const float* __restrict__ ALPHA1,
                                                    bf16* __restrict__ AGG1b) {
    int wid = blockIdx.x * 4 + (threadIdx.x >> 6);
    int lane = threadIdx.x & 63;
    if (wid >= TN) return;
    int t = wid / N_NODES, n = wid % N_NODES;
    int rs = rowstart[n], re = rowstart[n + 1];
    int tb = t * N_NODES;
    size_t ab = (size_t)t * EP;
    float a0 = 0.f, a1 = 0.f, a2 = 0.f, a3 = 0.f;
    for (int e = rs; e < re; e++) {
        int src = csr_src[e];
        float4 al = *(const float4*)(ALPHA1 + (ab + e) * 4);
        float xv = b2f(H0b[(size_t)(tb + src) * 64 + lane]);
        a0 += al.x * xv; a1 += al.y * xv; a2 += al.z * xv; a3 += al.w * xv;
    }
    size_t ob = (size_t)wid * 256;
    AGG1b[ob +   0 + lane] = __float2bfloat16(a0);
    AGG1b[ob +  64 + lane] = __float2bfloat16(a1);
    AGG1b[ob + 128 + lane] = __float2bfloat16(a2);
    AGG1b[ob + 192 + lane] = __float2bfloat16(a3);
}

/* epilogue GEMM: HS[row,c] = LN(ELU(0.25 * AGG[row,:] @ Wbig[:,c] + b1)),
   Wbig[h*64+k][c] = W1[k][h*64+c]. Thread (q=tid>>6, c=tid&63) holds 64 fp32
   weights in VGPRs (k-quarter q); AGG rows staged fp32 in LDS; wave-uniform
   float4 broadcast reads; 4-way partial reduce through LDS; fused epilogue. */
__global__ __launch_bounds__(256) void k_post1(const bf16* __restrict__ AGG1b,
                                               const float* __restrict__ W1,
                                               const float* __restrict__ b1,
                                               const float* __restrict__ ln_g,
                                               const float* __restrict__ ln_b,
                                               float* __restrict__ HS) {
    __shared__ float xs[16][256];        /* 16 KB */
    __shared__ float part[16][4][64];    /* 16 KB */
    int tid = threadIdx.x;
    int q = tid >> 6, c = tid & 63;
    /* wq[k] = Wbig[q*64+k][c] = W1[k*256 + q*64 + c] */
    float wq[64];
#pragma unroll
    for (int k = 0; k < 64; k++) wq[k] = W1[k * 256 + q * 64 + c];
    int rbase = blockIdx.x * 16;
    /* stage 16 AGG rows (bf16) -> fp32 LDS; 512 uint4 per block */
    const uint4* ag4 = (const uint4*)(AGG1b + (size_t)rbase * 256);
    for (int i = tid; i < 512; i += 256) {
        uint4 u = ag4[i];
        int r = i >> 5, base = (i & 31) * 8;
        xs[r][base + 0] = __uint_as_float(u.x << 16);
        xs[r][base + 1] = __uint_as_float(u.x & 0xffff0000u);
        xs[r][base + 2] = __uint_as_float(u.y << 16);
        xs[r][base + 3] = __uint_as_float(u.y & 0xffff0000u);
        xs[r][base + 4] = __uint_as_float(u.z << 16);
        xs[r][base + 5] = __uint_as_float(u.z & 0xffff0000u);
        xs[r][base + 6] = __uint_as_float(u.w << 16);
        xs[r][base + 7] = __uint_as_float(u.w & 0xffff0000u);
    }
    __syncthreads();
    for (int r = 0; r < 16; r++) {
        const float* xr = &xs[r][q * 64];
        float acc = 0.f;
#pragma unroll
        for (int kk = 0; kk < 16; kk++) {
            float4 xv = *(const float4*)(xr + kk * 4);
            acc += xv.x * wq[kk * 4 + 0] + xv.y * wq[kk * 4 + 1]
                 + xv.z * wq[kk * 4 + 2] + xv.w * wq[kk * 4 + 3];
        }
        part[r][q][c] = acc;
    }
    __syncthreads();
    /* epilogue: wave q handles rows q*4 .. q*4+3; lane index within wave = c */
    float b1c = b1[c], gg = ln_g[c], bb = ln_b[c];
    for (int rr = 0; rr < 4; rr++) {
        int r = q * 4 + rr;
        float v = (part[r][0][c] + part[r][1][c] + part[r][2][c] + part[r][3][c]) * 0.25f + b1c;
        v = v > 0.f ? v : (__expf(v) - 1.f);
        float s = v;
#pragma unroll
        for (int o = 32; o; o >>= 1) s += __shfl_xor(s, o, 64);
        float mu = s * (1.f / 64.f);
        float d = v - mu;
        float qd = d * d;
#pragma unroll
        for (int o = 32; o; o >>= 1) qd += __shfl_xor(qd, o, 64);
        float var = qd * (1.f / 64.f);
        HS[(size_t)(rbase + r) * 64 + c] = d * rsqrtf(var + 1e-5f) * gg + bb;
    }
}

/* ---------------- GRU ---------------- */

__global__ void k_zero(float* p, int nelem) {
    int i = blockIdx.x * blockDim.x + threadIdx.x;
    if (i < nelem) p[i] = 0.f;
}

/* non-recurrent half: GI[row,j] = b_ih[j] + dot(W_ih[j], HS[row]) for all rows.
   192 threads (one per gate-row), 48 rows/block; weights in VGPRs. */
__global__ __launch_bounds__(192) void k_gi(const float* __restrict__ HS,
                                            const float* __restrict__ W_ih,
                                            const float* __restrict__ b_ih,
                                            bf16* __restrict__ GIb) {
    __shared__ float xs[64];
    int j = threadIdx.x;
    float wi[64];
    const float4* wi4 = (const float4*)(W_ih) + (size_t)j * 16;
#pragma unroll
    for (int q = 0; q < 16; q++) {
        float4 a = wi4[q];
        wi[q * 4 + 0] = a.x; wi[q * 4 + 1] = a.y; wi[q * 4 + 2] = a.z; wi[q * 4 + 3] = a.w;
    }
    float bi = b_ih[j];
    for (int rr = 0; rr < 48; rr++) {
        int row = blockIdx.x * 48 + rr;
        if (j < 64) xs[j] = HS[(size_t)row * 64 + j];
        __syncthreads();
        float gi = bi;
#pragma unroll
        for (int k = 0; k < 64; k++) gi += wi[k] * xs[k];
        GIb[(size_t)row * 192 + j] = __float2bfloat16(gi);
        __syncthreads();
    }
}

/* recurrent half: gh = b_hh + W_hh@h, combine with precomputed GI. 40 rows/block. */
__global__ __launch_bounds__(192) void k_gru_step(int t,
                                                  const bf16* __restrict__ GIb,
                                                  const float* __restrict__ W_hh,
                                                  const float* __restrict__ b_hh,
                                                  const float* __restrict__ Hprev,
                                                  float* __restrict__ Hnew) {
    __shared__ float hsv[64], gis[192], ghs[192];
    int j = threadIdx.x;
    float wh[64];
    const float4* wh4 = (const float4*)(W_hh) + (size_t)j * 16;
#pragma unroll
    for (int q = 0; q < 16; q++) {
        float4 b = wh4[q];
        wh[q * 4 + 0] = b.x; wh[q * 4 + 1] = b.y; wh[q * 4 + 2] = b.z; wh[q * 4 + 3] = b.w;
    }
    float bh = b_hh[j];
    for (int rr = 0; rr < 40; rr++) {
        int n = blockIdx.x * 40 + rr;
        if (j < 64) hsv[j] = Hprev[(size_t)n * 64 + j];
        __syncthreads();
        float gh = bh;
#pragma unroll
        for (int k = 0; k < 64; k++) gh += wh[k] * hsv[k];
        gis[j] = b2f(GIb[((size_t)t * N_NODES + n) * 192 + j]);
        ghs[j] = gh;
        __syncthreads();
        if (j < 64) {
            float r = 1.f / (1.f + __expf(-(gis[j] + ghs[j])));
            float z = 1.f / (1.f + __expf(-(gis[64 + j] + ghs[64 + j])));
            float g = tanhf(gis[128 + j] + r * ghs[128 + j]);
            Hnew[(size_t)n * 64 + j] = (1.f - z) * g + z * hsv[j];
        }
        __syncthreads();
    }
}

/* ---------------- output writers (fp32) ---------------- */

__global__ void k_out_ei(const int* __restrict__ ei, float* __restrict__ out) {
    int i = blockIdx.x * blockDim.x + threadIdx.x;
    if (i >= 2 * EP) return;
    int v;
    if (i < EP) {
        v = (i < E_EDGES) ? ei[i] : (i - E_EDGES);                 // src row
    } else {
        int jj = i - EP;
        v = (jj < E_EDGES) ? ei[E_EDGES + jj] : (jj - E_EDGES);    // dst row
    }
    out[i] = (float)v;
}

/* ---------------- launch ---------------- */

extern "C" void kernel_launch(void* const* d_in, const int* in_sizes, int n_in,
                              void* d_out, int out_size, void* d_ws, size_t ws_size,
                              hipStream_t stream) {
    const float* x      = (const float*)d_in[0];
    const int*   ei     = (const int*)d_in[1];
    const float* W0     = (const float*)d_in[2];
    const float* a_src0 = (const float*)d_in[3];
    const float* a_dst0 = (const float*)d_in[4];
    const float* b0     = (const float*)d_in[5];
    const float* W1     = (const float*)d_in[6];
    const float* a_src1 = (const float*)d_in[7];
    const float* a_dst1 = (const float*)d_in[8];
    const float* b1     = (const float*)d_in[9];
    const float* ln_g   = (const float*)d_in[10];
    const float* ln_b   = (const float*)d_in[11];
    const float* W_ih   = (const float*)d_in[12];
    const float* W_hh   = (const float*)d_in[13];
    const float* b_ih   = (const float*)d_in[14];
    const float* b_hh   = (const float*)d_in[15];
    float* out = (float*)d_out;

    char* w = (char*)d_ws;
    size_t off = 0;
    auto take = [&](size_t bytes) -> void* {
        void* p = w + off;
        off = (off + bytes + 255) & ~(size_t)255;
        return p;
    };
    int*   counts  = (int*)take(N_NODES * 4);
    int*   fill    = (int*)take(N_NODES * 4);
    int*   rowst   = (int*)take((N_NODES + 1) * 4);
    int*   csr_src = (int*)take((size_t)EP * 4);
    bf16*  XW0b    = (bf16*)take((size_t)TN * 64 * 2);
    float* ALS0    = (float*)take((size_t)TN * 4 * 4);
    float* ALD0    = (float*)take((size_t)TN * 4 * 4);
    float* M0      = (float*)take((size_t)TN * 4 * 4);
    float* SI0     = (float*)take((size_t)TN * 4 * 4);
    float* ALPHA0  = (float*)take((size_t)TEP * 4 * 4);
    bf16*  H0b     = (bf16*)take((size_t)TN * 64 * 2);
    float* P1s     = (float*)take(256 * 4);
    float* P1d     = (float*)take(256 * 4);
    float* ALS1    = (float*)take((size_t)TN * 4 * 4);
    float* ALD1    = (float*)take((size_t)TN * 4 * 4);
    float* M1      = (float*)take((size_t)TN * 4 * 4);
    float* SI1     = (float*)take((size_t)TN * 4 * 4);
    float* ALPHA1  = (float*)take((size_t)TEP * 4 * 4);
    bf16*  AGG1b   = (bf16*)take((size_t)TN * 256 * 2);
    float* HS      = (float*)take((size_t)TN * 64 * 4);
    bf16*  GIb     = (bf16*)take((size_t)TN * 192 * 2);
    float* HA      = (float*)take((size_t)N_NODES * 64 * 4);
    float* HB      = (float*)take((size_t)N_NODES * 64 * 4);
    (void)ws_size; (void)in_sizes; (void)n_in; (void)out_size;

    const int B = 256;
    /* CSR build + prep (independent) */
    k_init<<<(N_NODES + B - 1) / B, B, 0, stream>>>(counts, fill);
    k_count<<<(EP + B - 1) / B, B, 0, stream>>>(ei, counts);
    k_scan<<<1, 1024, 0, stream>>>(counts, rowst);
    k_scatter<<<(EP + B - 1) / B, B, 0, stream>>>(ei, rowst, fill, csr_src);
    k_prep1<<<1, B, 0, stream>>>(W1, a_src1, a_dst1, P1s, P1d);

    /* GAT layer 0 (all t batched) */
    k_gemm0<<<TN / 4, B, 0, stream>>>(x, W0, a_src0, a_dst0, XW0b, ALS0, ALD0);
    k_softmax_wave<<<TN / 4, B, 0, stream>>>(rowst, csr_src, ALS0, ALD0, M0, SI0, ALPHA0);
    k_accum0<<<TN / 4, B, 0, stream>>>(rowst, csr_src, XW0b, ALPHA0, b0, H0b);

    /* GAT layer 1: logits via P, softmax+alpha, aggregate-then-GEMM */
    k_logits1<<<TN / 4, B, 0, stream>>>(H0b, P1s, P1d, ALS1, ALD1);
    k_softmax_wave<<<TN / 4, B, 0, stream>>>(rowst, csr_src, ALS1, ALD1, M1, SI1, ALPHA1);
    k_alpha_out<<<(EP + B - 1) / B, B, 0, stream>>>(ei, ALS1, ALD1, M1, SI1,
                                                    out + (size_t)N_NODES * HID);
    k_accum1_agg<<<TN / 4, B, 0, stream>>>(rowst, csr_src, H0b, ALPHA1, AGG1b);
    k_post1<<<TN / 16, B, 0, stream>>>(AGG1b, W1, b1, ln_g, ln_b, HS);

    /* GRU: non-recurrent half batched over all t, then 6 sequential steps */
    k_gi<<<TN / 48, 192, 0, stream>>>(HS, W_ih, b_ih, GIb);
    k_zero<<<(N_NODES * 64 + B - 1) / B, B, 0, stream>>>(HA, N_NODES * 64);
    float* hbuf[2] = { HA, HB };
    for (int t = 0; t < T_STEPS; t++) {
        float* prev = hbuf[t & 1];
        float* next = (t == T_STEPS - 1) ? out : hbuf[1 - (t & 1)];
        k_gru_step<<<N_NODES / 40, 192, 0, stream>>>(t, GIb, W_hh, b_hh, prev, next);
    }

    /* outputs (fp32): [hT (640000)] [alpha_last (680000)] [edge_index (340000)] */
    k_out_ei<<<(2 * EP + B - 1) / B, B, 0, stream>>>(ei, out + (size_t)N_NODES * HID + (size_t)EP * HEADS);
}

// Round 7
// 715.457 us; speedup vs baseline: 1.7450x; 1.0654x over previous
//
#include <hip/hip_runtime.h>
#include <hip/hip_bf16.h>
#include <cstdint>
#include <cstddef>

#define N_NODES 10000
#define T_STEPS 6
#define F_IN    64
#define HID     64
#define HEADS   4
#define E_EDGES 160000
#define EP      (E_EDGES + N_NODES)   /* 170000 edges incl self-loops */
#define TN      (T_STEPS * N_NODES)   /* 60000 */

typedef __hip_bfloat16 bf16;

__device__ __forceinline__ float b2f(bf16 v) { return __bfloat162float(v); }
__device__ __forceinline__ float bfu(unsigned short s) { return __uint_as_float((unsigned)s << 16); }
__device__ __forceinline__ unsigned short f2bu(float f) {
    bf16 b = __float2bfloat16(f);
    return *(unsigned short*)&b;
}
__device__ __forceinline__ float sel4(float4 v, int h) {
    float r = v.x;
    r = (h == 1) ? v.y : r;
    r = (h == 2) ? v.z : r;
    r = (h == 3) ? v.w : r;
    return r;
}

/* ---------------- CSR build ---------------- */

__global__ void k_init(int* counts, int* fill) {
    int i = blockIdx.x * blockDim.x + threadIdx.x;
    if (i < N_NODES) { counts[i] = 0; fill[i] = 0; }
}

__global__ void k_count(const int* ei, int* counts) {
    int e = blockIdx.x * blockDim.x + threadIdx.x;
    if (e >= EP) return;
    int dst = (e < E_EDGES) ? ei[E_EDGES + e] : (e - E_EDGES);
    atomicAdd(&counts[dst], 1);
}

__global__ void k_scan(const int* counts, int* rowstart) {
    __shared__ int part[1024];
    int tid = threadIdx.x;
    const int chunk = (N_NODES + 1023) / 1024;  // 10
    int base = tid * chunk;
    int s = 0;
    for (int i = 0; i < chunk; i++) { int idx = base + i; if (idx < N_NODES) s += counts[idx]; }
    part[tid] = s;
    __syncthreads();
    for (int off = 1; off < 1024; off <<= 1) {
        int v = (tid >= off) ? part[tid - off] : 0;
        __syncthreads();
        part[tid] += v;
        __syncthreads();
    }
    int run = (tid == 0) ? 0 : part[tid - 1];
    for (int i = 0; i < chunk; i++) {
        int idx = base + i;
        if (idx < N_NODES) { rowstart[idx] = run; run += counts[idx]; }
    }
    if (tid == 0) rowstart[N_NODES] = EP;
}

__global__ void k_scatter(const int* ei, const int* rowstart, int* fill,
                          int* csr_src, int* csr_eid) {
    int e = blockIdx.x * blockDim.x + threadIdx.x;
    if (e >= EP) return;
    int src = (e < E_EDGES) ? ei[e] : (e - E_EDGES);
    int dst = (e < E_EDGES) ? ei[E_EDGES + e] : (e - E_EDGES);
    int pos = rowstart[dst] + atomicAdd(&fill[dst], 1);
    csr_src[pos] = src;
    csr_eid[pos] = e;
}

/* ---------------- prep: P-matrices for layer-1 logits ---------------- */

/* P1s[h][k] = sum_c W1[k, h*64+c] * a_src1[h,c]  (same for dst). One block. */
__global__ __launch_bounds__(256) void k_prep1(const float* __restrict__ W1,
                                               const float* __restrict__ a_src1,
                                               const float* __restrict__ a_dst1,
                                               float* __restrict__ P1s,
                                               float* __restrict__ P1d) {
    int tid = threadIdx.x;
    int h = tid >> 6, k = tid & 63;
    float ps = 0.f, pd = 0.f;
    for (int c = 0; c < 64; c++) {
        float wv = W1[k * 256 + h * 64 + c];
        ps += wv * a_src1[h * 64 + c];
        pd += wv * a_dst1[h * 64 + c];
    }
    P1s[h * 64 + k] = ps;
    P1d[h * 64 + k] = pd;
}

/* ---------------- GAT layer 0 GEMM ---------------- */

/* X[60000,64] @ W0[64,64] -> XW0 (bf16) + per-row logits. 16 rows/block. */
__global__ __launch_bounds__(256) void k_gemm0(const float* __restrict__ x,
                                               const float* __restrict__ W0,
                                               const float* __restrict__ a_src0,
                                               const float* __restrict__ a_dst0,
                                               bf16* __restrict__ XW0b,
                                               float* __restrict__ ALS0,
                                               float* __restrict__ ALD0) {
    __shared__ float wl[64 * 64];
    __shared__ float xl[16][64];
    int tid = threadIdx.x;
    for (int i = tid; i < 4096; i += 256) wl[i] = W0[i];
    int rbase = blockIdx.x * 16;
    for (int i = tid; i < 1024; i += 256) {
        int r = i >> 6, c = i & 63;
        int row = rbase + r;
        int t = row / N_NODES, n = row % N_NODES;
        xl[r][c] = x[(size_t)(n * T_STEPS + t) * F_IN + c];  // x is [N,T,F]
    }
    __syncthreads();
    int w = tid >> 6, c = tid & 63;
    int h = c >> 4, cc = c & 15;
    float as0 = a_src0[h * 16 + cc], ad0 = a_dst0[h * 16 + cc];
    for (int rr = 0; rr < 4; rr++) {
        int r = w * 4 + rr;
        int row = rbase + r;
        float acc = 0.f;
#pragma unroll
        for (int k = 0; k < 64; k++) acc += xl[r][k] * wl[k * 64 + c];
        XW0b[(size_t)row * 64 + c] = __float2bfloat16(acc);
        float ps = acc * as0, pd = acc * ad0;
#pragma unroll
        for (int o = 8; o; o >>= 1) { ps += __shfl_xor(ps, o, 64); pd += __shfl_xor(pd, o, 64); }
        if (cc == 0) { ALS0[row * 4 + h] = ps; ALD0[row * 4 + h] = pd; }
    }
}

/* ---------------- fused layer-0: softmax + accumulate + logits1 ----------
   one wave per (t,n). Pass A: stats (lanes stride edges). Pass B: 4 edges per
   iteration, 16 lanes/edge, ushort4 loads. Epilogue: bias+ELU -> H0b, plus
   layer-1 logits via P (fused). */
__global__ __launch_bounds__(256) void k_fused0(const int* __restrict__ rowst,
                                                const int* __restrict__ csr_src,
                                                const bf16* __restrict__ XW0b,
                                                const float* __restrict__ ALS0,
                                                const float* __restrict__ ALD0,
                                                const float* __restrict__ b0,
                                                const float* __restrict__ P1s,
                                                const float* __restrict__ P1d,
                                                bf16* __restrict__ H0b,
                                                float* __restrict__ ALS1,
                                                float* __restrict__ ALD1) {
    __shared__ float p1s_l[256], p1d_l[256];
    int tid = threadIdx.x;
    p1s_l[tid] = P1s[tid];
    p1d_l[tid] = P1d[tid];
    __syncthreads();
    int wid = blockIdx.x * 4 + (tid >> 6);
    int lane = tid & 63;
    int t = wid / N_NODES, n = wid % N_NODES;
    int rs = rowst[n], re = rowst[n + 1];
    int tb = t * N_NODES;
    float4 ad = *(const float4*)(ALD0 + (size_t)wid * 4);
    /* pass A: max */
    float m0 = -1e30f, m1 = -1e30f, m2 = -1e30f, m3 = -1e30f;
    for (int e = rs + lane; e < re; e += 64) {
        int src = csr_src[e];
        float4 as = *(const float4*)(ALS0 + (size_t)(tb + src) * 4);
        float l0 = as.x + ad.x; l0 = l0 > 0.f ? l0 : 0.2f * l0; m0 = fmaxf(m0, l0);
        float l1 = as.y + ad.y; l1 = l1 > 0.f ? l1 : 0.2f * l1; m1 = fmaxf(m1, l1);
        float l2 = as.z + ad.z; l2 = l2 > 0.f ? l2 : 0.2f * l2; m2 = fmaxf(m2, l2);
        float l3 = as.w + ad.w; l3 = l3 > 0.f ? l3 : 0.2f * l3; m3 = fmaxf(m3, l3);
    }
#pragma unroll
    for (int o = 32; o; o >>= 1) {
        m0 = fmaxf(m0, __shfl_xor(m0, o, 64));
        m1 = fmaxf(m1, __shfl_xor(m1, o, 64));
        m2 = fmaxf(m2, __shfl_xor(m2, o, 64));
        m3 = fmaxf(m3, __shfl_xor(m3, o, 64));
    }
    /* pass A2: sum */
    float s0 = 0.f, s1 = 0.f, s2 = 0.f, s3 = 0.f;
    for (int e = rs + lane; e < re; e += 64) {
        int src = csr_src[e];
        float4 as = *(const float4*)(ALS0 + (size_t)(tb + src) * 4);
        float l0 = as.x + ad.x; l0 = l0 > 0.f ? l0 : 0.2f * l0; s0 += __expf(l0 - m0);
        float l1 = as.y + ad.y; l1 = l1 > 0.f ? l1 : 0.2f * l1; s1 += __expf(l1 - m1);
        float l2 = as.z + ad.z; l2 = l2 > 0.f ? l2 : 0.2f * l2; s2 += __expf(l2 - m2);
        float l3 = as.w + ad.w; l3 = l3 > 0.f ? l3 : 0.2f * l3; s3 += __expf(l3 - m3);
    }
#pragma unroll
    for (int o = 32; o; o >>= 1) {
        s0 += __shfl_xor(s0, o, 64); s1 += __shfl_xor(s1, o, 64);
        s2 += __shfl_xor(s2, o, 64); s3 += __shfl_xor(s3, o, 64);
    }
    float i0 = 1.f / (s0 + 1e-16f), i1 = 1.f / (s1 + 1e-16f);
    float i2 = 1.f / (s2 + 1e-16f), i3 = 1.f / (s3 + 1e-16f);
    /* pass B: accumulate, 4 edges/iter, 16 lanes/edge */
    int g = lane >> 4, il = lane & 15;
    int h = il >> 2;
    float mh  = (h == 0) ? m0 : (h == 1) ? m1 : (h == 2) ? m2 : m3;
    float ih  = (h == 0) ? i0 : (h == 1) ? i1 : (h == 2) ? i2 : i3;
    float adh = sel4(ad, h);
    float a0 = 0.f, a1 = 0.f, a2 = 0.f, a3 = 0.f;
    for (int e0 = rs; e0 < re; e0 += 4) {
        int e = e0 + g;
        if (e < re) {
            int src = csr_src[e];
            float4 as = *(const float4*)(ALS0 + (size_t)(tb + src) * 4);
            float l = sel4(as, h) + adh; l = l > 0.f ? l : 0.2f * l;
            float a = __expf(l - mh) * ih;
            ushort4 u = *(const ushort4*)(XW0b + (size_t)(tb + src) * 64 + il * 4);
            a0 += a * bfu(u.x); a1 += a * bfu(u.y);
            a2 += a * bfu(u.z); a3 += a * bfu(u.w);
        }
    }
#pragma unroll
    for (int o = 16; o <= 32; o <<= 1) {
        a0 += __shfl_xor(a0, o, 64); a1 += __shfl_xor(a1, o, 64);
        a2 += __shfl_xor(a2, o, 64); a3 += __shfl_xor(a3, o, 64);
    }
    int cb = il * 4;
    float v0 = a0 + b0[cb + 0]; v0 = v0 > 0.f ? v0 : (__expf(v0) - 1.f);
    float v1 = a1 + b0[cb + 1]; v1 = v1 > 0.f ? v1 : (__expf(v1) - 1.f);
    float v2 = a2 + b0[cb + 2]; v2 = v2 > 0.f ? v2 : (__expf(v2) - 1.f);
    float v3 = a3 + b0[cb + 3]; v3 = v3 > 0.f ? v3 : (__expf(v3) - 1.f);
    /* fused layer-1 logits: ALS1[wid,hh] = sum_c h0[c]*P1s[hh*64+c] */
    float ps[4], pd[4];
#pragma unroll
    for (int hh = 0; hh < 4; hh++) {
        int base = hh * 64 + cb;
        ps[hh] = v0 * p1s_l[base] + v1 * p1s_l[base + 1] + v2 * p1s_l[base + 2] + v3 * p1s_l[base + 3];
        pd[hh] = v0 * p1d_l[base] + v1 * p1d_l[base + 1] + v2 * p1d_l[base + 2] + v3 * p1d_l[base + 3];
    }
#pragma unroll
    for (int o = 1; o <= 8; o <<= 1) {
#pragma unroll
        for (int hh = 0; hh < 4; hh++) {
            ps[hh] += __shfl_xor(ps[hh], o, 64);
            pd[hh] += __shfl_xor(pd[hh], o, 64);
        }
    }
    if (lane == 0) {
        float4 s4; s4.x = ps[0]; s4.y = ps[1]; s4.z = ps[2]; s4.w = ps[3];
        float4 d4; d4.x = pd[0]; d4.y = pd[1]; d4.z = pd[2]; d4.w = pd[3];
        *(float4*)(ALS1 + (size_t)wid * 4) = s4;
        *(float4*)(ALD1 + (size_t)wid * 4) = d4;
    }
    if (g == 0) {
        ushort4 o4;
        o4.x = f2bu(v0); o4.y = f2bu(v1); o4.z = f2bu(v2); o4.w = f2bu(v3);
        *(ushort4*)(H0b + (size_t)wid * 64 + cb) = o4;
    }
}

/* ---------------- fused layer-1: softmax + aggregate (+alpha out t=5) ---- */
__global__ __launch_bounds__(256) void k_fused1(const int* __restrict__ rowst,
                                                const int* __restrict__ csr_src,
                                                const int* __restrict__ csr_eid,
                                                const bf16* __restrict__ H0b,
                                                const float* __restrict__ ALS1,
                                                const float* __restrict__ ALD1,
                                                bf16* __restrict__ AGG1b,
                                                float* __restrict__ out_alpha) {
    int tid = threadIdx.x;
    int wid = blockIdx.x * 4 + (tid >> 6);
    int lane = tid & 63;
    int t = wid / N_NODES, n = wid % N_NODES;
    int rs = rowst[n], re = rowst[n + 1];
    int tb = t * N_NODES;
    float4 ad = *(const float4*)(ALD1 + (size_t)wid * 4);
    float m0 = -1e30f, m1 = -1e30f, m2 = -1e30f, m3 = -1e30f;
    for (int e = rs + lane; e < re; e += 64) {
        int src = csr_src[e];
        float4 as = *(const float4*)(ALS1 + (size_t)(tb + src) * 4);
        float l0 = as.x + ad.x; l0 = l0 > 0.f ? l0 : 0.2f * l0; m0 = fmaxf(m0, l0);
        float l1 = as.y + ad.y; l1 = l1 > 0.f ? l1 : 0.2f * l1; m1 = fmaxf(m1, l1);
        float l2 = as.z + ad.z; l2 = l2 > 0.f ? l2 : 0.2f * l2; m2 = fmaxf(m2, l2);
        float l3 = as.w + ad.w; l3 = l3 > 0.f ? l3 : 0.2f * l3; m3 = fmaxf(m3, l3);
    }
#pragma unroll
    for (int o = 32; o; o >>= 1) {
        m0 = fmaxf(m0, __shfl_xor(m0, o, 64));
        m1 = fmaxf(m1, __shfl_xor(m1, o, 64));
        m2 = fmaxf(m2, __shfl_xor(m2, o, 64));
        m3 = fmaxf(m3, __shfl_xor(m3, o, 64));
    }
    float s0 = 0.f, s1 = 0.f, s2 = 0.f, s3 = 0.f;
    for (int e = rs + lane; e < re; e += 64) {
        int src = csr_src[e];
        float4 as = *(const float4*)(ALS1 + (size_t)(tb + src) * 4);
        float l0 = as.x + ad.x; l0 = l0 > 0.f ? l0 : 0.2f * l0; s0 += __expf(l0 - m0);
        float l1 = as.y + ad.y; l1 = l1 > 0.f ? l1 : 0.2f * l1; s1 += __expf(l1 - m1);
        float l2 = as.z + ad.z; l2 = l2 > 0.f ? l2 : 0.2f * l2; s2 += __expf(l2 - m2);
        float l3 = as.w + ad.w; l3 = l3 > 0.f ? l3 : 0.2f * l3; s3 += __expf(l3 - m3);
    }
#pragma unroll
    for (int o = 32; o; o >>= 1) {
        s0 += __shfl_xor(s0, o, 64); s1 += __shfl_xor(s1, o, 64);
        s2 += __shfl_xor(s2, o, 64); s3 += __shfl_xor(s3, o, 64);
    }
    float i0 = 1.f / (s0 + 1e-16f), i1 = 1.f / (s1 + 1e-16f);
    float i2 = 1.f / (s2 + 1e-16f), i3 = 1.f / (s3 + 1e-16f);
    int g = lane >> 4, il = lane & 15;
    bool do_out = (t == T_STEPS - 1);
    float acc[4][4];
#pragma unroll
    for (int hh = 0; hh < 4; hh++)
#pragma unroll
        for (int j = 0; j < 4; j++) acc[hh][j] = 0.f;
    for (int e0 = rs; e0 < re; e0 += 4) {
        int e = e0 + g;
        if (e < re) {
            int src = csr_src[e];
            float4 as = *(const float4*)(ALS1 + (size_t)(tb + src) * 4);
            float l0 = as.x + ad.x; l0 = l0 > 0.f ? l0 : 0.2f * l0;
            float l1 = as.y + ad.y; l1 = l1 > 0.f ? l1 : 0.2f * l1;
            float l2 = as.z + ad.z; l2 = l2 > 0.f ? l2 : 0.2f * l2;
            float l3 = as.w + ad.w; l3 = l3 > 0.f ? l3 : 0.2f * l3;
            float al0 = __expf(l0 - m0) * i0;
            float al1 = __expf(l1 - m1) * i1;
            float al2 = __expf(l2 - m2) * i2;
            float al3 = __expf(l3 - m3) * i3;
            if (do_out && il == 0) {
                int eid = csr_eid[e];
                float4 o4; o4.x = al0; o4.y = al1; o4.z = al2; o4.w = al3;
                *(float4*)(out_alpha + (size_t)eid * 4) = o4;
            }
            ushort4 u = *(const ushort4*)(H0b + (size_t)(tb + src) * 64 + il * 4);
            float x0 = bfu(u.x), x1 = bfu(u.y), x2 = bfu(u.z), x3 = bfu(u.w);
            acc[0][0] += al0 * x0; acc[0][1] += al0 * x1; acc[0][2] += al0 * x2; acc[0][3] += al0 * x3;
            acc[1][0] += al1 * x0; acc[1][1] += al1 * x1; acc[1][2] += al1 * x2; acc[1][3] += al1 * x3;
            acc[2][0] += al2 * x0; acc[2][1] += al2 * x1; acc[2][2] += al2 * x2; acc[2][3] += al2 * x3;
            acc[3][0] += al3 * x0; acc[3][1] += al3 * x1; acc[3][2] += al3 * x2; acc[3][3] += al3 * x3;
        }
    }
#pragma unroll
    for (int o = 16; o <= 32; o <<= 1)
#pragma unroll
        for (int hh = 0; hh < 4; hh++)
#pragma unroll
            for (int j = 0; j < 4; j++)
                acc[hh][j] += __shfl_xor(acc[hh][j], o, 64);
    if (g == 0) {
        int cb = il * 4;
        size_t ob = (size_t)wid * 256 + cb;
#pragma unroll
        for (int hh = 0; hh < 4; hh++) {
            ushort4 o4;
            o4.x = f2bu(acc[hh][0]); o4.y = f2bu(acc[hh][1]);
            o4.z = f2bu(acc[hh][2]); o4.w = f2bu(acc[hh][3]);
            *(ushort4*)(AGG1b + ob + hh * 64) = o4;
        }
    }
}

/* epilogue GEMM: HS[row,c] = LN(ELU(0.25 * AGG[row,:] @ Wbig[:,c] + b1)). */
__global__ __launch_bounds__(256) void k_post1(const bf16* __restrict__ AGG1b,
                                               const float* __restrict__ W1,
                                               const float* __restrict__ b1,
                                               const float* __restrict__ ln_g,
                                               const float* __restrict__ ln_b,
                                               float* __restrict__ HS) {
    __shared__ float xs[16][256];        /* 16 KB */
    __shared__ float part[16][4][64];    /* 16 KB */
    int tid = threadIdx.x;
    int q = tid >> 6, c = tid & 63;
    float wq[64];
#pragma unroll
    for (int k = 0; k < 64; k++) wq[k] = W1[k * 256 + q * 64 + c];
    int rbase = blockIdx.x * 16;
    /* stage 16 AGG rows bf16->fp32; 2 consecutive floats per write (2-way = free) */
    const unsigned* agu = (const unsigned*)(AGG1b + (size_t)rbase * 256);
    for (int i = tid; i < 2048; i += 256) {
        unsigned u = agu[i];
        int r = i >> 7, base = (i & 127) * 2;
        xs[r][base + 0] = __uint_as_float(u << 16);
        xs[r][base + 1] = __uint_as_float(u & 0xffff0000u);
    }
    __syncthreads();
    for (int r = 0; r < 16; r++) {
        const float* xr = &xs[r][q * 64];
        float acc = 0.f;
#pragma unroll
        for (int kk = 0; kk < 16; kk++) {
            float4 xv = *(const float4*)(xr + kk * 4);
            acc += xv.x * wq[kk * 4 + 0] + xv.y * wq[kk * 4 + 1]
                 + xv.z * wq[kk * 4 + 2] + xv.w * wq[kk * 4 + 3];
        }
        part[r][q][c] = acc;
    }
    __syncthreads();
    float b1c = b1[c], gg = ln_g[c], bb = ln_b[c];
    for (int rr = 0; rr < 4; rr++) {
        int r = q * 4 + rr;
        float v = (part[r][0][c] + part[r][1][c] + part[r][2][c] + part[r][3][c]) * 0.25f + b1c;
        v = v > 0.f ? v : (__expf(v) - 1.f);
        float s = v;
#pragma unroll
        for (int o = 32; o; o >>= 1) s += __shfl_xor(s, o, 64);
        float mu = s * (1.f / 64.f);
        float d = v - mu;
        float qd = d * d;
#pragma unroll
        for (int o = 32; o; o >>= 1) qd += __shfl_xor(qd, o, 64);
        float var = qd * (1.f / 64.f);
        HS[(size_t)(rbase + r) * 64 + c] = d * rsqrtf(var + 1e-5f) * gg + bb;
    }
}

/* ---------------- GRU: all 6 steps in one kernel ----------------
   Block = 192 threads, 16 nodes. Weights bf16x2-packed in LDS (transposed,
   conflict-free); h-state lives in LDS; final step writes hT to d_out. */
__global__ __launch_bounds__(192) void k_gru_all(const float* __restrict__ HS,
                                                 const float* __restrict__ W_ih,
                                                 const float* __restrict__ b_ih,
                                                 const float* __restrict__ W_hh,
                                                 const float* __restrict__ b_hh,
                                                 float* __restrict__ outh) {
    __shared__ unsigned wi2[32 * 192];   /* [k2][j] packed bf16x2: 24 KB */
    __shared__ unsigned wh2[32 * 192];   /* 24 KB */
    __shared__ float xs[16][64], Hst[16][64];      /* 8 KB */
    __shared__ float gis[8][192], ghs[8][192];     /* 12 KB */
    int j = threadIdx.x;
    for (int i = j; i < 6144; i += 192) {
        int k2 = i / 192, jj = i - k2 * 192;
        unsigned ua = ((unsigned)f2bu(W_ih[jj * 64 + k2 * 2 + 1]) << 16)
                    |  (unsigned)f2bu(W_ih[jj * 64 + k2 * 2]);
        unsigned ub = ((unsigned)f2bu(W_hh[jj * 64 + k2 * 2 + 1]) << 16)
                    |  (unsigned)f2bu(W_hh[jj * 64 + k2 * 2]);
        wi2[i] = ua;
        wh2[i] = ub;
    }
    for (int i = j; i < 1024; i += 192) Hst[i >> 6][i & 63] = 0.f;
    float bi = b_ih[j], bh = b_hh[j];
    int nb = blockIdx.x * 16;
    for (int t = 0; t < T_STEPS; t++) {
        for (int i = j; i < 1024; i += 192) {
            int r = i >> 6, c = i & 63;
            xs[r][c] = HS[((size_t)t * N_NODES + nb + r) * 64 + c];
        }
        __syncthreads();
        for (int half = 0; half < 2; half++) {
            for (int rr8 = 0; rr8 < 8; rr8++) {
                int rr = half * 8 + rr8;
                float gi = bi, gh = bh;
#pragma unroll
                for (int k2 = 0; k2 < 32; k2++) {
                    unsigned ua = wi2[k2 * 192 + j];
                    unsigned ub = wh2[k2 * 192 + j];
                    float x0 = xs[rr][k2 * 2], x1 = xs[rr][k2 * 2 + 1];
                    float h0 = Hst[rr][k2 * 2], h1 = Hst[rr][k2 * 2 + 1];
                    gi += __uint_as_float(ua << 16) * x0 + __uint_as_float(ua & 0xffff0000u) * x1;
                    gh += __uint_as_float(ub << 16) * h0 + __uint_as_float(ub & 0xffff0000u) * h1;
                }
                gis[rr8][j] = gi;
                ghs[rr8][j] = gh;
            }
            __syncthreads();
            if (j < 64) {
                for (int rr8 = 0; rr8 < 8; rr8++) {
                    int rr = half * 8 + rr8;
                    float r_ = 1.f / (1.f + __expf(-(gis[rr8][j] + ghs[rr8][j])));
                    float z  = 1.f / (1.f + __expf(-(gis[rr8][64 + j] + ghs[rr8][64 + j])));
                    float gv = tanhf(gis[rr8][128 + j] + r_ * ghs[rr8][128 + j]);
                    float hn = (1.f - z) * gv + z * Hst[rr][j];
                    Hst[rr][j] = hn;
                    if (t == T_STEPS - 1) outh[(size_t)(nb + rr) * 64 + j] = hn;
                }
            }
            __syncthreads();
        }
    }
}

/* ---------------- output writer (fp32) ---------------- */

__global__ void k_out_ei(const int* __restrict__ ei, float* __restrict__ out) {
    int i = blockIdx.x * blockDim.x + threadIdx.x;
    if (i >= 2 * EP) return;
    int v;
    if (i < EP) {
        v = (i < E_EDGES) ? ei[i] : (i - E_EDGES);                 // src row
    } else {
        int jj = i - EP;
        v = (jj < E_EDGES) ? ei[E_EDGES + jj] : (jj - E_EDGES);    // dst row
    }
    out[i] = (float)v;
}

/* ---------------- launch ---------------- */

extern "C" void kernel_launch(void* const* d_in, const int* in_sizes, int n_in,
                              void* d_out, int out_size, void* d_ws, size_t ws_size,
                              hipStream_t stream) {
    const float* x      = (const float*)d_in[0];
    const int*   ei     = (const int*)d_in[1];
    const float* W0     = (const float*)d_in[2];
    const float* a_src0 = (const float*)d_in[3];
    const float* a_dst0 = (const float*)d_in[4];
    const float* b0     = (const float*)d_in[5];
    const float* W1     = (const float*)d_in[6];
    const float* a_src1 = (const float*)d_in[7];
    const float* a_dst1 = (const float*)d_in[8];
    const float* b1     = (const float*)d_in[9];
    const float* ln_g   = (const float*)d_in[10];
    const float* ln_b   = (const float*)d_in[11];
    const float* W_ih   = (const float*)d_in[12];
    const float* W_hh   = (const float*)d_in[13];
    const float* b_ih   = (const float*)d_in[14];
    const float* b_hh   = (const float*)d_in[15];
    float* out = (float*)d_out;

    char* w = (char*)d_ws;
    size_t off = 0;
    auto take = [&](size_t bytes) -> void* {
        void* p = w + off;
        off = (off + bytes + 255) & ~(size_t)255;
        return p;
    };
    int*   counts  = (int*)take(N_NODES * 4);
    int*   fill    = (int*)take(N_NODES * 4);
    int*   rowst   = (int*)take((N_NODES + 1) * 4);
    int*   csr_src = (int*)take((size_t)EP * 4);
    int*   csr_eid = (int*)take((size_t)EP * 4);
    bf16*  XW0b    = (bf16*)take((size_t)TN * 64 * 2);
    float* ALS0    = (float*)take((size_t)TN * 4 * 4);
    float* ALD0    = (float*)take((size_t)TN * 4 * 4);
    bf16*  H0b     = (bf16*)take((size_t)TN * 64 * 2);
    float* P1s     = (float*)take(256 * 4);
    float* P1d     = (float*)take(256 * 4);
    float* ALS1    = (float*)take((size_t)TN * 4 * 4);
    float* ALD1    = (float*)take((size_t)TN * 4 * 4);
    bf16*  AGG1b   = (bf16*)take((size_t)TN * 256 * 2);
    float* HS      = (float*)take((size_t)TN * 64 * 4);
    (void)ws_size; (void)in_sizes; (void)n_in; (void)out_size;

    const int B = 256;
    /* CSR build + prep */
    k_init<<<(N_NODES + B - 1) / B, B, 0, stream>>>(counts, fill);
    k_count<<<(EP + B - 1) / B, B, 0, stream>>>(ei, counts);
    k_scan<<<1, 1024, 0, stream>>>(counts, rowst);
    k_scatter<<<(EP + B - 1) / B, B, 0, stream>>>(ei, rowst, fill, csr_src, csr_eid);
    k_prep1<<<1, B, 0, stream>>>(W1, a_src1, a_dst1, P1s, P1d);

    /* GAT layer 0 */
    k_gemm0<<<TN / 16, B, 0, stream>>>(x, W0, a_src0, a_dst0, XW0b, ALS0, ALD0);
    k_fused0<<<TN / 4, B, 0, stream>>>(rowst, csr_src, XW0b, ALS0, ALD0, b0,
                                       P1s, P1d, H0b, ALS1, ALD1);

    /* GAT layer 1 */
    k_fused1<<<TN / 4, B, 0, stream>>>(rowst, csr_src, csr_eid, H0b, ALS1, ALD1,
                                       AGG1b, out + (size_t)N_NODES * HID);
    k_post1<<<TN / 16, B, 0, stream>>>(AGG1b, W1, b1, ln_g, ln_b, HS);

    /* GRU (all 6 steps; writes hT to out) */
    k_gru_all<<<N_NODES / 16, 192, 0, stream>>>(HS, W_ih, b_ih, W_hh, b_hh, out);

    /* edge-index output */
    k_out_ei<<<(2 * EP + B - 1) / B, B, 0, stream>>>(ei, out + (size_t)N_NODES * HID + (size_t)EP * HEADS);
}

// Round 8
// 541.258 us; speedup vs baseline: 2.3066x; 1.3218x over previous
//
#include <hip/hip_runtime.h>
#include <hip/hip_bf16.h>
#include <cstdint>
#include <cstddef>

#define N_NODES 10000
#define T_STEPS 6
#define F_IN    64
#define HID     64
#define HEADS   4
#define E_EDGES 160000
#define EP      (E_EDGES + N_NODES)   /* 170000 edges incl self-loops */
#define TN      (T_STEPS * N_NODES)   /* 60000 */

typedef __hip_bfloat16 bf16;

__device__ __forceinline__ float b2f(bf16 v) { return __bfloat162float(v); }
__device__ __forceinline__ float bfu(unsigned short s) { return __uint_as_float((unsigned)s << 16); }
__device__ __forceinline__ unsigned short f2bu(float f) {
    bf16 b = __float2bfloat16(f);
    return *(unsigned short*)&b;
}
__device__ __forceinline__ float sel4(float4 v, int h) {
    float r = v.x;
    r = (h == 1) ? v.y : r;
    r = (h == 2) ? v.z : r;
    r = (h == 3) ? v.w : r;
    return r;
}

/* ---------------- CSR build ---------------- */

__global__ void k_init(int* counts, int* fill) {
    int i = blockIdx.x * blockDim.x + threadIdx.x;
    if (i < N_NODES) { counts[i] = 0; fill[i] = 0; }
}

__global__ void k_count(const int* ei, int* counts) {
    int e = blockIdx.x * blockDim.x + threadIdx.x;
    if (e >= EP) return;
    int dst = (e < E_EDGES) ? ei[E_EDGES + e] : (e - E_EDGES);
    atomicAdd(&counts[dst], 1);
}

__global__ void k_scan(const int* counts, int* rowstart) {
    __shared__ int part[1024];
    int tid = threadIdx.x;
    const int chunk = (N_NODES + 1023) / 1024;  // 10
    int base = tid * chunk;
    int s = 0;
    for (int i = 0; i < chunk; i++) { int idx = base + i; if (idx < N_NODES) s += counts[idx]; }
    part[tid] = s;
    __syncthreads();
    for (int off = 1; off < 1024; off <<= 1) {
        int v = (tid >= off) ? part[tid - off] : 0;
        __syncthreads();
        part[tid] += v;
        __syncthreads();
    }
    int run = (tid == 0) ? 0 : part[tid - 1];
    for (int i = 0; i < chunk; i++) {
        int idx = base + i;
        if (idx < N_NODES) { rowstart[idx] = run; run += counts[idx]; }
    }
    if (tid == 0) rowstart[N_NODES] = EP;
}

__global__ void k_scatter(const int* ei, const int* rowstart, int* fill,
                          int* csr_src, int* csr_eid) {
    int e = blockIdx.x * blockDim.x + threadIdx.x;
    if (e >= EP) return;
    int src = (e < E_EDGES) ? ei[e] : (e - E_EDGES);
    int dst = (e < E_EDGES) ? ei[E_EDGES + e] : (e - E_EDGES);
    int pos = rowstart[dst] + atomicAdd(&fill[dst], 1);
    csr_src[pos] = src;
    csr_eid[pos] = e;
}

/* ---------------- prep: P-matrices for layer-1 logits ---------------- */

__global__ __launch_bounds__(256) void k_prep1(const float* __restrict__ W1,
                                               const float* __restrict__ a_src1,
                                               const float* __restrict__ a_dst1,
                                               float* __restrict__ P1s,
                                               float* __restrict__ P1d) {
    int tid = threadIdx.x;
    int h = tid >> 6, k = tid & 63;
    float ps = 0.f, pd = 0.f;
    for (int c = 0; c < 64; c++) {
        float wv = W1[k * 256 + h * 64 + c];
        ps += wv * a_src1[h * 64 + c];
        pd += wv * a_dst1[h * 64 + c];
    }
    P1s[h * 64 + k] = ps;
    P1d[h * 64 + k] = pd;
}

/* ---------------- GAT layer 0 GEMM ---------------- */

__global__ __launch_bounds__(256) void k_gemm0(const float* __restrict__ x,
                                               const float* __restrict__ W0,
                                               const float* __restrict__ a_src0,
                                               const float* __restrict__ a_dst0,
                                               bf16* __restrict__ XW0b,
                                               float* __restrict__ ALS0,
                                               float* __restrict__ ALD0) {
    __shared__ float wl[64 * 64];
    __shared__ float xl[16][64];
    int tid = threadIdx.x;
    for (int i = tid; i < 4096; i += 256) wl[i] = W0[i];
    int rbase = blockIdx.x * 16;
    for (int i = tid; i < 1024; i += 256) {
        int r = i >> 6, c = i & 63;
        int row = rbase + r;
        int t = row / N_NODES, n = row % N_NODES;
        xl[r][c] = x[(size_t)(n * T_STEPS + t) * F_IN + c];  // x is [N,T,F]
    }
    __syncthreads();
    int w = tid >> 6, c = tid & 63;
    int h = c >> 4, cc = c & 15;
    float as0 = a_src0[h * 16 + cc], ad0 = a_dst0[h * 16 + cc];
    for (int rr = 0; rr < 4; rr++) {
        int r = w * 4 + rr;
        int row = rbase + r;
        float acc = 0.f;
#pragma unroll
        for (int k = 0; k < 64; k++) acc += xl[r][k] * wl[k * 64 + c];
        XW0b[(size_t)row * 64 + c] = __float2bfloat16(acc);
        float ps = acc * as0, pd = acc * ad0;
#pragma unroll
        for (int o = 8; o; o >>= 1) { ps += __shfl_xor(ps, o, 64); pd += __shfl_xor(pd, o, 64); }
        if (cc == 0) { ALS0[row * 4 + h] = ps; ALD0[row * 4 + h] = pd; }
    }
}

/* ---------------- fused layer-0: softmax + accumulate + logits1 ---------- */
__global__ __launch_bounds__(256) void k_fused0(const int* __restrict__ rowst,
                                                const int* __restrict__ csr_src,
                                                const bf16* __restrict__ XW0b,
                                                const float* __restrict__ ALS0,
                                                const float* __restrict__ ALD0,
                                                const float* __restrict__ b0,
                                                const float* __restrict__ P1s,
                                                const float* __restrict__ P1d,
                                                bf16* __restrict__ H0b,
                                                float* __restrict__ ALS1,
                                                float* __restrict__ ALD1) {
    __shared__ float p1s_l[256], p1d_l[256];
    int tid = threadIdx.x;
    p1s_l[tid] = P1s[tid];
    p1d_l[tid] = P1d[tid];
    __syncthreads();
    int wid = blockIdx.x * 4 + (tid >> 6);
    int lane = tid & 63;
    int t = wid / N_NODES, n = wid % N_NODES;
    int rs = rowst[n], re = rowst[n + 1];
    int tb = t * N_NODES;
    float4 ad = *(const float4*)(ALD0 + (size_t)wid * 4);
    float m0 = -1e30f, m1 = -1e30f, m2 = -1e30f, m3 = -1e30f;
    for (int e = rs + lane; e < re; e += 64) {
        int src = csr_src[e];
        float4 as = *(const float4*)(ALS0 + (size_t)(tb + src) * 4);
        float l0 = as.x + ad.x; l0 = l0 > 0.f ? l0 : 0.2f * l0; m0 = fmaxf(m0, l0);
        float l1 = as.y + ad.y; l1 = l1 > 0.f ? l1 : 0.2f * l1; m1 = fmaxf(m1, l1);
        float l2 = as.z + ad.z; l2 = l2 > 0.f ? l2 : 0.2f * l2; m2 = fmaxf(m2, l2);
        float l3 = as.w + ad.w; l3 = l3 > 0.f ? l3 : 0.2f * l3; m3 = fmaxf(m3, l3);
    }
#pragma unroll
    for (int o = 32; o; o >>= 1) {
        m0 = fmaxf(m0, __shfl_xor(m0, o, 64));
        m1 = fmaxf(m1, __shfl_xor(m1, o, 64));
        m2 = fmaxf(m2, __shfl_xor(m2, o, 64));
        m3 = fmaxf(m3, __shfl_xor(m3, o, 64));
    }
    float s0 = 0.f, s1 = 0.f, s2 = 0.f, s3 = 0.f;
    for (int e = rs + lane; e < re; e += 64) {
        int src = csr_src[e];
        float4 as = *(const float4*)(ALS0 + (size_t)(tb + src) * 4);
        float l0 = as.x + ad.x; l0 = l0 > 0.f ? l0 : 0.2f * l0; s0 += __expf(l0 - m0);
        float l1 = as.y + ad.y; l1 = l1 > 0.f ? l1 : 0.2f * l1; s1 += __expf(l1 - m1);
        float l2 = as.z + ad.z; l2 = l2 > 0.f ? l2 : 0.2f * l2; s2 += __expf(l2 - m2);
        float l3 = as.w + ad.w; l3 = l3 > 0.f ? l3 : 0.2f * l3; s3 += __expf(l3 - m3);
    }
#pragma unroll
    for (int o = 32; o; o >>= 1) {
        s0 += __shfl_xor(s0, o, 64); s1 += __shfl_xor(s1, o, 64);
        s2 += __shfl_xor(s2, o, 64); s3 += __shfl_xor(s3, o, 64);
    }
    float i0 = 1.f / (s0 + 1e-16f), i1 = 1.f / (s1 + 1e-16f);
    float i2 = 1.f / (s2 + 1e-16f), i3 = 1.f / (s3 + 1e-16f);
    int g = lane >> 4, il = lane & 15;
    int h = il >> 2;
    float mh  = (h == 0) ? m0 : (h == 1) ? m1 : (h == 2) ? m2 : m3;
    float ih  = (h == 0) ? i0 : (h == 1) ? i1 : (h == 2) ? i2 : i3;
    float adh = sel4(ad, h);
    float a0 = 0.f, a1 = 0.f, a2 = 0.f, a3 = 0.f;
    for (int e0 = rs; e0 < re; e0 += 4) {
        int e = e0 + g;
        if (e < re) {
            int src = csr_src[e];
            float4 as = *(const float4*)(ALS0 + (size_t)(tb + src) * 4);
            float l = sel4(as, h) + adh; l = l > 0.f ? l : 0.2f * l;
            float a = __expf(l - mh) * ih;
            ushort4 u = *(const ushort4*)(XW0b + (size_t)(tb + src) * 64 + il * 4);
            a0 += a * bfu(u.x); a1 += a * bfu(u.y);
            a2 += a * bfu(u.z); a3 += a * bfu(u.w);
        }
    }
#pragma unroll
    for (int o = 16; o <= 32; o <<= 1) {
        a0 += __shfl_xor(a0, o, 64); a1 += __shfl_xor(a1, o, 64);
        a2 += __shfl_xor(a2, o, 64); a3 += __shfl_xor(a3, o, 64);
    }
    int cb = il * 4;
    float v0 = a0 + b0[cb + 0]; v0 = v0 > 0.f ? v0 : (__expf(v0) - 1.f);
    float v1 = a1 + b0[cb + 1]; v1 = v1 > 0.f ? v1 : (__expf(v1) - 1.f);
    float v2 = a2 + b0[cb + 2]; v2 = v2 > 0.f ? v2 : (__expf(v2) - 1.f);
    float v3 = a3 + b0[cb + 3]; v3 = v3 > 0.f ? v3 : (__expf(v3) - 1.f);
    float ps[4], pd[4];
#pragma unroll
    for (int hh = 0; hh < 4; hh++) {
        int base = hh * 64 + cb;
        ps[hh] = v0 * p1s_l[base] + v1 * p1s_l[base + 1] + v2 * p1s_l[base + 2] + v3 * p1s_l[base + 3];
        pd[hh] = v0 * p1d_l[base] + v1 * p1d_l[base + 1] + v2 * p1d_l[base + 2] + v3 * p1d_l[base + 3];
    }
#pragma unroll
    for (int o = 1; o <= 8; o <<= 1) {
#pragma unroll
        for (int hh = 0; hh < 4; hh++) {
            ps[hh] += __shfl_xor(ps[hh], o, 64);
            pd[hh] += __shfl_xor(pd[hh], o, 64);
        }
    }
    if (lane == 0) {
        float4 s4; s4.x = ps[0]; s4.y = ps[1]; s4.z = ps[2]; s4.w = ps[3];
        float4 d4; d4.x = pd[0]; d4.y = pd[1]; d4.z = pd[2]; d4.w = pd[3];
        *(float4*)(ALS1 + (size_t)wid * 4) = s4;
        *(float4*)(ALD1 + (size_t)wid * 4) = d4;
    }
    if (g == 0) {
        ushort4 o4;
        o4.x = f2bu(v0); o4.y = f2bu(v1); o4.z = f2bu(v2); o4.w = f2bu(v3);
        *(ushort4*)(H0b + (size_t)wid * 64 + cb) = o4;
    }
}

/* ---------------- fused layer-1: softmax + aggregate (+alpha out t=5) ---- */
__global__ __launch_bounds__(256) void k_fused1(const int* __restrict__ rowst,
                                                const int* __restrict__ csr_src,
                                                const int* __restrict__ csr_eid,
                                                const bf16* __restrict__ H0b,
                                                const float* __restrict__ ALS1,
                                                const float* __restrict__ ALD1,
                                                bf16* __restrict__ AGG1b,
                                                float* __restrict__ out_alpha) {
    int tid = threadIdx.x;
    int wid = blockIdx.x * 4 + (tid >> 6);
    int lane = tid & 63;
    int t = wid / N_NODES, n = wid % N_NODES;
    int rs = rowst[n], re = rowst[n + 1];
    int tb = t * N_NODES;
    float4 ad = *(const float4*)(ALD1 + (size_t)wid * 4);
    float m0 = -1e30f, m1 = -1e30f, m2 = -1e30f, m3 = -1e30f;
    for (int e = rs + lane; e < re; e += 64) {
        int src = csr_src[e];
        float4 as = *(const float4*)(ALS1 + (size_t)(tb + src) * 4);
        float l0 = as.x + ad.x; l0 = l0 > 0.f ? l0 : 0.2f * l0; m0 = fmaxf(m0, l0);
        float l1 = as.y + ad.y; l1 = l1 > 0.f ? l1 : 0.2f * l1; m1 = fmaxf(m1, l1);
        float l2 = as.z + ad.z; l2 = l2 > 0.f ? l2 : 0.2f * l2; m2 = fmaxf(m2, l2);
        float l3 = as.w + ad.w; l3 = l3 > 0.f ? l3 : 0.2f * l3; m3 = fmaxf(m3, l3);
    }
#pragma unroll
    for (int o = 32; o; o >>= 1) {
        m0 = fmaxf(m0, __shfl_xor(m0, o, 64));
        m1 = fmaxf(m1, __shfl_xor(m1, o, 64));
        m2 = fmaxf(m2, __shfl_xor(m2, o, 64));
        m3 = fmaxf(m3, __shfl_xor(m3, o, 64));
    }
    float s0 = 0.f, s1 = 0.f, s2 = 0.f, s3 = 0.f;
    for (int e = rs + lane; e < re; e += 64) {
        int src = csr_src[e];
        float4 as = *(const float4*)(ALS1 + (size_t)(tb + src) * 4);
        float l0 = as.x + ad.x; l0 = l0 > 0.f ? l0 : 0.2f * l0; s0 += __expf(l0 - m0);
        float l1 = as.y + ad.y; l1 = l1 > 0.f ? l1 : 0.2f * l1; s1 += __expf(l1 - m1);
        float l2 = as.z + ad.z; l2 = l2 > 0.f ? l2 : 0.2f * l2; s2 += __expf(l2 - m2);
        float l3 = as.w + ad.w; l3 = l3 > 0.f ? l3 : 0.2f * l3; s3 += __expf(l3 - m3);
    }
#pragma unroll
    for (int o = 32; o; o >>= 1) {
        s0 += __shfl_xor(s0, o, 64); s1 += __shfl_xor(s1, o, 64);
        s2 += __shfl_xor(s2, o, 64); s3 += __shfl_xor(s3, o, 64);
    }
    float i0 = 1.f / (s0 + 1e-16f), i1 = 1.f / (s1 + 1e-16f);
    float i2 = 1.f / (s2 + 1e-16f), i3 = 1.f / (s3 + 1e-16f);
    int g = lane >> 4, il = lane & 15;
    bool do_out = (t == T_STEPS - 1);
    float acc[4][4];
#pragma unroll
    for (int hh = 0; hh < 4; hh++)
#pragma unroll
        for (int j = 0; j < 4; j++) acc[hh][j] = 0.f;
    for (int e0 = rs; e0 < re; e0 += 4) {
        int e = e0 + g;
        if (e < re) {
            int src = csr_src[e];
            float4 as = *(const float4*)(ALS1 + (size_t)(tb + src) * 4);
            float l0 = as.x + ad.x; l0 = l0 > 0.f ? l0 : 0.2f * l0;
            float l1 = as.y + ad.y; l1 = l1 > 0.f ? l1 : 0.2f * l1;
            float l2 = as.z + ad.z; l2 = l2 > 0.f ? l2 : 0.2f * l2;
            float l3 = as.w + ad.w; l3 = l3 > 0.f ? l3 : 0.2f * l3;
            float al0 = __expf(l0 - m0) * i0;
            float al1 = __expf(l1 - m1) * i1;
            float al2 = __expf(l2 - m2) * i2;
            float al3 = __expf(l3 - m3) * i3;
            if (do_out && il == 0) {
                int eid = csr_eid[e];
                float4 o4; o4.x = al0; o4.y = al1; o4.z = al2; o4.w = al3;
                *(float4*)(out_alpha + (size_t)eid * 4) = o4;
            }
            ushort4 u = *(const ushort4*)(H0b + (size_t)(tb + src) * 64 + il * 4);
            float x0 = bfu(u.x), x1 = bfu(u.y), x2 = bfu(u.z), x3 = bfu(u.w);
            acc[0][0] += al0 * x0; acc[0][1] += al0 * x1; acc[0][2] += al0 * x2; acc[0][3] += al0 * x3;
            acc[1][0] += al1 * x0; acc[1][1] += al1 * x1; acc[1][2] += al1 * x2; acc[1][3] += al1 * x3;
            acc[2][0] += al2 * x0; acc[2][1] += al2 * x1; acc[2][2] += al2 * x2; acc[2][3] += al2 * x3;
            acc[3][0] += al3 * x0; acc[3][1] += al3 * x1; acc[3][2] += al3 * x2; acc[3][3] += al3 * x3;
        }
    }
#pragma unroll
    for (int o = 16; o <= 32; o <<= 1)
#pragma unroll
        for (int hh = 0; hh < 4; hh++)
#pragma unroll
            for (int j = 0; j < 4; j++)
                acc[hh][j] += __shfl_xor(acc[hh][j], o, 64);
    if (g == 0) {
        int cb = il * 4;
        size_t ob = (size_t)wid * 256 + cb;
#pragma unroll
        for (int hh = 0; hh < 4; hh++) {
            ushort4 o4;
            o4.x = f2bu(acc[hh][0]); o4.y = f2bu(acc[hh][1]);
            o4.z = f2bu(acc[hh][2]); o4.w = f2bu(acc[hh][3]);
            *(ushort4*)(AGG1b + ob + hh * 64) = o4;
        }
    }
}

/* epilogue GEMM: HSb[row,c] = bf16(LN(ELU(0.25 * AGG[row,:]@Wbig[:,c] + b1))). */
__global__ __launch_bounds__(256) void k_post1(const bf16* __restrict__ AGG1b,
                                               const float* __restrict__ W1,
                                               const float* __restrict__ b1,
                                               const float* __restrict__ ln_g,
                                               const float* __restrict__ ln_b,
                                               bf16* __restrict__ HSb) {
    __shared__ float xs[16][256];
    __shared__ float part[16][4][64];
    int tid = threadIdx.x;
    int q = tid >> 6, c = tid & 63;
    float wq[64];
#pragma unroll
    for (int k = 0; k < 64; k++) wq[k] = W1[k * 256 + q * 64 + c];
    int rbase = blockIdx.x * 16;
    const unsigned* agu = (const unsigned*)(AGG1b + (size_t)rbase * 256);
    for (int i = tid; i < 2048; i += 256) {
        unsigned u = agu[i];
        int r = i >> 7, base = (i & 127) * 2;
        xs[r][base + 0] = __uint_as_float(u << 16);
        xs[r][base + 1] = __uint_as_float(u & 0xffff0000u);
    }
    __syncthreads();
    for (int r = 0; r < 16; r++) {
        const float* xr = &xs[r][q * 64];
        float acc = 0.f;
#pragma unroll
        for (int kk = 0; kk < 16; kk++) {
            float4 xv = *(const float4*)(xr + kk * 4);
            acc += xv.x * wq[kk * 4 + 0] + xv.y * wq[kk * 4 + 1]
                 + xv.z * wq[kk * 4 + 2] + xv.w * wq[kk * 4 + 3];
        }
        part[r][q][c] = acc;
    }
    __syncthreads();
    float b1c = b1[c], gg = ln_g[c], bb = ln_b[c];
    for (int rr = 0; rr < 4; rr++) {
        int r = q * 4 + rr;
        float v = (part[r][0][c] + part[r][1][c] + part[r][2][c] + part[r][3][c]) * 0.25f + b1c;
        v = v > 0.f ? v : (__expf(v) - 1.f);
        float s = v;
#pragma unroll
        for (int o = 32; o; o >>= 1) s += __shfl_xor(s, o, 64);
        float mu = s * (1.f / 64.f);
        float d = v - mu;
        float qd = d * d;
#pragma unroll
        for (int o = 32; o; o >>= 1) qd += __shfl_xor(qd, o, 64);
        float var = qd * (1.f / 64.f);
        bf16 ob = __float2bfloat16(d * rsqrtf(var + 1e-5f) * gg + bb);
        HSb[(size_t)(rbase + r) * 64 + c] = ob;
    }
}

/* ---------------- GRU ---------------- */

__global__ void k_zero(float* p, int nelem) {
    int i = blockIdx.x * blockDim.x + threadIdx.x;
    if (i < nelem) p[i] = 0.f;
}

/* non-recurrent half: GI[row,j] = b_ih[j] + dot(W_ih[j], HS[row]).
   192 threads (one per gate-row), 48 rows/block; weights in VGPRs;
   x-rows staged once, read via wave-uniform b128 broadcasts. */
__global__ __launch_bounds__(192) void k_gi(const bf16* __restrict__ HSb,
                                            const float* __restrict__ W_ih,
                                            const float* __restrict__ b_ih,
                                            bf16* __restrict__ GIb) {
    __shared__ float xs[48][64];   /* 12 KB */
    int j = threadIdx.x;
    float wi[64];
    const float4* wi4 = (const float4*)(W_ih) + (size_t)j * 16;
#pragma unroll
    for (int q = 0; q < 16; q++) {
        float4 a = wi4[q];
        wi[q * 4 + 0] = a.x; wi[q * 4 + 1] = a.y; wi[q * 4 + 2] = a.z; wi[q * 4 + 3] = a.w;
    }
    float bi = b_ih[j];
    int rbase = blockIdx.x * 48;
    const unsigned* hu = (const unsigned*)(HSb + (size_t)rbase * 64);
    for (int i = j; i < 1536; i += 192) {
        unsigned u = hu[i];
        int r = i >> 5, cb = (i & 31) * 2;
        xs[r][cb + 0] = __uint_as_float(u << 16);
        xs[r][cb + 1] = __uint_as_float(u & 0xffff0000u);
    }
    __syncthreads();
    for (int r = 0; r < 48; r++) {
        float a0 = 0.f, a1 = 0.f, a2 = 0.f, a3 = 0.f;
#pragma unroll
        for (int kk = 0; kk < 16; kk++) {
            float4 xv = *(const float4*)(&xs[r][kk * 4]);
            a0 += xv.x * wi[kk * 4 + 0]; a1 += xv.y * wi[kk * 4 + 1];
            a2 += xv.z * wi[kk * 4 + 2]; a3 += xv.w * wi[kk * 4 + 3];
        }
        GIb[(size_t)(rbase + r) * 192 + j] = __float2bfloat16(bi + a0 + a1 + a2 + a3);
    }
}

/* recurrent step: thread j holds W_hh row j in VGPRs; 20 nodes/block (500 blocks).
   2 syncs total; gh exchanged via LDS; pointwise over all 192 threads. */
__global__ __launch_bounds__(192) void k_gru_step(int t,
                                                  const bf16* __restrict__ GIb,
                                                  const float* __restrict__ W_hh,
                                                  const float* __restrict__ b_hh,
                                                  const float* __restrict__ Hprev,
                                                  float* __restrict__ Hnew) {
    __shared__ float hsv[20][64];    /* 5 KB */
    __shared__ float ghs[20][192];   /* 15 KB */
    int j = threadIdx.x;
    float wh[64];
    const float4* wh4 = (const float4*)(W_hh) + (size_t)j * 16;
#pragma unroll
    for (int q = 0; q < 16; q++) {
        float4 b = wh4[q];
        wh[q * 4 + 0] = b.x; wh[q * 4 + 1] = b.y; wh[q * 4 + 2] = b.z; wh[q * 4 + 3] = b.w;
    }
    float bh = b_hh[j];
    int nb = blockIdx.x * 20;
    for (int i = j; i < 1280; i += 192) hsv[i >> 6][i & 63] = Hprev[(size_t)nb * 64 + i];
    __syncthreads();
    for (int r = 0; r < 20; r++) {
        float a0 = 0.f, a1 = 0.f, a2 = 0.f, a3 = 0.f;
#pragma unroll
        for (int kk = 0; kk < 16; kk++) {
            float4 xv = *(const float4*)(&hsv[r][kk * 4]);
            a0 += xv.x * wh[kk * 4 + 0]; a1 += xv.y * wh[kk * 4 + 1];
            a2 += xv.z * wh[kk * 4 + 2]; a3 += xv.w * wh[kk * 4 + 3];
        }
        ghs[r][j] = bh + a0 + a1 + a2 + a3;
    }
    __syncthreads();
    const bf16* gib = GIb + ((size_t)t * N_NODES + nb) * 192;
    for (int i = j; i < 1280; i += 192) {
        int r = i >> 6, c = i & 63;
        float gir = b2f(gib[(size_t)r * 192 + c]);
        float giz = b2f(gib[(size_t)r * 192 + 64 + c]);
        float gig = b2f(gib[(size_t)r * 192 + 128 + c]);
        float rr_ = 1.f / (1.f + __expf(-(gir + ghs[r][c])));
        float z   = 1.f / (1.f + __expf(-(giz + ghs[r][64 + c])));
        float g   = tanhf(gig + rr_ * ghs[r][128 + c]);
        Hnew[(size_t)nb * 64 + i] = (1.f - z) * g + z * hsv[r][c];
    }
}

/* ---------------- output writer (fp32) ---------------- */

__global__ void k_out_ei(const int* __restrict__ ei, float* __restrict__ out) {
    int i = blockIdx.x * blockDim.x + threadIdx.x;
    if (i >= 2 * EP) return;
    int v;
    if (i < EP) {
        v = (i < E_EDGES) ? ei[i] : (i - E_EDGES);                 // src row
    } else {
        int jj = i - EP;
        v = (jj < E_EDGES) ? ei[E_EDGES + jj] : (jj - E_EDGES);    // dst row
    }
    out[i] = (float)v;
}

/* ---------------- launch ---------------- */

extern "C" void kernel_launch(void* const* d_in, const int* in_sizes, int n_in,
                              void* d_out, int out_size, void* d_ws, size_t ws_size,
                              hipStream_t stream) {
    const float* x      = (const float*)d_in[0];
    const int*   ei     = (const int*)d_in[1];
    const float* W0     = (const float*)d_in[2];
    const float* a_src0 = (const float*)d_in[3];
    const float* a_dst0 = (const float*)d_in[4];
    const float* b0     = (const float*)d_in[5];
    const float* W1     = (const float*)d_in[6];
    const float* a_src1 = (const float*)d_in[7];
    const float* a_dst1 = (const float*)d_in[8];
    const float* b1     = (const float*)d_in[9];
    const float* ln_g   = (const float*)d_in[10];
    const float* ln_b   = (const float*)d_in[11];
    const float* W_ih   = (const float*)d_in[12];
    const float* W_hh   = (const float*)d_in[13];
    const float* b_ih   = (const float*)d_in[14];
    const float* b_hh   = (const float*)d_in[15];
    float* out = (float*)d_out;

    char* w = (char*)d_ws;
    size_t off = 0;
    auto take = [&](size_t bytes) -> void* {
        void* p = w + off;
        off = (off + bytes + 255) & ~(size_t)255;
        return p;
    };
    int*   counts  = (int*)take(N_NODES * 4);
    int*   fill    = (int*)take(N_NODES * 4);
    int*   rowst   = (int*)take((N_NODES + 1) * 4);
    int*   csr_src = (int*)take((size_t)EP * 4);
    int*   csr_eid = (int*)take((size_t)EP * 4);
    bf16*  XW0b    = (bf16*)take((size_t)TN * 64 * 2);
    float* ALS0    = (float*)take((size_t)TN * 4 * 4);
    float* ALD0    = (float*)take((size_t)TN * 4 * 4);
    bf16*  H0b     = (bf16*)take((size_t)TN * 64 * 2);
    float* P1s     = (float*)take(256 * 4);
    float* P1d     = (float*)take(256 * 4);
    float* ALS1    = (float*)take((size_t)TN * 4 * 4);
    float* ALD1    = (float*)take((size_t)TN * 4 * 4);
    bf16*  AGG1b   = (bf16*)take((size_t)TN * 256 * 2);
    bf16*  HSb     = (bf16*)take((size_t)TN * 64 * 2);
    bf16*  GIb     = (bf16*)take((size_t)TN * 192 * 2);
    float* HA      = (float*)take((size_t)N_NODES * 64 * 4);
    float* HB      = (float*)take((size_t)N_NODES * 64 * 4);
    (void)ws_size; (void)in_sizes; (void)n_in; (void)out_size;

    const int B = 256;
    /* CSR build + prep */
    k_init<<<(N_NODES + B - 1) / B, B, 0, stream>>>(counts, fill);
    k_count<<<(EP + B - 1) / B, B, 0, stream>>>(ei, counts);
    k_scan<<<1, 1024, 0, stream>>>(counts, rowst);
    k_scatter<<<(EP + B - 1) / B, B, 0, stream>>>(ei, rowst, fill, csr_src, csr_eid);
    k_prep1<<<1, B, 0, stream>>>(W1, a_src1, a_dst1, P1s, P1d);

    /* GAT layer 0 */
    k_gemm0<<<TN / 16, B, 0, stream>>>(x, W0, a_src0, a_dst0, XW0b, ALS0, ALD0);
    k_fused0<<<TN / 4, B, 0, stream>>>(rowst, csr_src, XW0b, ALS0, ALD0, b0,
                                       P1s, P1d, H0b, ALS1, ALD1);

    /* GAT layer 1 */
    k_fused1<<<TN / 4, B, 0, stream>>>(rowst, csr_src, csr_eid, H0b, ALS1, ALD1,
                                       AGG1b, out + (size_t)N_NODES * HID);
    k_post1<<<TN / 16, B, 0, stream>>>(AGG1b, W1, b1, ln_g, ln_b, HSb);

    /* GRU: non-recurrent half batched, then 6 light sequential steps */
    k_gi<<<TN / 48, 192, 0, stream>>>(HSb, W_ih, b_ih, GIb);
    k_zero<<<(N_NODES * 64 + B - 1) / B, B, 0, stream>>>(HA, N_NODES * 64);
    float* hbuf[2] = { HA, HB };
    for (int t = 0; t < T_STEPS; t++) {
        float* prev = hbuf[t & 1];
        float* next = (t == T_STEPS - 1) ? out : hbuf[1 - (t & 1)];
        k_gru_step<<<N_NODES / 20, 192, 0, stream>>>(t, GIb, W_hh, b_hh, prev, next);
    }

    /* edge-index output */
    k_out_ei<<<(2 * EP + B - 1) / B, B, 0, stream>>>(ei, out + (size_t)N_NODES * HID + (size_t)EP * HEADS);
}

// Round 9
// 516.005 us; speedup vs baseline: 2.4195x; 1.0489x over previous
//
#include <hip/hip_runtime.h>
#include <hip/hip_bf16.h>
#include <cstdint>
#include <cstddef>

#define N_NODES 10000
#define T_STEPS 6
#define F_IN    64
#define HID     64
#define HEADS   4
#define E_EDGES 160000
#define EP      (E_EDGES + N_NODES)   /* 170000 edges incl self-loops */
#define TN      (T_STEPS * N_NODES)   /* 60000 */

typedef __hip_bfloat16 bf16;

__device__ __forceinline__ float b2f(bf16 v) { return __bfloat162float(v); }
__device__ __forceinline__ float bfu(unsigned short s) { return __uint_as_float((unsigned)s << 16); }
__device__ __forceinline__ unsigned short f2bu(float f) {
    bf16 b = __float2bfloat16(f);
    return *(unsigned short*)&b;
}
__device__ __forceinline__ float sel4(float4 v, int h) {
    float r = v.x;
    r = (h == 1) ? v.y : r;
    r = (h == 2) ? v.z : r;
    r = (h == 3) ? v.w : r;
    return r;
}
__device__ __forceinline__ void lds_fence() {
    asm volatile("s_waitcnt lgkmcnt(0)" ::: "memory");
}

/* ---------------- CSR build ---------------- */

__global__ void k_init(int* counts, int* fill) {
    int i = blockIdx.x * blockDim.x + threadIdx.x;
    if (i < N_NODES) { counts[i] = 0; fill[i] = 0; }
}

__global__ void k_count(const int* ei, int* counts) {
    int e = blockIdx.x * blockDim.x + threadIdx.x;
    if (e >= EP) return;
    int dst = (e < E_EDGES) ? ei[E_EDGES + e] : (e - E_EDGES);
    atomicAdd(&counts[dst], 1);
}

__global__ void k_scan(const int* counts, int* rowstart) {
    __shared__ int part[1024];
    int tid = threadIdx.x;
    const int chunk = (N_NODES + 1023) / 1024;  // 10
    int base = tid * chunk;
    int s = 0;
    for (int i = 0; i < chunk; i++) { int idx = base + i; if (idx < N_NODES) s += counts[idx]; }
    part[tid] = s;
    __syncthreads();
    for (int off = 1; off < 1024; off <<= 1) {
        int v = (tid >= off) ? part[tid - off] : 0;
        __syncthreads();
        part[tid] += v;
        __syncthreads();
    }
    int run = (tid == 0) ? 0 : part[tid - 1];
    for (int i = 0; i < chunk; i++) {
        int idx = base + i;
        if (idx < N_NODES) { rowstart[idx] = run; run += counts[idx]; }
    }
    if (tid == 0) rowstart[N_NODES] = EP;
}

__global__ void k_scatter(const int* ei, const int* rowstart, int* fill,
                          int* csr_src, int* csr_eid) {
    int e = blockIdx.x * blockDim.x + threadIdx.x;
    if (e >= EP) return;
    int src = (e < E_EDGES) ? ei[e] : (e - E_EDGES);
    int dst = (e < E_EDGES) ? ei[E_EDGES + e] : (e - E_EDGES);
    int pos = rowstart[dst] + atomicAdd(&fill[dst], 1);
    csr_src[pos] = src;
    csr_eid[pos] = e;
}

/* ---------------- prep: P-matrices for layer-1 logits ---------------- */

__global__ __launch_bounds__(256) void k_prep1(const float* __restrict__ W1,
                                               const float* __restrict__ a_src1,
                                               const float* __restrict__ a_dst1,
                                               float* __restrict__ P1s,
                                               float* __restrict__ P1d) {
    int tid = threadIdx.x;
    int h = tid >> 6, k = tid & 63;
    float ps = 0.f, pd = 0.f;
    for (int c = 0; c < 64; c++) {
        float wv = W1[k * 256 + h * 64 + c];
        ps += wv * a_src1[h * 64 + c];
        pd += wv * a_dst1[h * 64 + c];
    }
    P1s[h * 64 + k] = ps;
    P1d[h * 64 + k] = pd;
}

/* ---------------- GAT layer 0 GEMM ---------------- */

__global__ __launch_bounds__(256) void k_gemm0(const float* __restrict__ x,
                                               const float* __restrict__ W0,
                                               const float* __restrict__ a_src0,
                                               const float* __restrict__ a_dst0,
                                               bf16* __restrict__ XW0b,
                                               float* __restrict__ ALS0,
                                               float* __restrict__ ALD0) {
    __shared__ float wl[64 * 64];
    __shared__ float xl[16][64];
    int tid = threadIdx.x;
    for (int i = tid; i < 4096; i += 256) wl[i] = W0[i];
    int rbase = blockIdx.x * 16;
    for (int i = tid; i < 1024; i += 256) {
        int r = i >> 6, c = i & 63;
        int row = rbase + r;
        int t = row / N_NODES, n = row % N_NODES;
        xl[r][c] = x[(size_t)(n * T_STEPS + t) * F_IN + c];  // x is [N,T,F]
    }
    __syncthreads();
    int w = tid >> 6, c = tid & 63;
    int h = c >> 4, cc = c & 15;
    float as0 = a_src0[h * 16 + cc], ad0 = a_dst0[h * 16 + cc];
    for (int rr = 0; rr < 4; rr++) {
        int r = w * 4 + rr;
        int row = rbase + r;
        float acc = 0.f;
#pragma unroll
        for (int k = 0; k < 64; k++) acc += xl[r][k] * wl[k * 64 + c];
        XW0b[(size_t)row * 64 + c] = __float2bfloat16(acc);
        float ps = acc * as0, pd = acc * ad0;
#pragma unroll
        for (int o = 8; o; o >>= 1) { ps += __shfl_xor(ps, o, 64); pd += __shfl_xor(pd, o, 64); }
        if (cc == 0) { ALS0[row * 4 + h] = ps; ALD0[row * 4 + h] = pd; }
    }
}

/* ---------------- fused layer-0: softmax + accumulate + logits1 ----------
   One wave per (t,n). Fast path (deg<=64): single ALS sweep, 4 expf/edge,
   ex+src parked in per-wave LDS, unnormalized accumulate, scale by 1/s at end. */
__global__ __launch_bounds__(256) void k_fused0(const int* __restrict__ rowst,
                                                const int* __restrict__ csr_src,
                                                const bf16* __restrict__ XW0b,
                                                const float* __restrict__ ALS0,
                                                const float* __restrict__ ALD0,
                                                const float* __restrict__ b0,
                                                const float* __restrict__ P1s,
                                                const float* __restrict__ P1d,
                                                bf16* __restrict__ H0b,
                                                float* __restrict__ ALS1,
                                                float* __restrict__ ALD1) {
    __shared__ float p1s_l[256], p1d_l[256];
    __shared__ float exv[4][256];
    __shared__ int   srcs[4][64];
    int tid = threadIdx.x;
    p1s_l[tid] = P1s[tid];
    p1d_l[tid] = P1d[tid];
    __syncthreads();
    int wv = tid >> 6;
    int wid = blockIdx.x * 4 + wv;
    int lane = tid & 63;
    int t = wid / N_NODES, n = wid % N_NODES;
    int rs = rowst[n], re = rowst[n + 1];
    int deg = re - rs;
    int tb = t * N_NODES;
    float4 ad = *(const float4*)(ALD0 + (size_t)wid * 4);
    int g = lane >> 4, il = lane & 15;
    int h = il >> 2;
    float a0 = 0.f, a1 = 0.f, a2 = 0.f, a3 = 0.f;
    float scale_h = 1.f;

    if (deg <= 64) {
        int e = rs + lane;
        bool valid = e < re;
        int src = csr_src[valid ? e : rs];
        float4 as = *(const float4*)(ALS0 + (size_t)(tb + src) * 4);
        float l0 = as.x + ad.x; l0 = l0 > 0.f ? l0 : 0.2f * l0;
        float l1 = as.y + ad.y; l1 = l1 > 0.f ? l1 : 0.2f * l1;
        float l2 = as.z + ad.z; l2 = l2 > 0.f ? l2 : 0.2f * l2;
        float l3 = as.w + ad.w; l3 = l3 > 0.f ? l3 : 0.2f * l3;
        if (!valid) { l0 = -1e30f; l1 = -1e30f; l2 = -1e30f; l3 = -1e30f; }
        float m0 = l0, m1 = l1, m2 = l2, m3 = l3;
#pragma unroll
        for (int o = 32; o; o >>= 1) {
            m0 = fmaxf(m0, __shfl_xor(m0, o, 64));
            m1 = fmaxf(m1, __shfl_xor(m1, o, 64));
            m2 = fmaxf(m2, __shfl_xor(m2, o, 64));
            m3 = fmaxf(m3, __shfl_xor(m3, o, 64));
        }
        float e0 = __expf(l0 - m0), e1 = __expf(l1 - m1);
        float e2 = __expf(l2 - m2), e3 = __expf(l3 - m3);
        float s0 = e0, s1 = e1, s2 = e2, s3 = e3;
#pragma unroll
        for (int o = 32; o; o >>= 1) {
            s0 += __shfl_xor(s0, o, 64); s1 += __shfl_xor(s1, o, 64);
            s2 += __shfl_xor(s2, o, 64); s3 += __shfl_xor(s3, o, 64);
        }
        float i0 = 1.f / (s0 + 1e-16f), i1 = 1.f / (s1 + 1e-16f);
        float i2 = 1.f / (s2 + 1e-16f), i3 = 1.f / (s3 + 1e-16f);
        float4 ex4; ex4.x = e0; ex4.y = e1; ex4.z = e2; ex4.w = e3;
        *(float4*)&exv[wv][lane * 4] = ex4;
        srcs[wv][lane] = src;
        lds_fence();
        for (int k = g; k < deg; k += 4) {
            float aex = exv[wv][k * 4 + h];
            int s2_ = srcs[wv][k];
            ushort4 u = *(const ushort4*)(XW0b + (size_t)(tb + s2_) * 64 + il * 4);
            a0 += aex * bfu(u.x); a1 += aex * bfu(u.y);
            a2 += aex * bfu(u.z); a3 += aex * bfu(u.w);
        }
        scale_h = (h == 0) ? i0 : (h == 1) ? i1 : (h == 2) ? i2 : i3;
    } else {
        /* general path: old 3-sweep recompute */
        float m0 = -1e30f, m1 = -1e30f, m2 = -1e30f, m3 = -1e30f;
        for (int e = rs + lane; e < re; e += 64) {
            int src = csr_src[e];
            float4 as = *(const float4*)(ALS0 + (size_t)(tb + src) * 4);
            float l0 = as.x + ad.x; l0 = l0 > 0.f ? l0 : 0.2f * l0; m0 = fmaxf(m0, l0);
            float l1 = as.y + ad.y; l1 = l1 > 0.f ? l1 : 0.2f * l1; m1 = fmaxf(m1, l1);
            float l2 = as.z + ad.z; l2 = l2 > 0.f ? l2 : 0.2f * l2; m2 = fmaxf(m2, l2);
            float l3 = as.w + ad.w; l3 = l3 > 0.f ? l3 : 0.2f * l3; m3 = fmaxf(m3, l3);
        }
#pragma unroll
        for (int o = 32; o; o >>= 1) {
            m0 = fmaxf(m0, __shfl_xor(m0, o, 64));
            m1 = fmaxf(m1, __shfl_xor(m1, o, 64));
            m2 = fmaxf(m2, __shfl_xor(m2, o, 64));
            m3 = fmaxf(m3, __shfl_xor(m3, o, 64));
        }
        float s0 = 0.f, s1 = 0.f, s2 = 0.f, s3 = 0.f;
        for (int e = rs + lane; e < re; e += 64) {
            int src = csr_src[e];
            float4 as = *(const float4*)(ALS0 + (size_t)(tb + src) * 4);
            float l0 = as.x + ad.x; l0 = l0 > 0.f ? l0 : 0.2f * l0; s0 += __expf(l0 - m0);
            float l1 = as.y + ad.y; l1 = l1 > 0.f ? l1 : 0.2f * l1; s1 += __expf(l1 - m1);
            float l2 = as.z + ad.z; l2 = l2 > 0.f ? l2 : 0.2f * l2; s2 += __expf(l2 - m2);
            float l3 = as.w + ad.w; l3 = l3 > 0.f ? l3 : 0.2f * l3; s3 += __expf(l3 - m3);
        }
#pragma unroll
        for (int o = 32; o; o >>= 1) {
            s0 += __shfl_xor(s0, o, 64); s1 += __shfl_xor(s1, o, 64);
            s2 += __shfl_xor(s2, o, 64); s3 += __shfl_xor(s3, o, 64);
        }
        float i0 = 1.f / (s0 + 1e-16f), i1 = 1.f / (s1 + 1e-16f);
        float i2 = 1.f / (s2 + 1e-16f), i3 = 1.f / (s3 + 1e-16f);
        float mh = (h == 0) ? m0 : (h == 1) ? m1 : (h == 2) ? m2 : m3;
        float ih = (h == 0) ? i0 : (h == 1) ? i1 : (h == 2) ? i2 : i3;
        float adh = sel4(ad, h);
        for (int e0_ = rs; e0_ < re; e0_ += 4) {
            int e = e0_ + g;
            if (e < re) {
                int src = csr_src[e];
                float4 as = *(const float4*)(ALS0 + (size_t)(tb + src) * 4);
                float l = sel4(as, h) + adh; l = l > 0.f ? l : 0.2f * l;
                float a = __expf(l - mh) * ih;
                ushort4 u = *(const ushort4*)(XW0b + (size_t)(tb + src) * 64 + il * 4);
                a0 += a * bfu(u.x); a1 += a * bfu(u.y);
                a2 += a * bfu(u.z); a3 += a * bfu(u.w);
            }
        }
        scale_h = 1.f;
    }
#pragma unroll
    for (int o = 16; o <= 32; o <<= 1) {
        a0 += __shfl_xor(a0, o, 64); a1 += __shfl_xor(a1, o, 64);
        a2 += __shfl_xor(a2, o, 64); a3 += __shfl_xor(a3, o, 64);
    }
    int cb = il * 4;
    float v0 = a0 * scale_h + b0[cb + 0]; v0 = v0 > 0.f ? v0 : (__expf(v0) - 1.f);
    float v1 = a1 * scale_h + b0[cb + 1]; v1 = v1 > 0.f ? v1 : (__expf(v1) - 1.f);
    float v2 = a2 * scale_h + b0[cb + 2]; v2 = v2 > 0.f ? v2 : (__expf(v2) - 1.f);
    float v3 = a3 * scale_h + b0[cb + 3]; v3 = v3 > 0.f ? v3 : (__expf(v3) - 1.f);
    float ps[4], pd[4];
#pragma unroll
    for (int hh = 0; hh < 4; hh++) {
        int base = hh * 64 + cb;
        ps[hh] = v0 * p1s_l[base] + v1 * p1s_l[base + 1] + v2 * p1s_l[base + 2] + v3 * p1s_l[base + 3];
        pd[hh] = v0 * p1d_l[base] + v1 * p1d_l[base + 1] + v2 * p1d_l[base + 2] + v3 * p1d_l[base + 3];
    }
#pragma unroll
    for (int o = 1; o <= 8; o <<= 1) {
#pragma unroll
        for (int hh = 0; hh < 4; hh++) {
            ps[hh] += __shfl_xor(ps[hh], o, 64);
            pd[hh] += __shfl_xor(pd[hh], o, 64);
        }
    }
    if (lane == 0) {
        float4 s4; s4.x = ps[0]; s4.y = ps[1]; s4.z = ps[2]; s4.w = ps[3];
        float4 d4; d4.x = pd[0]; d4.y = pd[1]; d4.z = pd[2]; d4.w = pd[3];
        *(float4*)(ALS1 + (size_t)wid * 4) = s4;
        *(float4*)(ALD1 + (size_t)wid * 4) = d4;
    }
    if (g == 0) {
        ushort4 o4;
        o4.x = f2bu(v0); o4.y = f2bu(v1); o4.z = f2bu(v2); o4.w = f2bu(v3);
        *(ushort4*)(H0b + (size_t)wid * 64 + cb) = o4;
    }
}

/* ---------------- fused layer-1: softmax + aggregate (+alpha out t=5) ---- */
__global__ __launch_bounds__(256) void k_fused1(const int* __restrict__ rowst,
                                                const int* __restrict__ csr_src,
                                                const int* __restrict__ csr_eid,
                                                const bf16* __restrict__ H0b,
                                                const float* __restrict__ ALS1,
                                                const float* __restrict__ ALD1,
                                                bf16* __restrict__ AGG1b,
                                                float* __restrict__ out_alpha) {
    __shared__ float exv[4][256];
    __shared__ int   srcs[4][64];
    int tid = threadIdx.x;
    int wv = tid >> 6;
    int wid = blockIdx.x * 4 + wv;
    int lane = tid & 63;
    int t = wid / N_NODES, n = wid % N_NODES;
    int rs = rowst[n], re = rowst[n + 1];
    int deg = re - rs;
    int tb = t * N_NODES;
    float4 ad = *(const float4*)(ALD1 + (size_t)wid * 4);
    int g = lane >> 4, il = lane & 15;
    bool do_out = (t == T_STEPS - 1);
    float acc[4][4];
#pragma unroll
    for (int hh = 0; hh < 4; hh++)
#pragma unroll
        for (int j = 0; j < 4; j++) acc[hh][j] = 0.f;
    float i0 = 1.f, i1 = 1.f, i2 = 1.f, i3 = 1.f;

    if (deg <= 64) {
        int e = rs + lane;
        bool valid = e < re;
        int src = csr_src[valid ? e : rs];
        float4 as = *(const float4*)(ALS1 + (size_t)(tb + src) * 4);
        float l0 = as.x + ad.x; l0 = l0 > 0.f ? l0 : 0.2f * l0;
        float l1 = as.y + ad.y; l1 = l1 > 0.f ? l1 : 0.2f * l1;
        float l2 = as.z + ad.z; l2 = l2 > 0.f ? l2 : 0.2f * l2;
        float l3 = as.w + ad.w; l3 = l3 > 0.f ? l3 : 0.2f * l3;
        if (!valid) { l0 = -1e30f; l1 = -1e30f; l2 = -1e30f; l3 = -1e30f; }
        float m0 = l0, m1 = l1, m2 = l2, m3 = l3;
#pragma unroll
        for (int o = 32; o; o >>= 1) {
            m0 = fmaxf(m0, __shfl_xor(m0, o, 64));
            m1 = fmaxf(m1, __shfl_xor(m1, o, 64));
            m2 = fmaxf(m2, __shfl_xor(m2, o, 64));
            m3 = fmaxf(m3, __shfl_xor(m3, o, 64));
        }
        float e0 = __expf(l0 - m0), e1 = __expf(l1 - m1);
        float e2 = __expf(l2 - m2), e3 = __expf(l3 - m3);
        float s0 = e0, s1 = e1, s2 = e2, s3 = e3;
#pragma unroll
        for (int o = 32; o; o >>= 1) {
            s0 += __shfl_xor(s0, o, 64); s1 += __shfl_xor(s1, o, 64);
            s2 += __shfl_xor(s2, o, 64); s3 += __shfl_xor(s3, o, 64);
        }
        i0 = 1.f / (s0 + 1e-16f); i1 = 1.f / (s1 + 1e-16f);
        i2 = 1.f / (s2 + 1e-16f); i3 = 1.f / (s3 + 1e-16f);
        float4 ex4; ex4.x = e0; ex4.y = e1; ex4.z = e2; ex4.w = e3;
        *(float4*)&exv[wv][lane * 4] = ex4;
        srcs[wv][lane] = src;
        lds_fence();
        for (int k = g; k < deg; k += 4) {
            float4 ex = *(const float4*)&exv[wv][k * 4];
            int s2_ = srcs[wv][k];
            ushort4 u = *(const ushort4*)(H0b + (size_t)(tb + s2_) * 64 + il * 4);
            float x0 = bfu(u.x), x1 = bfu(u.y), x2 = bfu(u.z), x3 = bfu(u.w);
            acc[0][0] += ex.x * x0; acc[0][1] += ex.x * x1; acc[0][2] += ex.x * x2; acc[0][3] += ex.x * x3;
            acc[1][0] += ex.y * x0; acc[1][1] += ex.y * x1; acc[1][2] += ex.y * x2; acc[1][3] += ex.y * x3;
            acc[2][0] += ex.z * x0; acc[2][1] += ex.z * x1; acc[2][2] += ex.z * x2; acc[2][3] += ex.z * x3;
            acc[3][0] += ex.w * x0; acc[3][1] += ex.w * x1; acc[3][2] += ex.w * x2; acc[3][3] += ex.w * x3;
        }
        if (do_out && valid) {
            int eid = csr_eid[e];
            float4 o4; o4.x = e0 * i0; o4.y = e1 * i1; o4.z = e2 * i2; o4.w = e3 * i3;
            *(float4*)(out_alpha + (size_t)eid * 4) = o4;
        }
    } else {
        /* general path: old 3-sweep recompute */
        float m0 = -1e30f, m1 = -1e30f, m2 = -1e30f, m3 = -1e30f;
        for (int e = rs + lane; e < re; e += 64) {
            int src = csr_src[e];
            float4 as = *(const float4*)(ALS1 + (size_t)(tb + src) * 4);
            float l0 = as.x + ad.x; l0 = l0 > 0.f ? l0 : 0.2f * l0; m0 = fmaxf(m0, l0);
            float l1 = as.y + ad.y; l1 = l1 > 0.f ? l1 : 0.2f * l1; m1 = fmaxf(m1, l1);
            float l2 = as.z + ad.z; l2 = l2 > 0.f ? l2 : 0.2f * l2; m2 = fmaxf(m2, l2);
            float l3 = as.w + ad.w; l3 = l3 > 0.f ? l3 : 0.2f * l3; m3 = fmaxf(m3, l3);
        }
#pragma unroll
        for (int o = 32; o; o >>= 1) {
            m0 = fmaxf(m0, __shfl_xor(m0, o, 64));
            m1 = fmaxf(m1, __shfl_xor(m1, o, 64));
            m2 = fmaxf(m2, __shfl_xor(m2, o, 64));
            m3 = fmaxf(m3, __shfl_xor(m3, o, 64));
        }
        float s0 = 0.f, s1 = 0.f, s2 = 0.f, s3 = 0.f;
        for (int e = rs + lane; e < re; e += 64) {
            int src = csr_src[e];
            float4 as = *(const float4*)(ALS1 + (size_t)(tb + src) * 4);
            float l0 = as.x + ad.x; l0 = l0 > 0.f ? l0 : 0.2f * l0; s0 += __expf(l0 - m0);
            float l1 = as.y + ad.y; l1 = l1 > 0.f ? l1 : 0.2f * l1; s1 += __expf(l1 - m1);
            float l2 = as.z + ad.z; l2 = l2 > 0.f ? l2 : 0.2f * l2; s2 += __expf(l2 - m2);
            float l3 = as.w + ad.w; l3 = l3 > 0.f ? l3 : 0.2f * l3; s3 += __expf(l3 - m3);
        }
#pragma unroll
        for (int o = 32; o; o >>= 1) {
            s0 += __shfl_xor(s0, o, 64); s1 += __shfl_xor(s1, o, 64);
            s2 += __shfl_xor(s2, o, 64); s3 += __shfl_xor(s3, o, 64);
        }
        float j0 = 1.f / (s0 + 1e-16f), j1 = 1.f / (s1 + 1e-16f);
        float j2 = 1.f / (s2 + 1e-16f), j3 = 1.f / (s3 + 1e-16f);
        for (int e0_ = rs; e0_ < re; e0_ += 4) {
            int e = e0_ + g;
            if (e < re) {
                int src = csr_src[e];
                float4 as = *(const float4*)(ALS1 + (size_t)(tb + src) * 4);
                float l0 = as.x + ad.x; l0 = l0 > 0.f ? l0 : 0.2f * l0;
                float l1 = as.y + ad.y; l1 = l1 > 0.f ? l1 : 0.2f * l1;
                float l2 = as.z + ad.z; l2 = l2 > 0.f ? l2 : 0.2f * l2;
                float l3 = as.w + ad.w; l3 = l3 > 0.f ? l3 : 0.2f * l3;
                float al0 = __expf(l0 - m0) * j0;
                float al1 = __expf(l1 - m1) * j1;
                float al2 = __expf(l2 - m2) * j2;
                float al3 = __expf(l3 - m3) * j3;
                if (do_out && il == 0) {
                    int eid = csr_eid[e];
                    float4 o4; o4.x = al0; o4.y = al1; o4.z = al2; o4.w = al3;
                    *(float4*)(out_alpha + (size_t)eid * 4) = o4;
                }
                ushort4 u = *(const ushort4*)(H0b + (size_t)(tb + src) * 64 + il * 4);
                float x0 = bfu(u.x), x1 = bfu(u.y), x2 = bfu(u.z), x3 = bfu(u.w);
                acc[0][0] += al0 * x0; acc[0][1] += al0 * x1; acc[0][2] += al0 * x2; acc[0][3] += al0 * x3;
                acc[1][0] += al1 * x0; acc[1][1] += al1 * x1; acc[1][2] += al1 * x2; acc[1][3] += al1 * x3;
                acc[2][0] += al2 * x0; acc[2][1] += al2 * x1; acc[2][2] += al2 * x2; acc[2][3] += al2 * x3;
                acc[3][0] += al3 * x0; acc[3][1] += al3 * x1; acc[3][2] += al3 * x2; acc[3][3] += al3 * x3;
            }
        }
        i0 = i1 = i2 = i3 = 1.f;
    }
    /* scale by inverse sums, reduce across groups, write */
    {
        float iv[4] = { i0, i1, i2, i3 };
#pragma unroll
        for (int hh = 0; hh < 4; hh++)
#pragma unroll
            for (int j = 0; j < 4; j++) acc[hh][j] *= iv[hh];
    }
#pragma unroll
    for (int o = 16; o <= 32; o <<= 1)
#pragma unroll
        for (int hh = 0; hh < 4; hh++)
#pragma unroll
            for (int j = 0; j < 4; j++)
                acc[hh][j] += __shfl_xor(acc[hh][j], o, 64);
    if (g == 0) {
        int cb = il * 4;
        size_t ob = (size_t)wid * 256 + cb;
#pragma unroll
        for (int hh = 0; hh < 4; hh++) {
            ushort4 o4;
            o4.x = f2bu(acc[hh][0]); o4.y = f2bu(acc[hh][1]);
            o4.z = f2bu(acc[hh][2]); o4.w = f2bu(acc[hh][3]);
            *(ushort4*)(AGG1b + ob + hh * 64) = o4;
        }
    }
}

/* epilogue GEMM: HSb[row,c] = bf16(LN(ELU(0.25 * AGG[row,:]@Wbig[:,c] + b1))). */
__global__ __launch_bounds__(256) void k_post1(const bf16* __restrict__ AGG1b,
                                               const float* __restrict__ W1,
                                               const float* __restrict__ b1,
                                               const float* __restrict__ ln_g,
                                               const float* __restrict__ ln_b,
                                               bf16* __restrict__ HSb) {
    __shared__ float xs[16][256];
    __shared__ float part[16][4][64];
    int tid = threadIdx.x;
    int q = tid >> 6, c = tid & 63;
    float wq[64];
#pragma unroll
    for (int k = 0; k < 64; k++) wq[k] = W1[k * 256 + q * 64 + c];
    int rbase = blockIdx.x * 16;
    const unsigned* agu = (const unsigned*)(AGG1b + (size_t)rbase * 256);
    for (int i = tid; i < 2048; i += 256) {
        unsigned u = agu[i];
        int r = i >> 7, base = (i & 127) * 2;
        xs[r][base + 0] = __uint_as_float(u << 16);
        xs[r][base + 1] = __uint_as_float(u & 0xffff0000u);
    }
    __syncthreads();
    for (int r = 0; r < 16; r++) {
        const float* xr = &xs[r][q * 64];
        float acc = 0.f;
#pragma unroll
        for (int kk = 0; kk < 16; kk++) {
            float4 xv = *(const float4*)(xr + kk * 4);
            acc += xv.x * wq[kk * 4 + 0] + xv.y * wq[kk * 4 + 1]
                 + xv.z * wq[kk * 4 + 2] + xv.w * wq[kk * 4 + 3];
        }
        part[r][q][c] = acc;
    }
    __syncthreads();
    float b1c = b1[c], gg = ln_g[c], bb = ln_b[c];
    for (int rr = 0; rr < 4; rr++) {
        int r = q * 4 + rr;
        float v = (part[r][0][c] + part[r][1][c] + part[r][2][c] + part[r][3][c]) * 0.25f + b1c;
        v = v > 0.f ? v : (__expf(v) - 1.f);
        float s = v;
#pragma unroll
        for (int o = 32; o; o >>= 1) s += __shfl_xor(s, o, 64);
        float mu = s * (1.f / 64.f);
        float d = v - mu;
        float qd = d * d;
#pragma unroll
        for (int o = 32; o; o >>= 1) qd += __shfl_xor(qd, o, 64);
        float var = qd * (1.f / 64.f);
        bf16 ob = __float2bfloat16(d * rsqrtf(var + 1e-5f) * gg + bb);
        HSb[(size_t)(rbase + r) * 64 + c] = ob;
    }
}

/* ---------------- GRU ---------------- */

__global__ void k_zero(float* p, int nelem) {
    int i = blockIdx.x * blockDim.x + threadIdx.x;
    if (i < nelem) p[i] = 0.f;
}

__global__ __launch_bounds__(192) void k_gi(const bf16* __restrict__ HSb,
                                            const float* __restrict__ W_ih,
                                            const float* __restrict__ b_ih,
                                            bf16* __restrict__ GIb) {
    __shared__ float xs[48][64];
    int j = threadIdx.x;
    float wi[64];
    const float4* wi4 = (const float4*)(W_ih) + (size_t)j * 16;
#pragma unroll
    for (int q = 0; q < 16; q++) {
        float4 a = wi4[q];
        wi[q * 4 + 0] = a.x; wi[q * 4 + 1] = a.y; wi[q * 4 + 2] = a.z; wi[q * 4 + 3] = a.w;
    }
    float bi = b_ih[j];
    int rbase = blockIdx.x * 48;
    const unsigned* hu = (const unsigned*)(HSb + (size_t)rbase * 64);
    for (int i = j; i < 1536; i += 192) {
        unsigned u = hu[i];
        int r = i >> 5, cb = (i & 31) * 2;
        xs[r][cb + 0] = __uint_as_float(u << 16);
        xs[r][cb + 1] = __uint_as_float(u & 0xffff0000u);
    }
    __syncthreads();
    for (int r = 0; r < 48; r++) {
        float a0 = 0.f, a1 = 0.f, a2 = 0.f, a3 = 0.f;
#pragma unroll
        for (int kk = 0; kk < 16; kk++) {
            float4 xv = *(const float4*)(&xs[r][kk * 4]);
            a0 += xv.x * wi[kk * 4 + 0]; a1 += xv.y * wi[kk * 4 + 1];
            a2 += xv.z * wi[kk * 4 + 2]; a3 += xv.w * wi[kk * 4 + 3];
        }
        GIb[(size_t)(rbase + r) * 192 + j] = __float2bfloat16(bi + a0 + a1 + a2 + a3);
    }
}

__global__ __launch_bounds__(192) void k_gru_step(int t,
                                                  const bf16* __restrict__ GIb,
                                                  const float* __restrict__ W_hh,
                                                  const float* __restrict__ b_hh,
                                                  const float* __restrict__ Hprev,
                                                  float* __restrict__ Hnew) {
    __shared__ float hsv[20][64];
    __shared__ float ghs[20][192];
    int j = threadIdx.x;
    float wh[64];
    const float4* wh4 = (const float4*)(W_hh) + (size_t)j * 16;
#pragma unroll
    for (int q = 0; q < 16; q++) {
        float4 b = wh4[q];
        wh[q * 4 + 0] = b.x; wh[q * 4 + 1] = b.y; wh[q * 4 + 2] = b.z; wh[q * 4 + 3] = b.w;
    }
    float bh = b_hh[j];
    int nb = blockIdx.x * 20;
    for (int i = j; i < 1280; i += 192) hsv[i >> 6][i & 63] = Hprev[(size_t)nb * 64 + i];
    __syncthreads();
    for (int r = 0; r < 20; r++) {
        float a0 = 0.f, a1 = 0.f, a2 = 0.f, a3 = 0.f;
#pragma unroll
        for (int kk = 0; kk < 16; kk++) {
            float4 xv = *(const float4*)(&hsv[r][kk * 4]);
            a0 += xv.x * wh[kk * 4 + 0]; a1 += xv.y * wh[kk * 4 + 1];
            a2 += xv.z * wh[kk * 4 + 2]; a3 += xv.w * wh[kk * 4 + 3];
        }
        ghs[r][j] = bh + a0 + a1 + a2 + a3;
    }
    __syncthreads();
    const bf16* gib = GIb + ((size_t)t * N_NODES + nb) * 192;
    for (int i = j; i < 1280; i += 192) {
        int r = i >> 6, c = i & 63;
        float gir = b2f(gib[(size_t)r * 192 + c]);
        float giz = b2f(gib[(size_t)r * 192 + 64 + c]);
        float gig = b2f(gib[(size_t)r * 192 + 128 + c]);
        float rr_ = 1.f / (1.f + __expf(-(gir + ghs[r][c])));
        float z   = 1.f / (1.f + __expf(-(giz + ghs[r][64 + c])));
        float g   = tanhf(gig + rr_ * ghs[r][128 + c]);
        Hnew[(size_t)nb * 64 + i] = (1.f - z) * g + z * hsv[r][c];
    }
}

/* ---------------- output writer (fp32) ---------------- */

__global__ void k_out_ei(const int* __restrict__ ei, float* __restrict__ out) {
    int i = blockIdx.x * blockDim.x + threadIdx.x;
    if (i >= 2 * EP) return;
    int v;
    if (i < EP) {
        v = (i < E_EDGES) ? ei[i] : (i - E_EDGES);                 // src row
    } else {
        int jj = i - EP;
        v = (jj < E_EDGES) ? ei[E_EDGES + jj] : (jj - E_EDGES);    // dst row
    }
    out[i] = (float)v;
}

/* ---------------- launch ---------------- */

extern "C" void kernel_launch(void* const* d_in, const int* in_sizes, int n_in,
                              void* d_out, int out_size, void* d_ws, size_t ws_size,
                              hipStream_t stream) {
    const float* x      = (const float*)d_in[0];
    const int*   ei     = (const int*)d_in[1];
    const float* W0     = (const float*)d_in[2];
    const float* a_src0 = (const float*)d_in[3];
    const float* a_dst0 = (const float*)d_in[4];
    const float* b0     = (const float*)d_in[5];
    const float* W1     = (const float*)d_in[6];
    const float* a_src1 = (const float*)d_in[7];
    const float* a_dst1 = (const float*)d_in[8];
    const float* b1     = (const float*)d_in[9];
    const float* ln_g   = (const float*)d_in[10];
    const float* ln_b   = (const float*)d_in[11];
    const float* W_ih   = (const float*)d_in[12];
    const float* W_hh   = (const float*)d_in[13];
    const float* b_ih   = (const float*)d_in[14];
    const float* b_hh   = (const float*)d_in[15];
    float* out = (float*)d_out;

    char* w = (char*)d_ws;
    size_t off = 0;
    auto take = [&](size_t bytes) -> void* {
        void* p = w + off;
        off = (off + bytes + 255) & ~(size_t)255;
        return p;
    };
    int*   counts  = (int*)take(N_NODES * 4);
    int*   fill    = (int*)take(N_NODES * 4);
    int*   rowst   = (int*)take((N_NODES + 1) * 4);
    int*   csr_src = (int*)take((size_t)EP * 4);
    int*   csr_eid = (int*)take((size_t)EP * 4);
    bf16*  XW0b    = (bf16*)take((size_t)TN * 64 * 2);
    float* ALS0    = (float*)take((size_t)TN * 4 * 4);
    float* ALD0    = (float*)take((size_t)TN * 4 * 4);
    bf16*  H0b     = (bf16*)take((size_t)TN * 64 * 2);
    float* P1s     = (float*)take(256 * 4);
    float* P1d     = (float*)take(256 * 4);
    float* ALS1    = (float*)take((size_t)TN * 4 * 4);
    float* ALD1    = (float*)take((size_t)TN * 4 * 4);
    bf16*  AGG1b   = (bf16*)take((size_t)TN * 256 * 2);
    bf16*  HSb     = (bf16*)take((size_t)TN * 64 * 2);
    bf16*  GIb     = (bf16*)take((size_t)TN * 192 * 2);
    float* HA      = (float*)take((size_t)N_NODES * 64 * 4);
    float* HB      = (float*)take((size_t)N_NODES * 64 * 4);
    (void)ws_size; (void)in_sizes; (void)n_in; (void)out_size;

    const int B = 256;
    /* CSR build + prep */
    k_init<<<(N_NODES + B - 1) / B, B, 0, stream>>>(counts, fill);
    k_count<<<(EP + B - 1) / B, B, 0, stream>>>(ei, counts);
    k_scan<<<1, 1024, 0, stream>>>(counts, rowst);
    k_scatter<<<(EP + B - 1) / B, B, 0, stream>>>(ei, rowst, fill, csr_src, csr_eid);
    k_prep1<<<1, B, 0, stream>>>(W1, a_src1, a_dst1, P1s, P1d);

    /* GAT layer 0 */
    k_gemm0<<<TN / 16, B, 0, stream>>>(x, W0, a_src0, a_dst0, XW0b, ALS0, ALD0);
    k_fused0<<<TN / 4, B, 0, stream>>>(rowst, csr_src, XW0b, ALS0, ALD0, b0,
                                       P1s, P1d, H0b, ALS1, ALD1);

    /* GAT layer 1 */
    k_fused1<<<TN / 4, B, 0, stream>>>(rowst, csr_src, csr_eid, H0b, ALS1, ALD1,
                                       AGG1b, out + (size_t)N_NODES * HID);
    k_post1<<<TN / 16, B, 0, stream>>>(AGG1b, W1, b1, ln_g, ln_b, HSb);

    /* GRU: non-recurrent half batched, then 6 light sequential steps */
    k_gi<<<TN / 48, 192, 0, stream>>>(HSb, W_ih, b_ih, GIb);
    k_zero<<<(N_NODES * 64 + B - 1) / B, B, 0, stream>>>(HA, N_NODES * 64);
    float* hbuf[2] = { HA, HB };
    for (int t = 0; t < T_STEPS; t++) {
        float* prev = hbuf[t & 1];
        float* next = (t == T_STEPS - 1) ? out : hbuf[1 - (t & 1)];
        k_gru_step<<<N_NODES / 20, 192, 0, stream>>>(t, GIb, W_hh, b_hh, prev, next);
    }

    /* edge-index output */
    k_out_ei<<<(2 * EP + B - 1) / B, B, 0, stream>>>(ei, out + (size_t)N_NODES * HID + (size_t)EP * HEADS);
}

// Round 10
// 411.462 us; speedup vs baseline: 3.0342x; 1.2541x over previous
//
#include <hip/hip_runtime.h>
#include <hip/hip_bf16.h>
#include <cstdint>
#include <cstddef>

#define N_NODES 10000
#define T_STEPS 6
#define F_IN    64
#define HID     64
#define HEADS   4
#define E_EDGES 160000
#define EP      (E_EDGES + N_NODES)   /* 170000 edges incl self-loops */
#define TN      (T_STEPS * N_NODES)   /* 60000 */

typedef __hip_bfloat16 bf16;
typedef __attribute__((ext_vector_type(8))) short short8;
typedef __attribute__((ext_vector_type(4))) float floatx4;

__device__ __forceinline__ float b2f(bf16 v) { return __bfloat162float(v); }
__device__ __forceinline__ float bfu(unsigned short s) { return __uint_as_float((unsigned)s << 16); }
__device__ __forceinline__ unsigned short f2bu(float f) {
    bf16 b = __float2bfloat16(f);
    return *(unsigned short*)&b;
}
__device__ __forceinline__ float sel4(float4 v, int h) {
    float r = v.x;
    r = (h == 1) ? v.y : r;
    r = (h == 2) ? v.z : r;
    r = (h == 3) ? v.w : r;
    return r;
}
__device__ __forceinline__ void lds_fence() {
    asm volatile("s_waitcnt lgkmcnt(0)" ::: "memory");
}

/* ---------------- CSR build ---------------- */

__global__ void k_init(int* counts, int* fill) {
    int i = blockIdx.x * blockDim.x + threadIdx.x;
    if (i < N_NODES) { counts[i] = 0; fill[i] = 0; }
}

__global__ void k_count(const int* ei, int* counts) {
    int e = blockIdx.x * blockDim.x + threadIdx.x;
    if (e >= EP) return;
    int dst = (e < E_EDGES) ? ei[E_EDGES + e] : (e - E_EDGES);
    atomicAdd(&counts[dst], 1);
}

__global__ void k_scan(const int* counts, int* rowstart) {
    __shared__ int part[1024];
    int tid = threadIdx.x;
    const int chunk = (N_NODES + 1023) / 1024;  // 10
    int base = tid * chunk;
    int s = 0;
    for (int i = 0; i < chunk; i++) { int idx = base + i; if (idx < N_NODES) s += counts[idx]; }
    part[tid] = s;
    __syncthreads();
    for (int off = 1; off < 1024; off <<= 1) {
        int v = (tid >= off) ? part[tid - off] : 0;
        __syncthreads();
        part[tid] += v;
        __syncthreads();
    }
    int run = (tid == 0) ? 0 : part[tid - 1];
    for (int i = 0; i < chunk; i++) {
        int idx = base + i;
        if (idx < N_NODES) { rowstart[idx] = run; run += counts[idx]; }
    }
    if (tid == 0) rowstart[N_NODES] = EP;
}

__global__ void k_scatter(const int* ei, const int* rowstart, int* fill,
                          int* csr_src, int* csr_eid) {
    int e = blockIdx.x * blockDim.x + threadIdx.x;
    if (e >= EP) return;
    int src = (e < E_EDGES) ? ei[e] : (e - E_EDGES);
    int dst = (e < E_EDGES) ? ei[E_EDGES + e] : (e - E_EDGES);
    int pos = rowstart[dst] + atomicAdd(&fill[dst], 1);
    csr_src[pos] = src;
    csr_eid[pos] = e;
}

/* ---------------- prep: P-matrices for layer-1 logits ---------------- */

__global__ __launch_bounds__(256) void k_prep1(const float* __restrict__ W1,
                                               const float* __restrict__ a_src1,
                                               const float* __restrict__ a_dst1,
                                               float* __restrict__ P1s,
                                               float* __restrict__ P1d) {
    int tid = threadIdx.x;
    int h = tid >> 6, k = tid & 63;
    float ps = 0.f, pd = 0.f;
    for (int c = 0; c < 64; c++) {
        float wv = W1[k * 256 + h * 64 + c];
        ps += wv * a_src1[h * 64 + c];
        pd += wv * a_dst1[h * 64 + c];
    }
    P1s[h * 64 + k] = ps;
    P1d[h * 64 + k] = pd;
}

/* ---------------- GAT layer 0 GEMM ---------------- */

__global__ __launch_bounds__(256) void k_gemm0(const float* __restrict__ x,
                                               const float* __restrict__ W0,
                                               const float* __restrict__ a_src0,
                                               const float* __restrict__ a_dst0,
                                               bf16* __restrict__ XW0b,
                                               float* __restrict__ ALS0,
                                               float* __restrict__ ALD0) {
    __shared__ float wl[64 * 64];
    __shared__ float xl[16][64];
    int tid = threadIdx.x;
    for (int i = tid; i < 4096; i += 256) wl[i] = W0[i];
    int rbase = blockIdx.x * 16;
    for (int i = tid; i < 1024; i += 256) {
        int r = i >> 6, c = i & 63;
        int row = rbase + r;
        int t = row / N_NODES, n = row % N_NODES;
        xl[r][c] = x[(size_t)(n * T_STEPS + t) * F_IN + c];  // x is [N,T,F]
    }
    __syncthreads();
    int w = tid >> 6, c = tid & 63;
    int h = c >> 4, cc = c & 15;
    float as0 = a_src0[h * 16 + cc], ad0 = a_dst0[h * 16 + cc];
    for (int rr = 0; rr < 4; rr++) {
        int r = w * 4 + rr;
        int row = rbase + r;
        float acc = 0.f;
#pragma unroll
        for (int k = 0; k < 64; k++) acc += xl[r][k] * wl[k * 64 + c];
        XW0b[(size_t)row * 64 + c] = __float2bfloat16(acc);
        float ps = acc * as0, pd = acc * ad0;
#pragma unroll
        for (int o = 8; o; o >>= 1) { ps += __shfl_xor(ps, o, 64); pd += __shfl_xor(pd, o, 64); }
        if (cc == 0) { ALS0[row * 4 + h] = ps; ALD0[row * 4 + h] = pd; }
    }
}

/* ---------------- fused layer-0: softmax + accumulate + logits1 ---------- */
__global__ __launch_bounds__(256) void k_fused0(const int* __restrict__ rowst,
                                                const int* __restrict__ csr_src,
                                                const bf16* __restrict__ XW0b,
                                                const float* __restrict__ ALS0,
                                                const float* __restrict__ ALD0,
                                                const float* __restrict__ b0,
                                                const float* __restrict__ P1s,
                                                const float* __restrict__ P1d,
                                                bf16* __restrict__ H0b,
                                                float* __restrict__ ALS1,
                                                float* __restrict__ ALD1) {
    __shared__ float p1s_l[256], p1d_l[256];
    __shared__ float exv[4][256];
    __shared__ int   srcs[4][64];
    int tid = threadIdx.x;
    p1s_l[tid] = P1s[tid];
    p1d_l[tid] = P1d[tid];
    __syncthreads();
    int wv = tid >> 6;
    int wid = blockIdx.x * 4 + wv;
    int lane = tid & 63;
    int t = wid / N_NODES, n = wid % N_NODES;
    int rs = rowst[n], re = rowst[n + 1];
    int deg = re - rs;
    int tb = t * N_NODES;
    float4 ad = *(const float4*)(ALD0 + (size_t)wid * 4);
    int g = lane >> 4, il = lane & 15;
    int h = il >> 2;
    float a0 = 0.f, a1 = 0.f, a2 = 0.f, a3 = 0.f;
    float scale_h = 1.f;

    if (deg <= 64) {
        int e = rs + lane;
        bool valid = e < re;
        int src = csr_src[valid ? e : rs];
        float4 as = *(const float4*)(ALS0 + (size_t)(tb + src) * 4);
        float l0 = as.x + ad.x; l0 = l0 > 0.f ? l0 : 0.2f * l0;
        float l1 = as.y + ad.y; l1 = l1 > 0.f ? l1 : 0.2f * l1;
        float l2 = as.z + ad.z; l2 = l2 > 0.f ? l2 : 0.2f * l2;
        float l3 = as.w + ad.w; l3 = l3 > 0.f ? l3 : 0.2f * l3;
        if (!valid) { l0 = -1e30f; l1 = -1e30f; l2 = -1e30f; l3 = -1e30f; }
        float m0 = l0, m1 = l1, m2 = l2, m3 = l3;
#pragma unroll
        for (int o = 32; o; o >>= 1) {
            m0 = fmaxf(m0, __shfl_xor(m0, o, 64));
            m1 = fmaxf(m1, __shfl_xor(m1, o, 64));
            m2 = fmaxf(m2, __shfl_xor(m2, o, 64));
            m3 = fmaxf(m3, __shfl_xor(m3, o, 64));
        }
        float e0 = __expf(l0 - m0), e1 = __expf(l1 - m1);
        float e2 = __expf(l2 - m2), e3 = __expf(l3 - m3);
        float s0 = e0, s1 = e1, s2 = e2, s3 = e3;
#pragma unroll
        for (int o = 32; o; o >>= 1) {
            s0 += __shfl_xor(s0, o, 64); s1 += __shfl_xor(s1, o, 64);
            s2 += __shfl_xor(s2, o, 64); s3 += __shfl_xor(s3, o, 64);
        }
        float i0 = 1.f / (s0 + 1e-16f), i1 = 1.f / (s1 + 1e-16f);
        float i2 = 1.f / (s2 + 1e-16f), i3 = 1.f / (s3 + 1e-16f);
        float4 ex4; ex4.x = e0; ex4.y = e1; ex4.z = e2; ex4.w = e3;
        *(float4*)&exv[wv][lane * 4] = ex4;
        srcs[wv][lane] = src;
        lds_fence();
        for (int k = g; k < deg; k += 4) {
            float aex = exv[wv][k * 4 + h];
            int s2_ = srcs[wv][k];
            ushort4 u = *(const ushort4*)(XW0b + (size_t)(tb + s2_) * 64 + il * 4);
            a0 += aex * bfu(u.x); a1 += aex * bfu(u.y);
            a2 += aex * bfu(u.z); a3 += aex * bfu(u.w);
        }
        scale_h = (h == 0) ? i0 : (h == 1) ? i1 : (h == 2) ? i2 : i3;
    } else {
        float m0 = -1e30f, m1 = -1e30f, m2 = -1e30f, m3 = -1e30f;
        for (int e = rs + lane; e < re; e += 64) {
            int src = csr_src[e];
            float4 as = *(const float4*)(ALS0 + (size_t)(tb + src) * 4);
            float l0 = as.x + ad.x; l0 = l0 > 0.f ? l0 : 0.2f * l0; m0 = fmaxf(m0, l0);
            float l1 = as.y + ad.y; l1 = l1 > 0.f ? l1 : 0.2f * l1; m1 = fmaxf(m1, l1);
            float l2 = as.z + ad.z; l2 = l2 > 0.f ? l2 : 0.2f * l2; m2 = fmaxf(m2, l2);
            float l3 = as.w + ad.w; l3 = l3 > 0.f ? l3 : 0.2f * l3; m3 = fmaxf(m3, l3);
        }
#pragma unroll
        for (int o = 32; o; o >>= 1) {
            m0 = fmaxf(m0, __shfl_xor(m0, o, 64));
            m1 = fmaxf(m1, __shfl_xor(m1, o, 64));
            m2 = fmaxf(m2, __shfl_xor(m2, o, 64));
            m3 = fmaxf(m3, __shfl_xor(m3, o, 64));
        }
        float s0 = 0.f, s1 = 0.f, s2 = 0.f, s3 = 0.f;
        for (int e = rs + lane; e < re; e += 64) {
            int src = csr_src[e];
            float4 as = *(const float4*)(ALS0 + (size_t)(tb + src) * 4);
            float l0 = as.x + ad.x; l0 = l0 > 0.f ? l0 : 0.2f * l0; s0 += __expf(l0 - m0);
            float l1 = as.y + ad.y; l1 = l1 > 0.f ? l1 : 0.2f * l1; s1 += __expf(l1 - m1);
            float l2 = as.z + ad.z; l2 = l2 > 0.f ? l2 : 0.2f * l2; s2 += __expf(l2 - m2);
            float l3 = as.w + ad.w; l3 = l3 > 0.f ? l3 : 0.2f * l3; s3 += __expf(l3 - m3);
        }
#pragma unroll
        for (int o = 32; o; o >>= 1) {
            s0 += __shfl_xor(s0, o, 64); s1 += __shfl_xor(s1, o, 64);
            s2 += __shfl_xor(s2, o, 64); s3 += __shfl_xor(s3, o, 64);
        }
        float i0 = 1.f / (s0 + 1e-16f), i1 = 1.f / (s1 + 1e-16f);
        float i2 = 1.f / (s2 + 1e-16f), i3 = 1.f / (s3 + 1e-16f);
        float mh = (h == 0) ? m0 : (h == 1) ? m1 : (h == 2) ? m2 : m3;
        float ih = (h == 0) ? i0 : (h == 1) ? i1 : (h == 2) ? i2 : i3;
        float adh = sel4(ad, h);
        for (int e0_ = rs; e0_ < re; e0_ += 4) {
            int e = e0_ + g;
            if (e < re) {
                int src = csr_src[e];
                float4 as = *(const float4*)(ALS0 + (size_t)(tb + src) * 4);
                float l = sel4(as, h) + adh; l = l > 0.f ? l : 0.2f * l;
                float a = __expf(l - mh) * ih;
                ushort4 u = *(const ushort4*)(XW0b + (size_t)(tb + src) * 64 + il * 4);
                a0 += a * bfu(u.x); a1 += a * bfu(u.y);
                a2 += a * bfu(u.z); a3 += a * bfu(u.w);
            }
        }
        scale_h = 1.f;
    }
#pragma unroll
    for (int o = 16; o <= 32; o <<= 1) {
        a0 += __shfl_xor(a0, o, 64); a1 += __shfl_xor(a1, o, 64);
        a2 += __shfl_xor(a2, o, 64); a3 += __shfl_xor(a3, o, 64);
    }
    int cb = il * 4;
    float v0 = a0 * scale_h + b0[cb + 0]; v0 = v0 > 0.f ? v0 : (__expf(v0) - 1.f);
    float v1 = a1 * scale_h + b0[cb + 1]; v1 = v1 > 0.f ? v1 : (__expf(v1) - 1.f);
    float v2 = a2 * scale_h + b0[cb + 2]; v2 = v2 > 0.f ? v2 : (__expf(v2) - 1.f);
    float v3 = a3 * scale_h + b0[cb + 3]; v3 = v3 > 0.f ? v3 : (__expf(v3) - 1.f);
    float ps[4], pd[4];
#pragma unroll
    for (int hh = 0; hh < 4; hh++) {
        int base = hh * 64 + cb;
        ps[hh] = v0 * p1s_l[base] + v1 * p1s_l[base + 1] + v2 * p1s_l[base + 2] + v3 * p1s_l[base + 3];
        pd[hh] = v0 * p1d_l[base] + v1 * p1d_l[base + 1] + v2 * p1d_l[base + 2] + v3 * p1d_l[base + 3];
    }
#pragma unroll
    for (int o = 1; o <= 8; o <<= 1) {
#pragma unroll
        for (int hh = 0; hh < 4; hh++) {
            ps[hh] += __shfl_xor(ps[hh], o, 64);
            pd[hh] += __shfl_xor(pd[hh], o, 64);
        }
    }
    if (lane == 0) {
        float4 s4; s4.x = ps[0]; s4.y = ps[1]; s4.z = ps[2]; s4.w = ps[3];
        float4 d4; d4.x = pd[0]; d4.y = pd[1]; d4.z = pd[2]; d4.w = pd[3];
        *(float4*)(ALS1 + (size_t)wid * 4) = s4;
        *(float4*)(ALD1 + (size_t)wid * 4) = d4;
    }
    if (g == 0) {
        ushort4 o4;
        o4.x = f2bu(v0); o4.y = f2bu(v1); o4.z = f2bu(v2); o4.w = f2bu(v3);
        *(ushort4*)(H0b + (size_t)wid * 64 + cb) = o4;
    }
}

/* ---------------- fused layer-1: softmax + aggregate (+alpha out t=5) ---- */
__global__ __launch_bounds__(256) void k_fused1(const int* __restrict__ rowst,
                                                const int* __restrict__ csr_src,
                                                const int* __restrict__ csr_eid,
                                                const bf16* __restrict__ H0b,
                                                const float* __restrict__ ALS1,
                                                const float* __restrict__ ALD1,
                                                bf16* __restrict__ AGG1b,
                                                float* __restrict__ out_alpha) {
    __shared__ float exv[4][256];
    __shared__ int   srcs[4][64];
    int tid = threadIdx.x;
    int wv = tid >> 6;
    int wid = blockIdx.x * 4 + wv;
    int lane = tid & 63;
    int t = wid / N_NODES, n = wid % N_NODES;
    int rs = rowst[n], re = rowst[n + 1];
    int deg = re - rs;
    int tb = t * N_NODES;
    float4 ad = *(const float4*)(ALD1 + (size_t)wid * 4);
    int g = lane >> 4, il = lane & 15;
    bool do_out = (t == T_STEPS - 1);
    float acc[4][4];
#pragma unroll
    for (int hh = 0; hh < 4; hh++)
#pragma unroll
        for (int j = 0; j < 4; j++) acc[hh][j] = 0.f;
    float i0 = 1.f, i1 = 1.f, i2 = 1.f, i3 = 1.f;

    if (deg <= 64) {
        int e = rs + lane;
        bool valid = e < re;
        int src = csr_src[valid ? e : rs];
        float4 as = *(const float4*)(ALS1 + (size_t)(tb + src) * 4);
        float l0 = as.x + ad.x; l0 = l0 > 0.f ? l0 : 0.2f * l0;
        float l1 = as.y + ad.y; l1 = l1 > 0.f ? l1 : 0.2f * l1;
        float l2 = as.z + ad.z; l2 = l2 > 0.f ? l2 : 0.2f * l2;
        float l3 = as.w + ad.w; l3 = l3 > 0.f ? l3 : 0.2f * l3;
        if (!valid) { l0 = -1e30f; l1 = -1e30f; l2 = -1e30f; l3 = -1e30f; }
        float m0 = l0, m1 = l1, m2 = l2, m3 = l3;
#pragma unroll
        for (int o = 32; o; o >>= 1) {
            m0 = fmaxf(m0, __shfl_xor(m0, o, 64));
            m1 = fmaxf(m1, __shfl_xor(m1, o, 64));
            m2 = fmaxf(m2, __shfl_xor(m2, o, 64));
            m3 = fmaxf(m3, __shfl_xor(m3, o, 64));
        }
        float e0 = __expf(l0 - m0), e1 = __expf(l1 - m1);
        float e2 = __expf(l2 - m2), e3 = __expf(l3 - m3);
        float s0 = e0, s1 = e1, s2 = e2, s3 = e3;
#pragma unroll
        for (int o = 32; o; o >>= 1) {
            s0 += __shfl_xor(s0, o, 64); s1 += __shfl_xor(s1, o, 64);
            s2 += __shfl_xor(s2, o, 64); s3 += __shfl_xor(s3, o, 64);
        }
        i0 = 1.f / (s0 + 1e-16f); i1 = 1.f / (s1 + 1e-16f);
        i2 = 1.f / (s2 + 1e-16f); i3 = 1.f / (s3 + 1e-16f);
        float4 ex4; ex4.x = e0; ex4.y = e1; ex4.z = e2; ex4.w = e3;
        *(float4*)&exv[wv][lane * 4] = ex4;
        srcs[wv][lane] = src;
        lds_fence();
        for (int k = g; k < deg; k += 4) {
            float4 ex = *(const float4*)&exv[wv][k * 4];
            int s2_ = srcs[wv][k];
            ushort4 u = *(const ushort4*)(H0b + (size_t)(tb + s2_) * 64 + il * 4);
            float x0 = bfu(u.x), x1 = bfu(u.y), x2 = bfu(u.z), x3 = bfu(u.w);
            acc[0][0] += ex.x * x0; acc[0][1] += ex.x * x1; acc[0][2] += ex.x * x2; acc[0][3] += ex.x * x3;
            acc[1][0] += ex.y * x0; acc[1][1] += ex.y * x1; acc[1][2] += ex.y * x2; acc[1][3] += ex.y * x3;
            acc[2][0] += ex.z * x0; acc[2][1] += ex.z * x1; acc[2][2] += ex.z * x2; acc[2][3] += ex.z * x3;
            acc[3][0] += ex.w * x0; acc[3][1] += ex.w * x1; acc[3][2] += ex.w * x2; acc[3][3] += ex.w * x3;
        }
        if (do_out && valid) {
            int eid = csr_eid[e];
            float4 o4; o4.x = e0 * i0; o4.y = e1 * i1; o4.z = e2 * i2; o4.w = e3 * i3;
            *(float4*)(out_alpha + (size_t)eid * 4) = o4;
        }
    } else {
        float m0 = -1e30f, m1 = -1e30f, m2 = -1e30f, m3 = -1e30f;
        for (int e = rs + lane; e < re; e += 64) {
            int src = csr_src[e];
            float4 as = *(const float4*)(ALS1 + (size_t)(tb + src) * 4);
            float l0 = as.x + ad.x; l0 = l0 > 0.f ? l0 : 0.2f * l0; m0 = fmaxf(m0, l0);
            float l1 = as.y + ad.y; l1 = l1 > 0.f ? l1 : 0.2f * l1; m1 = fmaxf(m1, l1);
            float l2 = as.z + ad.z; l2 = l2 > 0.f ? l2 : 0.2f * l2; m2 = fmaxf(m2, l2);
            float l3 = as.w + ad.w; l3 = l3 > 0.f ? l3 : 0.2f * l3; m3 = fmaxf(m3, l3);
        }
#pragma unroll
        for (int o = 32; o; o >>= 1) {
            m0 = fmaxf(m0, __shfl_xor(m0, o, 64));
            m1 = fmaxf(m1, __shfl_xor(m1, o, 64));
            m2 = fmaxf(m2, __shfl_xor(m2, o, 64));
            m3 = fmaxf(m3, __shfl_xor(m3, o, 64));
        }
        float s0 = 0.f, s1 = 0.f, s2 = 0.f, s3 = 0.f;
        for (int e = rs + lane; e < re; e += 64) {
            int src = csr_src[e];
            float4 as = *(const float4*)(ALS1 + (size_t)(tb + src) * 4);
            float l0 = as.x + ad.x; l0 = l0 > 0.f ? l0 : 0.2f * l0; s0 += __expf(l0 - m0);
            float l1 = as.y + ad.y; l1 = l1 > 0.f ? l1 : 0.2f * l1; s1 += __expf(l1 - m1);
            float l2 = as.z + ad.z; l2 = l2 > 0.f ? l2 : 0.2f * l2; s2 += __expf(l2 - m2);
            float l3 = as.w + ad.w; l3 = l3 > 0.f ? l3 : 0.2f * l3; s3 += __expf(l3 - m3);
        }
#pragma unroll
        for (int o = 32; o; o >>= 1) {
            s0 += __shfl_xor(s0, o, 64); s1 += __shfl_xor(s1, o, 64);
            s2 += __shfl_xor(s2, o, 64); s3 += __shfl_xor(s3, o, 64);
        }
        float j0 = 1.f / (s0 + 1e-16f), j1 = 1.f / (s1 + 1e-16f);
        float j2 = 1.f / (s2 + 1e-16f), j3 = 1.f / (s3 + 1e-16f);
        for (int e0_ = rs; e0_ < re; e0_ += 4) {
            int e = e0_ + g;
            if (e < re) {
                int src = csr_src[e];
                float4 as = *(const float4*)(ALS1 + (size_t)(tb + src) * 4);
                float l0 = as.x + ad.x; l0 = l0 > 0.f ? l0 : 0.2f * l0;
                float l1 = as.y + ad.y; l1 = l1 > 0.f ? l1 : 0.2f * l1;
                float l2 = as.z + ad.z; l2 = l2 > 0.f ? l2 : 0.2f * l2;
                float l3 = as.w + ad.w; l3 = l3 > 0.f ? l3 : 0.2f * l3;
                float al0 = __expf(l0 - m0) * j0;
                float al1 = __expf(l1 - m1) * j1;
                float al2 = __expf(l2 - m2) * j2;
                float al3 = __expf(l3 - m3) * j3;
                if (do_out && il == 0) {
                    int eid = csr_eid[e];
                    float4 o4; o4.x = al0; o4.y = al1; o4.z = al2; o4.w = al3;
                    *(float4*)(out_alpha + (size_t)eid * 4) = o4;
                }
                ushort4 u = *(const ushort4*)(H0b + (size_t)(tb + src) * 64 + il * 4);
                float x0 = bfu(u.x), x1 = bfu(u.y), x2 = bfu(u.z), x3 = bfu(u.w);
                acc[0][0] += al0 * x0; acc[0][1] += al0 * x1; acc[0][2] += al0 * x2; acc[0][3] += al0 * x3;
                acc[1][0] += al1 * x0; acc[1][1] += al1 * x1; acc[1][2] += al1 * x2; acc[1][3] += al1 * x3;
                acc[2][0] += al2 * x0; acc[2][1] += al2 * x1; acc[2][2] += al2 * x2; acc[2][3] += al2 * x3;
                acc[3][0] += al3 * x0; acc[3][1] += al3 * x1; acc[3][2] += al3 * x2; acc[3][3] += al3 * x3;
            }
        }
        i0 = i1 = i2 = i3 = 1.f;
    }
    {
        float iv[4] = { i0, i1, i2, i3 };
#pragma unroll
        for (int hh = 0; hh < 4; hh++)
#pragma unroll
            for (int j = 0; j < 4; j++) acc[hh][j] *= iv[hh];
    }
#pragma unroll
    for (int o = 16; o <= 32; o <<= 1)
#pragma unroll
        for (int hh = 0; hh < 4; hh++)
#pragma unroll
            for (int j = 0; j < 4; j++)
                acc[hh][j] += __shfl_xor(acc[hh][j], o, 64);
    if (g == 0) {
        int cb = il * 4;
        size_t ob = (size_t)wid * 256 + cb;
#pragma unroll
        for (int hh = 0; hh < 4; hh++) {
            ushort4 o4;
            o4.x = f2bu(acc[hh][0]); o4.y = f2bu(acc[hh][1]);
            o4.z = f2bu(acc[hh][2]); o4.w = f2bu(acc[hh][3]);
            *(ushort4*)(AGG1b + ob + hh * 64) = o4;
        }
    }
}

/* epilogue GEMM: HSb[row,c] = bf16(LN(ELU(0.25 * AGG[row,:]@Wbig[:,c] + b1))). */
__global__ __launch_bounds__(256) void k_post1(const bf16* __restrict__ AGG1b,
                                               const float* __restrict__ W1,
                                               const float* __restrict__ b1,
                                               const float* __restrict__ ln_g,
                                               const float* __restrict__ ln_b,
                                               bf16* __restrict__ HSb) {
    __shared__ float xs[16][256];
    __shared__ float part[16][4][64];
    int tid = threadIdx.x;
    int q = tid >> 6, c = tid & 63;
    float wq[64];
#pragma unroll
    for (int k = 0; k < 64; k++) wq[k] = W1[k * 256 + q * 64 + c];
    int rbase = blockIdx.x * 16;
    const unsigned* agu = (const unsigned*)(AGG1b + (size_t)rbase * 256);
    for (int i = tid; i < 2048; i += 256) {
        unsigned u = agu[i];
        int r = i >> 7, base = (i & 127) * 2;
        xs[r][base + 0] = __uint_as_float(u << 16);
        xs[r][base + 1] = __uint_as_float(u & 0xffff0000u);
    }
    __syncthreads();
    for (int r = 0; r < 16; r++) {
        const float* xr = &xs[r][q * 64];
        float acc = 0.f;
#pragma unroll
        for (int kk = 0; kk < 16; kk++) {
            float4 xv = *(const float4*)(xr + kk * 4);
            acc += xv.x * wq[kk * 4 + 0] + xv.y * wq[kk * 4 + 1]
                 + xv.z * wq[kk * 4 + 2] + xv.w * wq[kk * 4 + 3];
        }
        part[r][q][c] = acc;
    }
    __syncthreads();
    float b1c = b1[c], gg = ln_g[c], bb = ln_b[c];
    for (int rr = 0; rr < 4; rr++) {
        int r = q * 4 + rr;
        float v = (part[r][0][c] + part[r][1][c] + part[r][2][c] + part[r][3][c]) * 0.25f + b1c;
        v = v > 0.f ? v : (__expf(v) - 1.f);
        float s = v;
#pragma unroll
        for (int o = 32; o; o >>= 1) s += __shfl_xor(s, o, 64);
        float mu = s * (1.f / 64.f);
        float d = v - mu;
        float qd = d * d;
#pragma unroll
        for (int o = 32; o; o >>= 1) qd += __shfl_xor(qd, o, 64);
        float var = qd * (1.f / 64.f);
        bf16 ob = __float2bfloat16(d * rsqrtf(var + 1e-5f) * gg + bb);
        HSb[(size_t)(rbase + r) * 64 + c] = ob;
    }
}

/* ---------------- GRU (MFMA) ---------------- */

__global__ void k_zero(float* p, int nelem) {
    int i = blockIdx.x * blockDim.x + threadIdx.x;
    if (i < nelem) p[i] = 0.f;
}

/* GI = HSb @ W_ih^T + b_ih via mfma_f32_16x16x32_bf16.
   One 16-row tile per wave; W_ih staged bf16 in LDS [j][k]; A = HSb direct.
   A-frag: lane holds A[m=lane&15][k=quad*8+j]; B-frag: B[k=quad*8+j][n=lane&15]
   = W[n][k] (row-major [j][k] = B^T layout); C/D: col=lane&15, row=quad*4+reg. */
__global__ __launch_bounds__(256) void k_gi(const bf16* __restrict__ HSb,
                                            const float* __restrict__ W_ih,
                                            const float* __restrict__ b_ih,
                                            bf16* __restrict__ GIb) {
    __shared__ __align__(16) bf16 wl[192 * 64];   /* 24 KB, [j][k] */
    int tid = threadIdx.x;
    for (int i = tid; i < 12288; i += 256) wl[i] = __float2bfloat16(W_ih[i]);
    __syncthreads();
    int wv = tid >> 6, lane = tid & 63;
    int tile = blockIdx.x * 4 + wv;
    if (tile >= TN / 16) return;
    int rb = tile * 16;
    int m = lane & 15, quad = lane >> 4;
    short8 a0 = *(const short8*)(HSb + (size_t)(rb + m) * 64 + quad * 8);
    short8 a1 = *(const short8*)(HSb + (size_t)(rb + m) * 64 + 32 + quad * 8);
#pragma unroll
    for (int ct = 0; ct < 12; ct++) {
        int cb = ct * 16;
        short8 bb0 = *(const short8*)(wl + (cb + m) * 64 + quad * 8);
        short8 bb1 = *(const short8*)(wl + (cb + m) * 64 + 32 + quad * 8);
        floatx4 acc = {0.f, 0.f, 0.f, 0.f};
        acc = __builtin_amdgcn_mfma_f32_16x16x32_bf16(a0, bb0, acc, 0, 0, 0);
        acc = __builtin_amdgcn_mfma_f32_16x16x32_bf16(a1, bb1, acc, 0, 0, 0);
        float bi = b_ih[cb + m];
#pragma unroll
        for (int r = 0; r < 4; r++)
            GIb[(size_t)(rb + quad * 4 + r) * 192 + cb + m] = __float2bfloat16(acc[r] + bi);
    }
}

/* GRU recurrent step via MFMA: gh = h@W_hh^T + b_hh, pointwise in-register.
   r/z/g gates for a (row,col) live in the same lane/reg across tiles ct, ct+4, ct+8. */
__global__ __launch_bounds__(256) void k_gru_step(int t,
                                                  const bf16* __restrict__ GIb,
                                                  const float* __restrict__ W_hh,
                                                  const float* __restrict__ b_hh,
                                                  const float* __restrict__ Hprev,
                                                  float* __restrict__ Hnew) {
    __shared__ __align__(16) bf16 wl[192 * 64];   /* 24 KB, [j][k] */
    int tid = threadIdx.x;
    for (int i = tid; i < 12288; i += 256) wl[i] = __float2bfloat16(W_hh[i]);
    __syncthreads();
    int wv = tid >> 6, lane = tid & 63;
    int tile = blockIdx.x * 4 + wv;
    if (tile >= N_NODES / 16) return;
    int rb = tile * 16;
    int m = lane & 15, quad = lane >> 4;
    const float* hrow = Hprev + (size_t)(rb + m) * 64 + quad * 8;
    short8 a0, a1;
#pragma unroll
    for (int j = 0; j < 8; j++) {
        a0[j] = (short)f2bu(hrow[j]);
        a1[j] = (short)f2bu(hrow[32 + j]);
    }
    floatx4 acc[12];
#pragma unroll
    for (int ct = 0; ct < 12; ct++) {
        int cb = ct * 16;
        short8 bb0 = *(const short8*)(wl + (cb + m) * 64 + quad * 8);
        short8 bb1 = *(const short8*)(wl + (cb + m) * 64 + 32 + quad * 8);
        floatx4 a = {0.f, 0.f, 0.f, 0.f};
        a = __builtin_amdgcn_mfma_f32_16x16x32_bf16(a0, bb0, a, 0, 0, 0);
        a = __builtin_amdgcn_mfma_f32_16x16x32_bf16(a1, bb1, a, 0, 0, 0);
        float bh = b_hh[cb + m];
#pragma unroll
        for (int r = 0; r < 4; r++) acc[ct][r] = a[r] + bh;
    }
    const bf16* gib = GIb + (size_t)t * N_NODES * 192;
#pragma unroll
    for (int ct = 0; ct < 4; ct++) {
        int c = ct * 16 + m;
#pragma unroll
        for (int r = 0; r < 4; r++) {
            int row = rb + quad * 4 + r;
            float gr = b2f(gib[(size_t)row * 192 + c]);
            float gz = b2f(gib[(size_t)row * 192 + 64 + c]);
            float gg = b2f(gib[(size_t)row * 192 + 128 + c]);
            float hp = Hprev[(size_t)row * 64 + c];
            float rr = 1.f / (1.f + __expf(-(gr + acc[ct][r])));
            float z  = 1.f / (1.f + __expf(-(gz + acc[ct + 4][r])));
            float g  = tanhf(gg + rr * acc[ct + 8][r]);
            Hnew[(size_t)row * 64 + c] = (1.f - z) * g + z * hp;
        }
    }
}

/* ---------------- output writer (fp32) ---------------- */

__global__ void k_out_ei(const int* __restrict__ ei, float* __restrict__ out) {
    int i = blockIdx.x * blockDim.x + threadIdx.x;
    if (i >= 2 * EP) return;
    int v;
    if (i < EP) {
        v = (i < E_EDGES) ? ei[i] : (i - E_EDGES);                 // src row
    } else {
        int jj = i - EP;
        v = (jj < E_EDGES) ? ei[E_EDGES + jj] : (jj - E_EDGES);    // dst row
    }
    out[i] = (float)v;
}

/* ---------------- launch ---------------- */

extern "C" void kernel_launch(void* const* d_in, const int* in_sizes, int n_in,
                              void* d_out, int out_size, void* d_ws, size_t ws_size,
                              hipStream_t stream) {
    const float* x      = (const float*)d_in[0];
    const int*   ei     = (const int*)d_in[1];
    const float* W0     = (const float*)d_in[2];
    const float* a_src0 = (const float*)d_in[3];
    const float* a_dst0 = (const float*)d_in[4];
    const float* b0     = (const float*)d_in[5];
    const float* W1     = (const float*)d_in[6];
    const float* a_src1 = (const float*)d_in[7];
    const float* a_dst1 = (const float*)d_in[8];
    const float* b1     = (const float*)d_in[9];
    const float* ln_g   = (const float*)d_in[10];
    const float* ln_b   = (const float*)d_in[11];
    const float* W_ih   = (const float*)d_in[12];
    const float* W_hh   = (const float*)d_in[13];
    const float* b_ih   = (const float*)d_in[14];
    const float* b_hh   = (const float*)d_in[15];
    float* out = (float*)d_out;

    char* w = (char*)d_ws;
    size_t off = 0;
    auto take = [&](size_t bytes) -> void* {
        void* p = w + off;
        off = (off + bytes + 255) & ~(size_t)255;
        return p;
    };
    int*   counts  = (int*)take(N_NODES * 4);
    int*   fill    = (int*)take(N_NODES * 4);
    int*   rowst   = (int*)take((N_NODES + 1) * 4);
    int*   csr_src = (int*)take((size_t)EP * 4);
    int*   csr_eid = (int*)take((size_t)EP * 4);
    bf16*  XW0b    = (bf16*)take((size_t)TN * 64 * 2);
    float* ALS0    = (float*)take((size_t)TN * 4 * 4);
    float* ALD0    = (float*)take((size_t)TN * 4 * 4);
    bf16*  H0b     = (bf16*)take((size_t)TN * 64 * 2);
    float* P1s     = (float*)take(256 * 4);
    float* P1d     = (float*)take(256 * 4);
    float* ALS1    = (float*)take((size_t)TN * 4 * 4);
    float* ALD1    = (float*)take((size_t)TN * 4 * 4);
    bf16*  AGG1b   = (bf16*)take((size_t)TN * 256 * 2);
    bf16*  HSb     = (bf16*)take((size_t)TN * 64 * 2);
    bf16*  GIb     = (bf16*)take((size_t)TN * 192 * 2);
    float* HA      = (float*)take((size_t)N_NODES * 64 * 4);
    float* HB      = (float*)take((size_t)N_NODES * 64 * 4);
    (void)ws_size; (void)in_sizes; (void)n_in; (void)out_size;

    const int B = 256;
    /* CSR build + prep */
    k_init<<<(N_NODES + B - 1) / B, B, 0, stream>>>(counts, fill);
    k_count<<<(EP + B - 1) / B, B, 0, stream>>>(ei, counts);
    k_scan<<<1, 1024, 0, stream>>>(counts, rowst);
    k_scatter<<<(EP + B - 1) / B, B, 0, stream>>>(ei, rowst, fill, csr_src, csr_eid);
    k_prep1<<<1, B, 0, stream>>>(W1, a_src1, a_dst1, P1s, P1d);

    /* GAT layer 0 */
    k_gemm0<<<TN / 16, B, 0, stream>>>(x, W0, a_src0, a_dst0, XW0b, ALS0, ALD0);
    k_fused0<<<TN / 4, B, 0, stream>>>(rowst, csr_src, XW0b, ALS0, ALD0, b0,
                                       P1s, P1d, H0b, ALS1, ALD1);

    /* GAT layer 1 */
    k_fused1<<<TN / 4, B, 0, stream>>>(rowst, csr_src, csr_eid, H0b, ALS1, ALD1,
                                       AGG1b, out + (size_t)N_NODES * HID);
    k_post1<<<TN / 16, B, 0, stream>>>(AGG1b, W1, b1, ln_g, ln_b, HSb);

    /* GRU: MFMA GI precompute + 6 MFMA recurrent steps */
    k_gi<<<(TN / 16 + 3) / 4, B, 0, stream>>>(HSb, W_ih, b_ih, GIb);
    k_zero<<<(N_NODES * 64 + B - 1) / B, B, 0, stream>>>(HA, N_NODES * 64);
    float* hbuf[2] = { HA, HB };
    for (int t = 0; t < T_STEPS; t++) {
        float* prev = hbuf[t & 1];
        float* next = (t == T_STEPS - 1) ? out : hbuf[1 - (t & 1)];
        k_gru_step<<<(N_NODES / 16 + 3) / 4, B, 0, stream>>>(t, GIb, W_hh, b_hh, prev, next);
    }

    /* edge-index output */
    k_out_ei<<<(2 * EP + B - 1) / B, B, 0, stream>>>(ei, out + (size_t)N_NODES * HID + (size_t)EP * HEADS);
}

// Round 11
// 327.198 us; speedup vs baseline: 3.8156x; 1.2575x over previous
//
#include <hip/hip_runtime.h>
#include <hip/hip_bf16.h>
#include <cstdint>
#include <cstddef>

#define N_NODES 10000
#define T_STEPS 6
#define F_IN    64
#define HID     64
#define HEADS   4
#define E_EDGES 160000
#define EP      (E_EDGES + N_NODES)   /* 170000 edges incl self-loops */
#define TN      (T_STEPS * N_NODES)   /* 60000 */
#define NTILES  (TN / 16)             /* 3750 */

typedef __hip_bfloat16 bf16;
typedef __attribute__((ext_vector_type(8))) short short8;
typedef __attribute__((ext_vector_type(4))) float floatx4;

__device__ __forceinline__ float b2f(bf16 v) { return __bfloat162float(v); }
__device__ __forceinline__ float bfu(unsigned short s) { return __uint_as_float((unsigned)s << 16); }
__device__ __forceinline__ unsigned short f2bu(float f) {
    bf16 b = __float2bfloat16(f);
    return *(unsigned short*)&b;
}
__device__ __forceinline__ float sel4(float4 v, int h) {
    float r = v.x;
    r = (h == 1) ? v.y : r;
    r = (h == 2) ? v.z : r;
    r = (h == 3) ? v.w : r;
    return r;
}
__device__ __forceinline__ void lds_fence() {
    asm volatile("s_waitcnt lgkmcnt(0)" ::: "memory");
}

/* ---------------- CSR build ---------------- */

__global__ void k_init(int* counts, int* fill) {
    int i = blockIdx.x * blockDim.x + threadIdx.x;
    if (i < N_NODES) { counts[i] = 0; fill[i] = 0; }
}

__global__ void k_count(const int* ei, int* counts) {
    int e = blockIdx.x * blockDim.x + threadIdx.x;
    if (e >= EP) return;
    int dst = (e < E_EDGES) ? ei[E_EDGES + e] : (e - E_EDGES);
    atomicAdd(&counts[dst], 1);
}

__global__ void k_scan(const int* counts, int* rowstart) {
    __shared__ int part[1024];
    int tid = threadIdx.x;
    const int chunk = (N_NODES + 1023) / 1024;  // 10
    int base = tid * chunk;
    int s = 0;
    for (int i = 0; i < chunk; i++) { int idx = base + i; if (idx < N_NODES) s += counts[idx]; }
    part[tid] = s;
    __syncthreads();
    for (int off = 1; off < 1024; off <<= 1) {
        int v = (tid >= off) ? part[tid - off] : 0;
        __syncthreads();
        part[tid] += v;
        __syncthreads();
    }
    int run = (tid == 0) ? 0 : part[tid - 1];
    for (int i = 0; i < chunk; i++) {
        int idx = base + i;
        if (idx < N_NODES) { rowstart[idx] = run; run += counts[idx]; }
    }
    if (tid == 0) rowstart[N_NODES] = EP;
}

__global__ void k_scatter(const int* ei, const int* rowstart, int* fill,
                          int* csr_src, int* csr_eid) {
    int e = blockIdx.x * blockDim.x + threadIdx.x;
    if (e >= EP) return;
    int src = (e < E_EDGES) ? ei[e] : (e - E_EDGES);
    int dst = (e < E_EDGES) ? ei[E_EDGES + e] : (e - E_EDGES);
    int pos = rowstart[dst] + atomicAdd(&fill[dst], 1);
    csr_src[pos] = src;
    csr_eid[pos] = e;
}

/* ---------------- prep: P-matrices for layer-1 logits ---------------- */

__global__ __launch_bounds__(256) void k_prep1(const float* __restrict__ W1,
                                               const float* __restrict__ a_src1,
                                               const float* __restrict__ a_dst1,
                                               float* __restrict__ P1s,
                                               float* __restrict__ P1d) {
    int tid = threadIdx.x;
    int h = tid >> 6, k = tid & 63;
    float ps = 0.f, pd = 0.f;
    for (int c = 0; c < 64; c++) {
        float wv = W1[k * 256 + h * 64 + c];
        ps += wv * a_src1[h * 64 + c];
        pd += wv * a_dst1[h * 64 + c];
    }
    P1s[h * 64 + k] = ps;
    P1d[h * 64 + k] = pd;
}

/* ---------------- GAT layer 0 GEMM (MFMA) ----------------
   XW = X @ W0 via mfma_f32_16x16x32_bf16. W0^T staged bf16 in LDS [c][k].
   Fused logits: head h == col-tile ct; butterfly within 16-lane quad. */
__global__ __launch_bounds__(256) void k_gemm0(const float* __restrict__ x,
                                               const float* __restrict__ W0,
                                               const float* __restrict__ a_src0,
                                               const float* __restrict__ a_dst0,
                                               bf16* __restrict__ XW0b,
                                               float* __restrict__ ALS0,
                                               float* __restrict__ ALD0) {
    __shared__ __align__(16) bf16 wt[64 * 64];   /* [c][k], 8 KB */
    int tid = threadIdx.x;
    for (int i = tid; i < 4096; i += 256) {
        int c = i >> 6, k = i & 63;
        wt[i] = __float2bfloat16(W0[k * 64 + c]);
    }
    __syncthreads();
    int wv = tid >> 6, lane = tid & 63;
    int tile = blockIdx.x * 4 + wv;
    if (tile >= NTILES) return;
    int rb = tile * 16;
    int m = lane & 15, quad = lane >> 4;
    int row = rb + m;
    int t = row / N_NODES, n = row - t * N_NODES;
    const float* xr = x + ((size_t)n * T_STEPS + t) * F_IN + quad * 8;
    short8 a0, a1;
#pragma unroll
    for (int j = 0; j < 8; j++) {
        a0[j] = (short)f2bu(xr[j]);
        a1[j] = (short)f2bu(xr[32 + j]);
    }
    floatx4 acc[4];
#pragma unroll
    for (int ct = 0; ct < 4; ct++) {
        short8 bb0 = *(const short8*)(wt + (ct * 16 + m) * 64 + quad * 8);
        short8 bb1 = *(const short8*)(wt + (ct * 16 + m) * 64 + 32 + quad * 8);
        floatx4 a = {0.f, 0.f, 0.f, 0.f};
        a = __builtin_amdgcn_mfma_f32_16x16x32_bf16(a0, bb0, a, 0, 0, 0);
        a = __builtin_amdgcn_mfma_f32_16x16x32_bf16(a1, bb1, a, 0, 0, 0);
        acc[ct] = a;
    }
#pragma unroll
    for (int ct = 0; ct < 4; ct++) {
        float as0 = a_src0[ct * 16 + m], ad0 = a_dst0[ct * 16 + m];
#pragma unroll
        for (int r = 0; r < 4; r++) {
            int orow = rb + quad * 4 + r;
            float v = acc[ct][r];
            XW0b[(size_t)orow * 64 + ct * 16 + m] = __float2bfloat16(v);
            float ps = v * as0, pd = v * ad0;
#pragma unroll
            for (int o = 8; o; o >>= 1) { ps += __shfl_xor(ps, o, 64); pd += __shfl_xor(pd, o, 64); }
            if (m == 0) { ALS0[orow * 4 + ct] = ps; ALD0[orow * 4 + ct] = pd; }
        }
    }
}

/* ---------------- fused layer-0: softmax + accumulate (no max-sub) ------- */
__global__ __launch_bounds__(256) void k_fused0(const int* __restrict__ rowst,
                                                const int* __restrict__ csr_src,
                                                const bf16* __restrict__ XW0b,
                                                const float* __restrict__ ALS0,
                                                const float* __restrict__ ALD0,
                                                const float* __restrict__ b0,
                                                bf16* __restrict__ H0b) {
    __shared__ float exv[4][256];
    __shared__ int   srcs[4][64];
    int tid = threadIdx.x;
    int wv = tid >> 6;
    int wid = blockIdx.x * 4 + wv;
    int lane = tid & 63;
    int t = wid / N_NODES, n = wid % N_NODES;
    int rs = rowst[n], re = rowst[n + 1];
    int deg = re - rs;
    int tb = t * N_NODES;
    float4 ad = *(const float4*)(ALD0 + (size_t)wid * 4);
    int g = lane >> 4, il = lane & 15;
    int h = il >> 2;
    float a0 = 0.f, a1 = 0.f, a2 = 0.f, a3 = 0.f;
    float scale_h;

    if (deg <= 64) {
        int e = rs + lane;
        bool valid = e < re;
        int src = csr_src[valid ? e : rs];
        float4 as = *(const float4*)(ALS0 + (size_t)(tb + src) * 4);
        float l0 = as.x + ad.x; l0 = l0 > 0.f ? l0 : 0.2f * l0; l0 = fminf(l0, 80.f);
        float l1 = as.y + ad.y; l1 = l1 > 0.f ? l1 : 0.2f * l1; l1 = fminf(l1, 80.f);
        float l2 = as.z + ad.z; l2 = l2 > 0.f ? l2 : 0.2f * l2; l2 = fminf(l2, 80.f);
        float l3 = as.w + ad.w; l3 = l3 > 0.f ? l3 : 0.2f * l3; l3 = fminf(l3, 80.f);
        float e0 = valid ? __expf(l0) : 0.f;
        float e1 = valid ? __expf(l1) : 0.f;
        float e2 = valid ? __expf(l2) : 0.f;
        float e3 = valid ? __expf(l3) : 0.f;
        float s0 = e0, s1 = e1, s2 = e2, s3 = e3;
#pragma unroll
        for (int o = 32; o; o >>= 1) {
            s0 += __shfl_xor(s0, o, 64); s1 += __shfl_xor(s1, o, 64);
            s2 += __shfl_xor(s2, o, 64); s3 += __shfl_xor(s3, o, 64);
        }
        float i0 = 1.f / (s0 + 1e-16f), i1 = 1.f / (s1 + 1e-16f);
        float i2 = 1.f / (s2 + 1e-16f), i3 = 1.f / (s3 + 1e-16f);
        float4 ex4; ex4.x = e0; ex4.y = e1; ex4.z = e2; ex4.w = e3;
        *(float4*)&exv[wv][lane * 4] = ex4;
        srcs[wv][lane] = src;
        lds_fence();
        for (int k = g; k < deg; k += 4) {
            float aex = exv[wv][k * 4 + h];
            int s2_ = srcs[wv][k];
            ushort4 u = *(const ushort4*)(XW0b + (size_t)(tb + s2_) * 64 + il * 4);
            a0 += aex * bfu(u.x); a1 += aex * bfu(u.y);
            a2 += aex * bfu(u.z); a3 += aex * bfu(u.w);
        }
        scale_h = (h == 0) ? i0 : (h == 1) ? i1 : (h == 2) ? i2 : i3;
    } else {
        /* general path: sum sweep + gather sweep (no max-sub) */
        float s0 = 0.f, s1 = 0.f, s2 = 0.f, s3 = 0.f;
        for (int e = rs + lane; e < re; e += 64) {
            int src = csr_src[e];
            float4 as = *(const float4*)(ALS0 + (size_t)(tb + src) * 4);
            float l0 = as.x + ad.x; l0 = l0 > 0.f ? l0 : 0.2f * l0; s0 += __expf(fminf(l0, 80.f));
            float l1 = as.y + ad.y; l1 = l1 > 0.f ? l1 : 0.2f * l1; s1 += __expf(fminf(l1, 80.f));
            float l2 = as.z + ad.z; l2 = l2 > 0.f ? l2 : 0.2f * l2; s2 += __expf(fminf(l2, 80.f));
            float l3 = as.w + ad.w; l3 = l3 > 0.f ? l3 : 0.2f * l3; s3 += __expf(fminf(l3, 80.f));
        }
#pragma unroll
        for (int o = 32; o; o >>= 1) {
            s0 += __shfl_xor(s0, o, 64); s1 += __shfl_xor(s1, o, 64);
            s2 += __shfl_xor(s2, o, 64); s3 += __shfl_xor(s3, o, 64);
        }
        float i0 = 1.f / (s0 + 1e-16f), i1 = 1.f / (s1 + 1e-16f);
        float i2 = 1.f / (s2 + 1e-16f), i3 = 1.f / (s3 + 1e-16f);
        float ih = (h == 0) ? i0 : (h == 1) ? i1 : (h == 2) ? i2 : i3;
        float adh = sel4(ad, h);
        for (int e0_ = rs; e0_ < re; e0_ += 4) {
            int e = e0_ + g;
            if (e < re) {
                int src = csr_src[e];
                float4 as = *(const float4*)(ALS0 + (size_t)(tb + src) * 4);
                float l = sel4(as, h) + adh; l = l > 0.f ? l : 0.2f * l;
                float a = __expf(fminf(l, 80.f)) * ih;
                ushort4 u = *(const ushort4*)(XW0b + (size_t)(tb + src) * 64 + il * 4);
                a0 += a * bfu(u.x); a1 += a * bfu(u.y);
                a2 += a * bfu(u.z); a3 += a * bfu(u.w);
            }
        }
        scale_h = 1.f;
    }
#pragma unroll
    for (int o = 16; o <= 32; o <<= 1) {
        a0 += __shfl_xor(a0, o, 64); a1 += __shfl_xor(a1, o, 64);
        a2 += __shfl_xor(a2, o, 64); a3 += __shfl_xor(a3, o, 64);
    }
    if (g == 0) {
        int cb = il * 4;
        float v0 = a0 * scale_h + b0[cb + 0]; v0 = v0 > 0.f ? v0 : (__expf(v0) - 1.f);
        float v1 = a1 * scale_h + b0[cb + 1]; v1 = v1 > 0.f ? v1 : (__expf(v1) - 1.f);
        float v2 = a2 * scale_h + b0[cb + 2]; v2 = v2 > 0.f ? v2 : (__expf(v2) - 1.f);
        float v3 = a3 * scale_h + b0[cb + 3]; v3 = v3 > 0.f ? v3 : (__expf(v3) - 1.f);
        ushort4 o4;
        o4.x = f2bu(v0); o4.y = f2bu(v1); o4.z = f2bu(v2); o4.w = f2bu(v3);
        *(ushort4*)(H0b + (size_t)wid * 64 + cb) = o4;
    }
}

/* ---------------- layer-1 logits via MFMA: H0b @ [P1s|P1d]^T ------------- */
__global__ __launch_bounds__(256) void k_logits1(const bf16* __restrict__ H0b,
                                                 const float* __restrict__ P1s,
                                                 const float* __restrict__ P1d,
                                                 float* __restrict__ ALS1,
                                                 float* __restrict__ ALD1) {
    int tid = threadIdx.x;
    int wv = tid >> 6, lane = tid & 63;
    int tile = blockIdx.x * 4 + wv;
    if (tile >= NTILES) return;
    int rb = tile * 16;
    int m = lane & 15, quad = lane >> 4;
    short8 a0 = *(const short8*)(H0b + (size_t)(rb + m) * 64 + quad * 8);
    short8 a1 = *(const short8*)(H0b + (size_t)(rb + m) * 64 + 32 + quad * 8);
    short8 bb0, bb1;
#pragma unroll
    for (int j = 0; j < 8; j++) {
        int k0 = quad * 8 + j, k1 = 32 + quad * 8 + j;
        float v0 = 0.f, v1 = 0.f;
        if (m < 4)      { v0 = P1s[m * 64 + k0];       v1 = P1s[m * 64 + k1]; }
        else if (m < 8) { v0 = P1d[(m - 4) * 64 + k0]; v1 = P1d[(m - 4) * 64 + k1]; }
        bb0[j] = (short)f2bu(v0);
        bb1[j] = (short)f2bu(v1);
    }
    floatx4 acc = {0.f, 0.f, 0.f, 0.f};
    acc = __builtin_amdgcn_mfma_f32_16x16x32_bf16(a0, bb0, acc, 0, 0, 0);
    acc = __builtin_amdgcn_mfma_f32_16x16x32_bf16(a1, bb1, acc, 0, 0, 0);
#pragma unroll
    for (int r = 0; r < 4; r++) {
        int row = rb + quad * 4 + r;
        if (m < 4)      ALS1[row * 4 + m] = acc[r];
        else if (m < 8) ALD1[row * 4 + (m - 4)] = acc[r];
    }
}

/* ---------------- fused layer-1: softmax + aggregate (+alpha out t=5) ---- */
__global__ __launch_bounds__(256) void k_fused1(const int* __restrict__ rowst,
                                                const int* __restrict__ csr_src,
                                                const int* __restrict__ csr_eid,
                                                const bf16* __restrict__ H0b,
                                                const float* __restrict__ ALS1,
                                                const float* __restrict__ ALD1,
                                                bf16* __restrict__ AGG1b,
                                                float* __restrict__ out_alpha) {
    __shared__ float exv[4][256];
    __shared__ int   srcs[4][64];
    int tid = threadIdx.x;
    int wv = tid >> 6;
    int wid = blockIdx.x * 4 + wv;
    int lane = tid & 63;
    int t = wid / N_NODES, n = wid % N_NODES;
    int rs = rowst[n], re = rowst[n + 1];
    int deg = re - rs;
    int tb = t * N_NODES;
    float4 ad = *(const float4*)(ALD1 + (size_t)wid * 4);
    int g = lane >> 4, il = lane & 15;
    bool do_out = (t == T_STEPS - 1);
    float acc[4][4];
#pragma unroll
    for (int hh = 0; hh < 4; hh++)
#pragma unroll
        for (int j = 0; j < 4; j++) acc[hh][j] = 0.f;
    float i0 = 1.f, i1 = 1.f, i2 = 1.f, i3 = 1.f;

    if (deg <= 64) {
        int e = rs + lane;
        bool valid = e < re;
        int src = csr_src[valid ? e : rs];
        float4 as = *(const float4*)(ALS1 + (size_t)(tb + src) * 4);
        float l0 = as.x + ad.x; l0 = l0 > 0.f ? l0 : 0.2f * l0; l0 = fminf(l0, 80.f);
        float l1 = as.y + ad.y; l1 = l1 > 0.f ? l1 : 0.2f * l1; l1 = fminf(l1, 80.f);
        float l2 = as.z + ad.z; l2 = l2 > 0.f ? l2 : 0.2f * l2; l2 = fminf(l2, 80.f);
        float l3 = as.w + ad.w; l3 = l3 > 0.f ? l3 : 0.2f * l3; l3 = fminf(l3, 80.f);
        float e0 = valid ? __expf(l0) : 0.f;
        float e1 = valid ? __expf(l1) : 0.f;
        float e2 = valid ? __expf(l2) : 0.f;
        float e3 = valid ? __expf(l3) : 0.f;
        float s0 = e0, s1 = e1, s2 = e2, s3 = e3;
#pragma unroll
        for (int o = 32; o; o >>= 1) {
            s0 += __shfl_xor(s0, o, 64); s1 += __shfl_xor(s1, o, 64);
            s2 += __shfl_xor(s2, o, 64); s3 += __shfl_xor(s3, o, 64);
        }
        i0 = 1.f / (s0 + 1e-16f); i1 = 1.f / (s1 + 1e-16f);
        i2 = 1.f / (s2 + 1e-16f); i3 = 1.f / (s3 + 1e-16f);
        float4 ex4; ex4.x = e0; ex4.y = e1; ex4.z = e2; ex4.w = e3;
        *(float4*)&exv[wv][lane * 4] = ex4;
        srcs[wv][lane] = src;
        lds_fence();
        for (int k = g; k < deg; k += 4) {
            float4 ex = *(const float4*)&exv[wv][k * 4];
            int s2_ = srcs[wv][k];
            ushort4 u = *(const ushort4*)(H0b + (size_t)(tb + s2_) * 64 + il * 4);
            float x0 = bfu(u.x), x1 = bfu(u.y), x2 = bfu(u.z), x3 = bfu(u.w);
            acc[0][0] += ex.x * x0; acc[0][1] += ex.x * x1; acc[0][2] += ex.x * x2; acc[0][3] += ex.x * x3;
            acc[1][0] += ex.y * x0; acc[1][1] += ex.y * x1; acc[1][2] += ex.y * x2; acc[1][3] += ex.y * x3;
            acc[2][0] += ex.z * x0; acc[2][1] += ex.z * x1; acc[2][2] += ex.z * x2; acc[2][3] += ex.z * x3;
            acc[3][0] += ex.w * x0; acc[3][1] += ex.w * x1; acc[3][2] += ex.w * x2; acc[3][3] += ex.w * x3;
        }
        if (do_out && valid) {
            int eid = csr_eid[e];
            float4 o4; o4.x = e0 * i0; o4.y = e1 * i1; o4.z = e2 * i2; o4.w = e3 * i3;
            *(float4*)(out_alpha + (size_t)eid * 4) = o4;
        }
    } else {
        float s0 = 0.f, s1 = 0.f, s2 = 0.f, s3 = 0.f;
        for (int e = rs + lane; e < re; e += 64) {
            int src = csr_src[e];
            float4 as = *(const float4*)(ALS1 + (size_t)(tb + src) * 4);
            float l0 = as.x + ad.x; l0 = l0 > 0.f ? l0 : 0.2f * l0; s0 += __expf(fminf(l0, 80.f));
            float l1 = as.y + ad.y; l1 = l1 > 0.f ? l1 : 0.2f * l1; s1 += __expf(fminf(l1, 80.f));
            float l2 = as.z + ad.z; l2 = l2 > 0.f ? l2 : 0.2f * l2; s2 += __expf(fminf(l2, 80.f));
            float l3 = as.w + ad.w; l3 = l3 > 0.f ? l3 : 0.2f * l3; s3 += __expf(fminf(l3, 80.f));
        }
#pragma unroll
        for (int o = 32; o; o >>= 1) {
            s0 += __shfl_xor(s0, o, 64); s1 += __shfl_xor(s1, o, 64);
            s2 += __shfl_xor(s2, o, 64); s3 += __shfl_xor(s3, o, 64);
        }
        float j0 = 1.f / (s0 + 1e-16f), j1 = 1.f / (s1 + 1e-16f);
        float j2 = 1.f / (s2 + 1e-16f), j3 = 1.f / (s3 + 1e-16f);
        for (int e0_ = rs; e0_ < re; e0_ += 4) {
            int e = e0_ + g;
            if (e < re) {
                int src = csr_src[e];
                float4 as = *(const float4*)(ALS1 + (size_t)(tb + src) * 4);
                float l0 = as.x + ad.x; l0 = l0 > 0.f ? l0 : 0.2f * l0;
                float l1 = as.y + ad.y; l1 = l1 > 0.f ? l1 : 0.2f * l1;
                float l2 = as.z + ad.z; l2 = l2 > 0.f ? l2 : 0.2f * l2;
                float l3 = as.w + ad.w; l3 = l3 > 0.f ? l3 : 0.2f * l3;
                float al0 = __expf(fminf(l0, 80.f)) * j0;
                float al1 = __expf(fminf(l1, 80.f)) * j1;
                float al2 = __expf(fminf(l2, 80.f)) * j2;
                float al3 = __expf(fminf(l3, 80.f)) * j3;
                if (do_out && il == 0) {
                    int eid = csr_eid[e];
                    float4 o4; o4.x = al0; o4.y = al1; o4.z = al2; o4.w = al3;
                    *(float4*)(out_alpha + (size_t)eid * 4) = o4;
                }
                ushort4 u = *(const ushort4*)(H0b + (size_t)(tb + src) * 64 + il * 4);
                float x0 = bfu(u.x), x1 = bfu(u.y), x2 = bfu(u.z), x3 = bfu(u.w);
                acc[0][0] += al0 * x0; acc[0][1] += al0 * x1; acc[0][2] += al0 * x2; acc[0][3] += al0 * x3;
                acc[1][0] += al1 * x0; acc[1][1] += al1 * x1; acc[1][2] += al1 * x2; acc[1][3] += al1 * x3;
                acc[2][0] += al2 * x0; acc[2][1] += al2 * x1; acc[2][2] += al2 * x2; acc[2][3] += al2 * x3;
                acc[3][0] += al3 * x0; acc[3][1] += al3 * x1; acc[3][2] += al3 * x2; acc[3][3] += al3 * x3;
            }
        }
        i0 = i1 = i2 = i3 = 1.f;
    }
    {
        float iv[4] = { i0, i1, i2, i3 };
#pragma unroll
        for (int hh = 0; hh < 4; hh++)
#pragma unroll
            for (int j = 0; j < 4; j++) acc[hh][j] *= iv[hh];
    }
#pragma unroll
    for (int o = 16; o <= 32; o <<= 1)
#pragma unroll
        for (int hh = 0; hh < 4; hh++)
#pragma unroll
            for (int j = 0; j < 4; j++)
                acc[hh][j] += __shfl_xor(acc[hh][j], o, 64);
    if (g == 0) {
        int cb = il * 4;
        size_t ob = (size_t)wid * 256 + cb;
#pragma unroll
        for (int hh = 0; hh < 4; hh++) {
            ushort4 o4;
            o4.x = f2bu(acc[hh][0]); o4.y = f2bu(acc[hh][1]);
            o4.z = f2bu(acc[hh][2]); o4.w = f2bu(acc[hh][3]);
            *(ushort4*)(AGG1b + ob + hh * 64) = o4;
        }
    }
}

/* ---------------- epilogue GEMM (MFMA): AGG @ Wbig + LN -----------------
   Wbig[K=h*64+kk][c] = W1[kk][h*64+c]; Wbig^T staged bf16 in LDS [c][K]. */
__global__ __launch_bounds__(256) void k_post1(const bf16* __restrict__ AGG1b,
                                               const float* __restrict__ W1,
                                               const float* __restrict__ b1,
                                               const float* __restrict__ ln_g,
                                               const float* __restrict__ ln_b,
                                               bf16* __restrict__ HSb) {
    __shared__ __align__(16) bf16 wt[64 * 256];   /* [c][K], 32 KB */
    int tid = threadIdx.x;
    for (int i = tid; i < 16384; i += 256) {
        int c = i >> 8, K = i & 255;
        wt[i] = __float2bfloat16(W1[(K & 63) * 256 + (K >> 6) * 64 + c]);
    }
    __syncthreads();
    int wv = tid >> 6, lane = tid & 63;
    int tile = blockIdx.x * 4 + wv;
    if (tile >= NTILES) return;
    int rb = tile * 16;
    int m = lane & 15, quad = lane >> 4;
    const bf16* arow = AGG1b + (size_t)(rb + m) * 256 + quad * 8;
    short8 af[8];
#pragma unroll
    for (int kb = 0; kb < 8; kb++) af[kb] = *(const short8*)(arow + kb * 32);
    floatx4 acc[4];
#pragma unroll
    for (int ct = 0; ct < 4; ct++) {
        const bf16* wrow = wt + (ct * 16 + m) * 256 + quad * 8;
        floatx4 a = {0.f, 0.f, 0.f, 0.f};
#pragma unroll
        for (int kb = 0; kb < 8; kb++) {
            short8 bf = *(const short8*)(wrow + kb * 32);
            a = __builtin_amdgcn_mfma_f32_16x16x32_bf16(af[kb], bf, a, 0, 0, 0);
        }
        acc[ct] = a;
    }
    float b1v[4], ggv[4], bbv[4];
#pragma unroll
    for (int ct = 0; ct < 4; ct++) {
        b1v[ct] = b1[ct * 16 + m]; ggv[ct] = ln_g[ct * 16 + m]; bbv[ct] = ln_b[ct * 16 + m];
    }
#pragma unroll
    for (int r = 0; r < 4; r++) {
        float v[4];
        float s = 0.f;
#pragma unroll
        for (int ct = 0; ct < 4; ct++) {
            float t_ = acc[ct][r] * 0.25f + b1v[ct];
            t_ = t_ > 0.f ? t_ : (__expf(t_) - 1.f);
            v[ct] = t_; s += t_;
        }
#pragma unroll
        for (int o = 8; o; o >>= 1) s += __shfl_xor(s, o, 64);
        float mu = s * (1.f / 64.f);
        float q = 0.f;
#pragma unroll
        for (int ct = 0; ct < 4; ct++) { float d = v[ct] - mu; q += d * d; }
#pragma unroll
        for (int o = 8; o; o >>= 1) q += __shfl_xor(q, o, 64);
        float rinv = rsqrtf(q * (1.f / 64.f) + 1e-5f);
        int row = rb + quad * 4 + r;
#pragma unroll
        for (int ct = 0; ct < 4; ct++)
            HSb[(size_t)row * 64 + ct * 16 + m] =
                __float2bfloat16((v[ct] - mu) * rinv * ggv[ct] + bbv[ct]);
    }
}

/* ---------------- GRU (MFMA) ---------------- */

__global__ void k_zero(float* p, int nelem) {
    int i = blockIdx.x * blockDim.x + threadIdx.x;
    if (i < nelem) p[i] = 0.f;
}

__global__ __launch_bounds__(256) void k_gi(const bf16* __restrict__ HSb,
                                            const float* __restrict__ W_ih,
                                            const float* __restrict__ b_ih,
                                            bf16* __restrict__ GIb) {
    __shared__ __align__(16) bf16 wl[192 * 64];   /* 24 KB, [j][k] */
    int tid = threadIdx.x;
    for (int i = tid; i < 12288; i += 256) wl[i] = __float2bfloat16(W_ih[i]);
    __syncthreads();
    int wv = tid >> 6, lane = tid & 63;
    int tile = blockIdx.x * 4 + wv;
    if (tile >= TN / 16) return;
    int rb = tile * 16;
    int m = lane & 15, quad = lane >> 4;
    short8 a0 = *(const short8*)(HSb + (size_t)(rb + m) * 64 + quad * 8);
    short8 a1 = *(const short8*)(HSb + (size_t)(rb + m) * 64 + 32 + quad * 8);
#pragma unroll
    for (int ct = 0; ct < 12; ct++) {
        int cb = ct * 16;
        short8 bb0 = *(const short8*)(wl + (cb + m) * 64 + quad * 8);
        short8 bb1 = *(const short8*)(wl + (cb + m) * 64 + 32 + quad * 8);
        floatx4 acc = {0.f, 0.f, 0.f, 0.f};
        acc = __builtin_amdgcn_mfma_f32_16x16x32_bf16(a0, bb0, acc, 0, 0, 0);
        acc = __builtin_amdgcn_mfma_f32_16x16x32_bf16(a1, bb1, acc, 0, 0, 0);
        float bi = b_ih[cb + m];
#pragma unroll
        for (int r = 0; r < 4; r++)
            GIb[(size_t)(rb + quad * 4 + r) * 192 + cb + m] = __float2bfloat16(acc[r] + bi);
    }
}

__global__ __launch_bounds__(256) void k_gru_step(int t,
                                                  const bf16* __restrict__ GIb,
                                                  const float* __restrict__ W_hh,
                                                  const float* __restrict__ b_hh,
                                                  const float* __restrict__ Hprev,
                                                  float* __restrict__ Hnew) {
    __shared__ __align__(16) bf16 wl[192 * 64];   /* 24 KB, [j][k] */
    int tid = threadIdx.x;
    for (int i = tid; i < 12288; i += 256) wl[i] = __float2bfloat16(W_hh[i]);
    __syncthreads();
    int wv = tid >> 6, lane = tid & 63;
    int tile = blockIdx.x * 4 + wv;
    if (tile >= N_NODES / 16) return;
    int rb = tile * 16;
    int m = lane & 15, quad = lane >> 4;
    const float* hrow = Hprev + (size_t)(rb + m) * 64 + quad * 8;
    short8 a0, a1;
#pragma unroll
    for (int j = 0; j < 8; j++) {
        a0[j] = (short)f2bu(hrow[j]);
        a1[j] = (short)f2bu(hrow[32 + j]);
    }
    floatx4 acc[12];
#pragma unroll
    for (int ct = 0; ct < 12; ct++) {
        int cb = ct * 16;
        short8 bb0 = *(const short8*)(wl + (cb + m) * 64 + quad * 8);
        short8 bb1 = *(const short8*)(wl + (cb + m) * 64 + 32 + quad * 8);
        floatx4 a = {0.f, 0.f, 0.f, 0.f};
        a = __builtin_amdgcn_mfma_f32_16x16x32_bf16(a0, bb0, a, 0, 0, 0);
        a = __builtin_amdgcn_mfma_f32_16x16x32_bf16(a1, bb1, a, 0, 0, 0);
        float bh = b_hh[cb + m];
#pragma unroll
        for (int r = 0; r < 4; r++) acc[ct][r] = a[r] + bh;
    }
    const bf16* gib = GIb + (size_t)t * N_NODES * 192;
#pragma unroll
    for (int ct = 0; ct < 4; ct++) {
        int c = ct * 16 + m;
#pragma unroll
        for (int r = 0; r < 4; r++) {
            int row = rb + quad * 4 + r;
            float gr = b2f(gib[(size_t)row * 192 + c]);
            float gz = b2f(gib[(size_t)row * 192 + 64 + c]);
            float gg = b2f(gib[(size_t)row * 192 + 128 + c]);
            float hp = Hprev[(size_t)row * 64 + c];
            float rr = 1.f / (1.f + __expf(-(gr + acc[ct][r])));
            float z  = 1.f / (1.f + __expf(-(gz + acc[ct + 4][r])));
            float g  = tanhf(gg + rr * acc[ct + 8][r]);
            Hnew[(size_t)row * 64 + c] = (1.f - z) * g + z * hp;
        }
    }
}

/* ---------------- output writer (fp32) ---------------- */

__global__ void k_out_ei(const int* __restrict__ ei, float* __restrict__ out) {
    int i = blockIdx.x * blockDim.x + threadIdx.x;
    if (i >= 2 * EP) return;
    int v;
    if (i < EP) {
        v = (i < E_EDGES) ? ei[i] : (i - E_EDGES);                 // src row
    } else {
        int jj = i - EP;
        v = (jj < E_EDGES) ? ei[E_EDGES + jj] : (jj - E_EDGES);    // dst row
    }
    out[i] = (float)v;
}

/* ---------------- launch ---------------- */

extern "C" void kernel_launch(void* const* d_in, const int* in_sizes, int n_in,
                              void* d_out, int out_size, void* d_ws, size_t ws_size,
                              hipStream_t stream) {
    const float* x      = (const float*)d_in[0];
    const int*   ei     = (const int*)d_in[1];
    const float* W0     = (const float*)d_in[2];
    const float* a_src0 = (const float*)d_in[3];
    const float* a_dst0 = (const float*)d_in[4];
    const float* b0     = (const float*)d_in[5];
    const float* W1     = (const float*)d_in[6];
    const float* a_src1 = (const float*)d_in[7];
    const float* a_dst1 = (const float*)d_in[8];
    const float* b1     = (const float*)d_in[9];
    const float* ln_g   = (const float*)d_in[10];
    const float* ln_b   = (const float*)d_in[11];
    const float* W_ih   = (const float*)d_in[12];
    const float* W_hh   = (const float*)d_in[13];
    const float* b_ih   = (const float*)d_in[14];
    const float* b_hh   = (const float*)d_in[15];
    float* out = (float*)d_out;

    char* w = (char*)d_ws;
    size_t off = 0;
    auto take = [&](size_t bytes) -> void* {
        void* p = w + off;
        off = (off + bytes + 255) & ~(size_t)255;
        return p;
    };
    int*   counts  = (int*)take(N_NODES * 4);
    int*   fill    = (int*)take(N_NODES * 4);
    int*   rowst   = (int*)take((N_NODES + 1) * 4);
    int*   csr_src = (int*)take((size_t)EP * 4);
    int*   csr_eid = (int*)take((size_t)EP * 4);
    bf16*  XW0b    = (bf16*)take((size_t)TN * 64 * 2);
    float* ALS0    = (float*)take((size_t)TN * 4 * 4);
    float* ALD0    = (float*)take((size_t)TN * 4 * 4);
    bf16*  H0b     = (bf16*)take((size_t)TN * 64 * 2);
    float* P1s     = (float*)take(256 * 4);
    float* P1d     = (float*)take(256 * 4);
    float* ALS1    = (float*)take((size_t)TN * 4 * 4);
    float* ALD1    = (float*)take((size_t)TN * 4 * 4);
    bf16*  AGG1b   = (bf16*)take((size_t)TN * 256 * 2);
    bf16*  HSb     = (bf16*)take((size_t)TN * 64 * 2);
    bf16*  GIb     = (bf16*)take((size_t)TN * 192 * 2);
    float* HA      = (float*)take((size_t)N_NODES * 64 * 4);
    float* HB      = (float*)take((size_t)N_NODES * 64 * 4);
    (void)ws_size; (void)in_sizes; (void)n_in; (void)out_size;

    const int B = 256;
    /* CSR build + prep */
    k_init<<<(N_NODES + B - 1) / B, B, 0, stream>>>(counts, fill);
    k_count<<<(EP + B - 1) / B, B, 0, stream>>>(ei, counts);
    k_scan<<<1, 1024, 0, stream>>>(counts, rowst);
    k_scatter<<<(EP + B - 1) / B, B, 0, stream>>>(ei, rowst, fill, csr_src, csr_eid);
    k_prep1<<<1, B, 0, stream>>>(W1, a_src1, a_dst1, P1s, P1d);

    const int GT = (NTILES + 3) / 4;   /* 938 blocks for 16-row-tile MFMA kernels */
    /* GAT layer 0 */
    k_gemm0<<<GT, B, 0, stream>>>(x, W0, a_src0, a_dst0, XW0b, ALS0, ALD0);
    k_fused0<<<TN / 4, B, 0, stream>>>(rowst, csr_src, XW0b, ALS0, ALD0, b0, H0b);
    k_logits1<<<GT, B, 0, stream>>>(H0b, P1s, P1d, ALS1, ALD1);

    /* GAT layer 1 */
    k_fused1<<<TN / 4, B, 0, stream>>>(rowst, csr_src, csr_eid, H0b, ALS1, ALD1,
                                       AGG1b, out + (size_t)N_NODES * HID);
    k_post1<<<GT, B, 0, stream>>>(AGG1b, W1, b1, ln_g, ln_b, HSb);

    /* GRU: MFMA GI precompute + 6 MFMA recurrent steps */
    k_gi<<<GT, B, 0, stream>>>(HSb, W_ih, b_ih, GIb);
    k_zero<<<(N_NODES * 64 + B - 1) / B, B, 0, stream>>>(HA, N_NODES * 64);
    float* hbuf[2] = { HA, HB };
    for (int t = 0; t < T_STEPS; t++) {
        float* prev = hbuf[t & 1];
        float* next = (t == T_STEPS - 1) ? out : hbuf[1 - (t & 1)];
        k_gru_step<<<(N_NODES / 16 + 3) / 4, B, 0, stream>>>(t, GIb, W_hh, b_hh, prev, next);
    }

    /* edge-index output */
    k_out_ei<<<(2 * EP + B - 1) / B, B, 0, stream>>>(ei, out + (size_t)N_NODES * HID + (size_t)EP * HEADS);
}

// Round 12
// 288.867 us; speedup vs baseline: 4.3219x; 1.1327x over previous
//
#include <hip/hip_runtime.h>
#include <hip/hip_bf16.h>
#include <cstdint>
#include <cstddef>

#define N_NODES 10000
#define T_STEPS 6
#define F_IN    64
#define HID     64
#define HEADS   4
#define E_EDGES 160000
#define EP      (E_EDGES + N_NODES)   /* 170000 edges incl self-loops */
#define TN      (T_STEPS * N_NODES)   /* 60000 */
#define NTILES  (TN / 16)             /* 3750 */

typedef __hip_bfloat16 bf16;
typedef __attribute__((ext_vector_type(8))) short short8;
typedef __attribute__((ext_vector_type(4))) float floatx4;

__device__ __forceinline__ float b2f(bf16 v) { return __bfloat162float(v); }
__device__ __forceinline__ float bfu(unsigned short s) { return __uint_as_float((unsigned)s << 16); }
__device__ __forceinline__ unsigned short f2bu(float f) {
    bf16 b = __float2bfloat16(f);
    return *(unsigned short*)&b;
}
__device__ __forceinline__ float sel4(float4 v, int h) {
    float r = v.x;
    r = (h == 1) ? v.y : r;
    r = (h == 2) ? v.z : r;
    r = (h == 3) ? v.w : r;
    return r;
}
__device__ __forceinline__ void lds_fence() {
    asm volatile("s_waitcnt lgkmcnt(0)" ::: "memory");
}

/* ---------------- CSR build ---------------- */

__global__ void k_init(int* counts, int* fill) {
    int i = blockIdx.x * blockDim.x + threadIdx.x;
    if (i < N_NODES) { counts[i] = 0; fill[i] = 0; }
}

__global__ void k_count(const int* ei, int* counts) {
    int e = blockIdx.x * blockDim.x + threadIdx.x;
    if (e >= EP) return;
    int dst = (e < E_EDGES) ? ei[E_EDGES + e] : (e - E_EDGES);
    atomicAdd(&counts[dst], 1);
}

__global__ void k_scan(const int* counts, int* rowstart) {
    __shared__ int part[1024];
    int tid = threadIdx.x;
    const int chunk = (N_NODES + 1023) / 1024;  // 10
    int base = tid * chunk;
    int s = 0;
    for (int i = 0; i < chunk; i++) { int idx = base + i; if (idx < N_NODES) s += counts[idx]; }
    part[tid] = s;
    __syncthreads();
    for (int off = 1; off < 1024; off <<= 1) {
        int v = (tid >= off) ? part[tid - off] : 0;
        __syncthreads();
        part[tid] += v;
        __syncthreads();
    }
    int run = (tid == 0) ? 0 : part[tid - 1];
    for (int i = 0; i < chunk; i++) {
        int idx = base + i;
        if (idx < N_NODES) { rowstart[idx] = run; run += counts[idx]; }
    }
    if (tid == 0) rowstart[N_NODES] = EP;
}

__global__ void k_scatter(const int* ei, const int* rowstart, int* fill,
                          int* csr_src, int* csr_eid) {
    int e = blockIdx.x * blockDim.x + threadIdx.x;
    if (e >= EP) return;
    int src = (e < E_EDGES) ? ei[e] : (e - E_EDGES);
    int dst = (e < E_EDGES) ? ei[E_EDGES + e] : (e - E_EDGES);
    int pos = rowstart[dst] + atomicAdd(&fill[dst], 1);
    csr_src[pos] = src;
    csr_eid[pos] = e;
}

/* ---------------- prep: P-matrices for layer-1 logits ---------------- */

__global__ __launch_bounds__(256) void k_prep1(const float* __restrict__ W1,
                                               const float* __restrict__ a_src1,
                                               const float* __restrict__ a_dst1,
                                               float* __restrict__ P1s,
                                               float* __restrict__ P1d) {
    int tid = threadIdx.x;
    int h = tid >> 6, k = tid & 63;
    float ps = 0.f, pd = 0.f;
    for (int c = 0; c < 64; c++) {
        float wv = W1[k * 256 + h * 64 + c];
        ps += wv * a_src1[h * 64 + c];
        pd += wv * a_dst1[h * 64 + c];
    }
    P1s[h * 64 + k] = ps;
    P1d[h * 64 + k] = pd;
}

/* ---------------- GAT layer 0 GEMM (MFMA) ---------------- */
__global__ __launch_bounds__(256) void k_gemm0(const float* __restrict__ x,
                                               const float* __restrict__ W0,
                                               const float* __restrict__ a_src0,
                                               const float* __restrict__ a_dst0,
                                               bf16* __restrict__ XW0b,
                                               float* __restrict__ ALS0,
                                               float* __restrict__ ALD0) {
    __shared__ __align__(16) bf16 wt[64 * 64];   /* [c][k], 8 KB */
    int tid = threadIdx.x;
    for (int i = tid; i < 4096; i += 256) {
        int c = i >> 6, k = i & 63;
        wt[i] = __float2bfloat16(W0[k * 64 + c]);
    }
    __syncthreads();
    int wv = tid >> 6, lane = tid & 63;
    int tile = blockIdx.x * 4 + wv;
    if (tile >= NTILES) return;
    int rb = tile * 16;
    int m = lane & 15, quad = lane >> 4;
    int row = rb + m;
    int t = row / N_NODES, n = row - t * N_NODES;
    const float* xr = x + ((size_t)n * T_STEPS + t) * F_IN + quad * 8;
    short8 a0, a1;
#pragma unroll
    for (int j = 0; j < 8; j++) {
        a0[j] = (short)f2bu(xr[j]);
        a1[j] = (short)f2bu(xr[32 + j]);
    }
    floatx4 acc[4];
#pragma unroll
    for (int ct = 0; ct < 4; ct++) {
        short8 bb0 = *(const short8*)(wt + (ct * 16 + m) * 64 + quad * 8);
        short8 bb1 = *(const short8*)(wt + (ct * 16 + m) * 64 + 32 + quad * 8);
        floatx4 a = {0.f, 0.f, 0.f, 0.f};
        a = __builtin_amdgcn_mfma_f32_16x16x32_bf16(a0, bb0, a, 0, 0, 0);
        a = __builtin_amdgcn_mfma_f32_16x16x32_bf16(a1, bb1, a, 0, 0, 0);
        acc[ct] = a;
    }
#pragma unroll
    for (int ct = 0; ct < 4; ct++) {
        float as0 = a_src0[ct * 16 + m], ad0 = a_dst0[ct * 16 + m];
#pragma unroll
        for (int r = 0; r < 4; r++) {
            int orow = rb + quad * 4 + r;
            float v = acc[ct][r];
            XW0b[(size_t)orow * 64 + ct * 16 + m] = __float2bfloat16(v);
            float ps = v * as0, pd = v * ad0;
#pragma unroll
            for (int o = 8; o; o >>= 1) { ps += __shfl_xor(ps, o, 64); pd += __shfl_xor(pd, o, 64); }
            if (m == 0) { ALS0[orow * 4 + ct] = ps; ALD0[orow * 4 + ct] = pd; }
        }
    }
}

/* ---------------- fused layer-0: softmax + accumulate (no max-sub) ------- */
__global__ __launch_bounds__(256) void k_fused0(const int* __restrict__ rowst,
                                                const int* __restrict__ csr_src,
                                                const bf16* __restrict__ XW0b,
                                                const float* __restrict__ ALS0,
                                                const float* __restrict__ ALD0,
                                                const float* __restrict__ b0,
                                                bf16* __restrict__ H0b) {
    __shared__ float exv[4][256];
    __shared__ int   srcs[4][64];
    int tid = threadIdx.x;
    int wv = tid >> 6;
    int wid = blockIdx.x * 4 + wv;
    int lane = tid & 63;
    int t = wid / N_NODES, n = wid % N_NODES;
    int rs = rowst[n], re = rowst[n + 1];
    int deg = re - rs;
    int tb = t * N_NODES;
    float4 ad = *(const float4*)(ALD0 + (size_t)wid * 4);
    int g = lane >> 4, il = lane & 15;
    int h = il >> 2;
    float a0 = 0.f, a1 = 0.f, a2 = 0.f, a3 = 0.f;
    float scale_h;

    if (deg <= 64) {
        int e = rs + lane;
        bool valid = e < re;
        int src = csr_src[valid ? e : rs];
        float4 as = *(const float4*)(ALS0 + (size_t)(tb + src) * 4);
        float l0 = as.x + ad.x; l0 = l0 > 0.f ? l0 : 0.2f * l0; l0 = fminf(l0, 80.f);
        float l1 = as.y + ad.y; l1 = l1 > 0.f ? l1 : 0.2f * l1; l1 = fminf(l1, 80.f);
        float l2 = as.z + ad.z; l2 = l2 > 0.f ? l2 : 0.2f * l2; l2 = fminf(l2, 80.f);
        float l3 = as.w + ad.w; l3 = l3 > 0.f ? l3 : 0.2f * l3; l3 = fminf(l3, 80.f);
        float e0 = valid ? __expf(l0) : 0.f;
        float e1 = valid ? __expf(l1) : 0.f;
        float e2 = valid ? __expf(l2) : 0.f;
        float e3 = valid ? __expf(l3) : 0.f;
        float s0 = e0, s1 = e1, s2 = e2, s3 = e3;
#pragma unroll
        for (int o = 32; o; o >>= 1) {
            s0 += __shfl_xor(s0, o, 64); s1 += __shfl_xor(s1, o, 64);
            s2 += __shfl_xor(s2, o, 64); s3 += __shfl_xor(s3, o, 64);
        }
        float i0 = 1.f / (s0 + 1e-16f), i1 = 1.f / (s1 + 1e-16f);
        float i2 = 1.f / (s2 + 1e-16f), i3 = 1.f / (s3 + 1e-16f);
        float4 ex4; ex4.x = e0; ex4.y = e1; ex4.z = e2; ex4.w = e3;
        *(float4*)&exv[wv][lane * 4] = ex4;
        srcs[wv][lane] = src;
        lds_fence();
        for (int k = g; k < deg; k += 4) {
            float aex = exv[wv][k * 4 + h];
            int s2_ = srcs[wv][k];
            ushort4 u = *(const ushort4*)(XW0b + (size_t)(tb + s2_) * 64 + il * 4);
            a0 += aex * bfu(u.x); a1 += aex * bfu(u.y);
            a2 += aex * bfu(u.z); a3 += aex * bfu(u.w);
        }
        scale_h = (h == 0) ? i0 : (h == 1) ? i1 : (h == 2) ? i2 : i3;
    } else {
        float s0 = 0.f, s1 = 0.f, s2 = 0.f, s3 = 0.f;
        for (int e = rs + lane; e < re; e += 64) {
            int src = csr_src[e];
            float4 as = *(const float4*)(ALS0 + (size_t)(tb + src) * 4);
            float l0 = as.x + ad.x; l0 = l0 > 0.f ? l0 : 0.2f * l0; s0 += __expf(fminf(l0, 80.f));
            float l1 = as.y + ad.y; l1 = l1 > 0.f ? l1 : 0.2f * l1; s1 += __expf(fminf(l1, 80.f));
            float l2 = as.z + ad.z; l2 = l2 > 0.f ? l2 : 0.2f * l2; s2 += __expf(fminf(l2, 80.f));
            float l3 = as.w + ad.w; l3 = l3 > 0.f ? l3 : 0.2f * l3; s3 += __expf(fminf(l3, 80.f));
        }
#pragma unroll
        for (int o = 32; o; o >>= 1) {
            s0 += __shfl_xor(s0, o, 64); s1 += __shfl_xor(s1, o, 64);
            s2 += __shfl_xor(s2, o, 64); s3 += __shfl_xor(s3, o, 64);
        }
        float i0 = 1.f / (s0 + 1e-16f), i1 = 1.f / (s1 + 1e-16f);
        float i2 = 1.f / (s2 + 1e-16f), i3 = 1.f / (s3 + 1e-16f);
        float ih = (h == 0) ? i0 : (h == 1) ? i1 : (h == 2) ? i2 : i3;
        float adh = sel4(ad, h);
        for (int e0_ = rs; e0_ < re; e0_ += 4) {
            int e = e0_ + g;
            if (e < re) {
                int src = csr_src[e];
                float4 as = *(const float4*)(ALS0 + (size_t)(tb + src) * 4);
                float l = sel4(as, h) + adh; l = l > 0.f ? l : 0.2f * l;
                float a = __expf(fminf(l, 80.f)) * ih;
                ushort4 u = *(const ushort4*)(XW0b + (size_t)(tb + src) * 64 + il * 4);
                a0 += a * bfu(u.x); a1 += a * bfu(u.y);
                a2 += a * bfu(u.z); a3 += a * bfu(u.w);
            }
        }
        scale_h = 1.f;
    }
#pragma unroll
    for (int o = 16; o <= 32; o <<= 1) {
        a0 += __shfl_xor(a0, o, 64); a1 += __shfl_xor(a1, o, 64);
        a2 += __shfl_xor(a2, o, 64); a3 += __shfl_xor(a3, o, 64);
    }
    if (g == 0) {
        int cb = il * 4;
        float v0 = a0 * scale_h + b0[cb + 0]; v0 = v0 > 0.f ? v0 : (__expf(v0) - 1.f);
        float v1 = a1 * scale_h + b0[cb + 1]; v1 = v1 > 0.f ? v1 : (__expf(v1) - 1.f);
        float v2 = a2 * scale_h + b0[cb + 2]; v2 = v2 > 0.f ? v2 : (__expf(v2) - 1.f);
        float v3 = a3 * scale_h + b0[cb + 3]; v3 = v3 > 0.f ? v3 : (__expf(v3) - 1.f);
        ushort4 o4;
        o4.x = f2bu(v0); o4.y = f2bu(v1); o4.z = f2bu(v2); o4.w = f2bu(v3);
        *(ushort4*)(H0b + (size_t)wid * 64 + cb) = o4;
    }
}

/* ---------------- layer-1 logits via MFMA: H0b @ [P1s|P1d]^T ------------- */
__global__ __launch_bounds__(256) void k_logits1(const bf16* __restrict__ H0b,
                                                 const float* __restrict__ P1s,
                                                 const float* __restrict__ P1d,
                                                 float* __restrict__ ALS1,
                                                 float* __restrict__ ALD1) {
    int tid = threadIdx.x;
    int wv = tid >> 6, lane = tid & 63;
    int tile = blockIdx.x * 4 + wv;
    if (tile >= NTILES) return;
    int rb = tile * 16;
    int m = lane & 15, quad = lane >> 4;
    short8 a0 = *(const short8*)(H0b + (size_t)(rb + m) * 64 + quad * 8);
    short8 a1 = *(const short8*)(H0b + (size_t)(rb + m) * 64 + 32 + quad * 8);
    short8 bb0, bb1;
#pragma unroll
    for (int j = 0; j < 8; j++) {
        int k0 = quad * 8 + j, k1 = 32 + quad * 8 + j;
        float v0 = 0.f, v1 = 0.f;
        if (m < 4)      { v0 = P1s[m * 64 + k0];       v1 = P1s[m * 64 + k1]; }
        else if (m < 8) { v0 = P1d[(m - 4) * 64 + k0]; v1 = P1d[(m - 4) * 64 + k1]; }
        bb0[j] = (short)f2bu(v0);
        bb1[j] = (short)f2bu(v1);
    }
    floatx4 acc = {0.f, 0.f, 0.f, 0.f};
    acc = __builtin_amdgcn_mfma_f32_16x16x32_bf16(a0, bb0, acc, 0, 0, 0);
    acc = __builtin_amdgcn_mfma_f32_16x16x32_bf16(a1, bb1, acc, 0, 0, 0);
#pragma unroll
    for (int r = 0; r < 4; r++) {
        int row = rb + quad * 4 + r;
        if (m < 4)      ALS1[row * 4 + m] = acc[r];
        else if (m < 8) ALD1[row * 4 + (m - 4)] = acc[r];
    }
}

/* ---------------- fused layer-1: softmax + aggregate (+alpha out t=5) ---- */
__global__ __launch_bounds__(256) void k_fused1(const int* __restrict__ rowst,
                                                const int* __restrict__ csr_src,
                                                const int* __restrict__ csr_eid,
                                                const bf16* __restrict__ H0b,
                                                const float* __restrict__ ALS1,
                                                const float* __restrict__ ALD1,
                                                bf16* __restrict__ AGG1b,
                                                float* __restrict__ out_alpha) {
    __shared__ float exv[4][256];
    __shared__ int   srcs[4][64];
    int tid = threadIdx.x;
    int wv = tid >> 6;
    int wid = blockIdx.x * 4 + wv;
    int lane = tid & 63;
    int t = wid / N_NODES, n = wid % N_NODES;
    int rs = rowst[n], re = rowst[n + 1];
    int deg = re - rs;
    int tb = t * N_NODES;
    float4 ad = *(const float4*)(ALD1 + (size_t)wid * 4);
    int g = lane >> 4, il = lane & 15;
    bool do_out = (t == T_STEPS - 1);
    float acc[4][4];
#pragma unroll
    for (int hh = 0; hh < 4; hh++)
#pragma unroll
        for (int j = 0; j < 4; j++) acc[hh][j] = 0.f;
    float i0 = 1.f, i1 = 1.f, i2 = 1.f, i3 = 1.f;

    if (deg <= 64) {
        int e = rs + lane;
        bool valid = e < re;
        int src = csr_src[valid ? e : rs];
        float4 as = *(const float4*)(ALS1 + (size_t)(tb + src) * 4);
        float l0 = as.x + ad.x; l0 = l0 > 0.f ? l0 : 0.2f * l0; l0 = fminf(l0, 80.f);
        float l1 = as.y + ad.y; l1 = l1 > 0.f ? l1 : 0.2f * l1; l1 = fminf(l1, 80.f);
        float l2 = as.z + ad.z; l2 = l2 > 0.f ? l2 : 0.2f * l2; l2 = fminf(l2, 80.f);
        float l3 = as.w + ad.w; l3 = l3 > 0.f ? l3 : 0.2f * l3; l3 = fminf(l3, 80.f);
        float e0 = valid ? __expf(l0) : 0.f;
        float e1 = valid ? __expf(l1) : 0.f;
        float e2 = valid ? __expf(l2) : 0.f;
        float e3 = valid ? __expf(l3) : 0.f;
        float s0 = e0, s1 = e1, s2 = e2, s3 = e3;
#pragma unroll
        for (int o = 32; o; o >>= 1) {
            s0 += __shfl_xor(s0, o, 64); s1 += __shfl_xor(s1, o, 64);
            s2 += __shfl_xor(s2, o, 64); s3 += __shfl_xor(s3, o, 64);
        }
        i0 = 1.f / (s0 + 1e-16f); i1 = 1.f / (s1 + 1e-16f);
        i2 = 1.f / (s2 + 1e-16f); i3 = 1.f / (s3 + 1e-16f);
        float4 ex4; ex4.x = e0; ex4.y = e1; ex4.z = e2; ex4.w = e3;
        *(float4*)&exv[wv][lane * 4] = ex4;
        srcs[wv][lane] = src;
        lds_fence();
        for (int k = g; k < deg; k += 4) {
            float4 ex = *(const float4*)&exv[wv][k * 4];
            int s2_ = srcs[wv][k];
            ushort4 u = *(const ushort4*)(H0b + (size_t)(tb + s2_) * 64 + il * 4);
            float x0 = bfu(u.x), x1 = bfu(u.y), x2 = bfu(u.z), x3 = bfu(u.w);
            acc[0][0] += ex.x * x0; acc[0][1] += ex.x * x1; acc[0][2] += ex.x * x2; acc[0][3] += ex.x * x3;
            acc[1][0] += ex.y * x0; acc[1][1] += ex.y * x1; acc[1][2] += ex.y * x2; acc[1][3] += ex.y * x3;
            acc[2][0] += ex.z * x0; acc[2][1] += ex.z * x1; acc[2][2] += ex.z * x2; acc[2][3] += ex.z * x3;
            acc[3][0] += ex.w * x0; acc[3][1] += ex.w * x1; acc[3][2] += ex.w * x2; acc[3][3] += ex.w * x3;
        }
        if (do_out && valid) {
            int eid = csr_eid[e];
            float4 o4; o4.x = e0 * i0; o4.y = e1 * i1; o4.z = e2 * i2; o4.w = e3 * i3;
            *(float4*)(out_alpha + (size_t)eid * 4) = o4;
        }
    } else {
        float s0 = 0.f, s1 = 0.f, s2 = 0.f, s3 = 0.f;
        for (int e = rs + lane; e < re; e += 64) {
            int src = csr_src[e];
            float4 as = *(const float4*)(ALS1 + (size_t)(tb + src) * 4);
            float l0 = as.x + ad.x; l0 = l0 > 0.f ? l0 : 0.2f * l0; s0 += __expf(fminf(l0, 80.f));
            float l1 = as.y + ad.y; l1 = l1 > 0.f ? l1 : 0.2f * l1; s1 += __expf(fminf(l1, 80.f));
            float l2 = as.z + ad.z; l2 = l2 > 0.f ? l2 : 0.2f * l2; s2 += __expf(fminf(l2, 80.f));
            float l3 = as.w + ad.w; l3 = l3 > 0.f ? l3 : 0.2f * l3; s3 += __expf(fminf(l3, 80.f));
        }
#pragma unroll
        for (int o = 32; o; o >>= 1) {
            s0 += __shfl_xor(s0, o, 64); s1 += __shfl_xor(s1, o, 64);
            s2 += __shfl_xor(s2, o, 64); s3 += __shfl_xor(s3, o, 64);
        }
        float j0 = 1.f / (s0 + 1e-16f), j1 = 1.f / (s1 + 1e-16f);
        float j2 = 1.f / (s2 + 1e-16f), j3 = 1.f / (s3 + 1e-16f);
        for (int e0_ = rs; e0_ < re; e0_ += 4) {
            int e = e0_ + g;
            if (e < re) {
                int src = csr_src[e];
                float4 as = *(const float4*)(ALS1 + (size_t)(tb + src) * 4);
                float l0 = as.x + ad.x; l0 = l0 > 0.f ? l0 : 0.2f * l0;
                float l1 = as.y + ad.y; l1 = l1 > 0.f ? l1 : 0.2f * l1;
                float l2 = as.z + ad.z; l2 = l2 > 0.f ? l2 : 0.2f * l2;
                float l3 = as.w + ad.w; l3 = l3 > 0.f ? l3 : 0.2f * l3;
                float al0 = __expf(fminf(l0, 80.f)) * j0;
                float al1 = __expf(fminf(l1, 80.f)) * j1;
                float al2 = __expf(fminf(l2, 80.f)) * j2;
                float al3 = __expf(fminf(l3, 80.f)) * j3;
                if (do_out && il == 0) {
                    int eid = csr_eid[e];
                    float4 o4; o4.x = al0; o4.y = al1; o4.z = al2; o4.w = al3;
                    *(float4*)(out_alpha + (size_t)eid * 4) = o4;
                }
                ushort4 u = *(const ushort4*)(H0b + (size_t)(tb + src) * 64 + il * 4);
                float x0 = bfu(u.x), x1 = bfu(u.y), x2 = bfu(u.z), x3 = bfu(u.w);
                acc[0][0] += al0 * x0; acc[0][1] += al0 * x1; acc[0][2] += al0 * x2; acc[0][3] += al0 * x3;
                acc[1][0] += al1 * x0; acc[1][1] += al1 * x1; acc[1][2] += al1 * x2; acc[1][3] += al1 * x3;
                acc[2][0] += al2 * x0; acc[2][1] += al2 * x1; acc[2][2] += al2 * x2; acc[2][3] += al2 * x3;
                acc[3][0] += al3 * x0; acc[3][1] += al3 * x1; acc[3][2] += al3 * x2; acc[3][3] += al3 * x3;
            }
        }
        i0 = i1 = i2 = i3 = 1.f;
    }
    {
        float iv[4] = { i0, i1, i2, i3 };
#pragma unroll
        for (int hh = 0; hh < 4; hh++)
#pragma unroll
            for (int j = 0; j < 4; j++) acc[hh][j] *= iv[hh];
    }
#pragma unroll
    for (int o = 16; o <= 32; o <<= 1)
#pragma unroll
        for (int hh = 0; hh < 4; hh++)
#pragma unroll
            for (int j = 0; j < 4; j++)
                acc[hh][j] += __shfl_xor(acc[hh][j], o, 64);
    if (g == 0) {
        int cb = il * 4;
        size_t ob = (size_t)wid * 256 + cb;
#pragma unroll
        for (int hh = 0; hh < 4; hh++) {
            ushort4 o4;
            o4.x = f2bu(acc[hh][0]); o4.y = f2bu(acc[hh][1]);
            o4.z = f2bu(acc[hh][2]); o4.w = f2bu(acc[hh][3]);
            *(ushort4*)(AGG1b + ob + hh * 64) = o4;
        }
    }
}

/* ---------------- epilogue GEMM (MFMA): AGG @ Wbig + LN ----------------- */
__global__ __launch_bounds__(256) void k_post1(const bf16* __restrict__ AGG1b,
                                               const float* __restrict__ W1,
                                               const float* __restrict__ b1,
                                               const float* __restrict__ ln_g,
                                               const float* __restrict__ ln_b,
                                               bf16* __restrict__ HSb) {
    __shared__ __align__(16) bf16 wt[64 * 256];   /* [c][K], 32 KB */
    int tid = threadIdx.x;
    for (int i = tid; i < 16384; i += 256) {
        int c = i >> 8, K = i & 255;
        wt[i] = __float2bfloat16(W1[(K & 63) * 256 + (K >> 6) * 64 + c]);
    }
    __syncthreads();
    int wv = tid >> 6, lane = tid & 63;
    int tile = blockIdx.x * 4 + wv;
    if (tile >= NTILES) return;
    int rb = tile * 16;
    int m = lane & 15, quad = lane >> 4;
    const bf16* arow = AGG1b + (size_t)(rb + m) * 256 + quad * 8;
    short8 af[8];
#pragma unroll
    for (int kb = 0; kb < 8; kb++) af[kb] = *(const short8*)(arow + kb * 32);
    floatx4 acc[4];
#pragma unroll
    for (int ct = 0; ct < 4; ct++) {
        const bf16* wrow = wt + (ct * 16 + m) * 256 + quad * 8;
        floatx4 a = {0.f, 0.f, 0.f, 0.f};
#pragma unroll
        for (int kb = 0; kb < 8; kb++) {
            short8 bf = *(const short8*)(wrow + kb * 32);
            a = __builtin_amdgcn_mfma_f32_16x16x32_bf16(af[kb], bf, a, 0, 0, 0);
        }
        acc[ct] = a;
    }
    float b1v[4], ggv[4], bbv[4];
#pragma unroll
    for (int ct = 0; ct < 4; ct++) {
        b1v[ct] = b1[ct * 16 + m]; ggv[ct] = ln_g[ct * 16 + m]; bbv[ct] = ln_b[ct * 16 + m];
    }
#pragma unroll
    for (int r = 0; r < 4; r++) {
        float v[4];
        float s = 0.f;
#pragma unroll
        for (int ct = 0; ct < 4; ct++) {
            float t_ = acc[ct][r] * 0.25f + b1v[ct];
            t_ = t_ > 0.f ? t_ : (__expf(t_) - 1.f);
            v[ct] = t_; s += t_;
        }
#pragma unroll
        for (int o = 8; o; o >>= 1) s += __shfl_xor(s, o, 64);
        float mu = s * (1.f / 64.f);
        float q = 0.f;
#pragma unroll
        for (int ct = 0; ct < 4; ct++) { float d = v[ct] - mu; q += d * d; }
#pragma unroll
        for (int o = 8; o; o >>= 1) q += __shfl_xor(q, o, 64);
        float rinv = rsqrtf(q * (1.f / 64.f) + 1e-5f);
        int row = rb + quad * 4 + r;
#pragma unroll
        for (int ct = 0; ct < 4; ct++)
            HSb[(size_t)row * 64 + ct * 16 + m] =
                __float2bfloat16((v[ct] - mu) * rinv * ggv[ct] + bbv[ct]);
    }
}

/* ---------------- GRU: ALL steps fused in one MFMA kernel ----------------
   One wave per 16-node tile, h held in registers (C-layout) across t=0..5;
   next-step A-frag produced by a wave-private padded-LDS transpose.
   gi computed in-kernel from HSb (no GIb); r/z gates accumulate gi+gh into
   one AGPR set; g-gate halves kept separate (gh_g scaled by r). h0 = 0. */
__global__ __launch_bounds__(256) void k_gru(const bf16* __restrict__ HSb,
                                             const float* __restrict__ W_ih,
                                             const float* __restrict__ b_ih,
                                             const float* __restrict__ W_hh,
                                             const float* __restrict__ b_hh,
                                             float* __restrict__ outh) {
    __shared__ __align__(16) bf16 wi[192 * 64];        /* 24 KB, [j][k] */
    __shared__ __align__(16) bf16 wh[192 * 64];        /* 24 KB, [j][k] */
    __shared__ __align__(16) bf16 hbuf[4][16 * 72];    /* 9 KB, stride-72 pad */
    int tid = threadIdx.x;
    for (int i = tid; i < 12288; i += 256) {
        wi[i] = __float2bfloat16(W_ih[i]);
        wh[i] = __float2bfloat16(W_hh[i]);
    }
    __syncthreads();
    int wv = tid >> 6, lane = tid & 63;
    int tile = blockIdx.x * 4 + wv;
    if (tile >= N_NODES / 16) return;
    int rb = tile * 16;
    int m = lane & 15, quad = lane >> 4;
    bf16* hb = &hbuf[wv][0];
    float bi_[12], bh_[12];
#pragma unroll
    for (int ct = 0; ct < 12; ct++) { bi_[ct] = b_ih[ct * 16 + m]; bh_[ct] = b_hh[ct * 16 + m]; }
    float hprev[4][4];
#pragma unroll
    for (int ct = 0; ct < 4; ct++)
#pragma unroll
        for (int r = 0; r < 4; r++) hprev[ct][r] = 0.f;

    for (int t = 0; t < T_STEPS; t++) {
        const bf16* xr = HSb + ((size_t)t * N_NODES + rb + m) * 64;
        short8 ax0 = *(const short8*)(xr + quad * 8);
        short8 ax1 = *(const short8*)(xr + 32 + quad * 8);
        short8 ah0, ah1;
        if (t > 0) {
            ah0 = *(const short8*)(hb + m * 72 + quad * 8);
            ah1 = *(const short8*)(hb + m * 72 + 32 + quad * 8);
        }
        floatx4 rz[8];      /* gi+gh for r,z gates (ct 0..7) */
        floatx4 gg_i[4];    /* gi for g gate (ct 8..11) */
        floatx4 gg_h[4];    /* gh for g gate */
#pragma unroll
        for (int ct = 0; ct < 8; ct++) {
            int cb = ct * 16;
            short8 b0 = *(const short8*)(wi + (cb + m) * 64 + quad * 8);
            short8 b1 = *(const short8*)(wi + (cb + m) * 64 + 32 + quad * 8);
            floatx4 a = {0.f, 0.f, 0.f, 0.f};
            a = __builtin_amdgcn_mfma_f32_16x16x32_bf16(ax0, b0, a, 0, 0, 0);
            a = __builtin_amdgcn_mfma_f32_16x16x32_bf16(ax1, b1, a, 0, 0, 0);
            if (t > 0) {
                short8 c0 = *(const short8*)(wh + (cb + m) * 64 + quad * 8);
                short8 c1 = *(const short8*)(wh + (cb + m) * 64 + 32 + quad * 8);
                a = __builtin_amdgcn_mfma_f32_16x16x32_bf16(ah0, c0, a, 0, 0, 0);
                a = __builtin_amdgcn_mfma_f32_16x16x32_bf16(ah1, c1, a, 0, 0, 0);
            }
            rz[ct] = a;
        }
#pragma unroll
        for (int ct = 0; ct < 4; ct++) {
            int cb = (ct + 8) * 16;
            short8 b0 = *(const short8*)(wi + (cb + m) * 64 + quad * 8);
            short8 b1 = *(const short8*)(wi + (cb + m) * 64 + 32 + quad * 8);
            floatx4 a = {0.f, 0.f, 0.f, 0.f};
            a = __builtin_amdgcn_mfma_f32_16x16x32_bf16(ax0, b0, a, 0, 0, 0);
            a = __builtin_amdgcn_mfma_f32_16x16x32_bf16(ax1, b1, a, 0, 0, 0);
            gg_i[ct] = a;
            floatx4 c = {0.f, 0.f, 0.f, 0.f};
            if (t > 0) {
                short8 c0 = *(const short8*)(wh + (cb + m) * 64 + quad * 8);
                short8 c1 = *(const short8*)(wh + (cb + m) * 64 + 32 + quad * 8);
                c = __builtin_amdgcn_mfma_f32_16x16x32_bf16(ah0, c0, c, 0, 0, 0);
                c = __builtin_amdgcn_mfma_f32_16x16x32_bf16(ah1, c1, c, 0, 0, 0);
            }
            gg_h[ct] = c;
        }
#pragma unroll
        for (int ct = 0; ct < 4; ct++) {
#pragma unroll
            for (int r = 0; r < 4; r++) {
                float rr = 1.f / (1.f + __expf(-(rz[ct][r] + bi_[ct] + bh_[ct])));
                float z  = 1.f / (1.f + __expf(-(rz[ct + 4][r] + bi_[ct + 4] + bh_[ct + 4])));
                float g  = tanhf(gg_i[ct][r] + bi_[ct + 8] + rr * (gg_h[ct][r] + bh_[ct + 8]));
                hprev[ct][r] = (1.f - z) * g + z * hprev[ct][r];
            }
        }
        if (t < T_STEPS - 1) {
#pragma unroll
            for (int ct = 0; ct < 4; ct++)
#pragma unroll
                for (int r = 0; r < 4; r++)
                    hb[(quad * 4 + r) * 72 + ct * 16 + m] = __float2bfloat16(hprev[ct][r]);
            lds_fence();
        }
    }
#pragma unroll
    for (int ct = 0; ct < 4; ct++)
#pragma unroll
        for (int r = 0; r < 4; r++)
            outh[(size_t)(rb + quad * 4 + r) * 64 + ct * 16 + m] = hprev[ct][r];
}

/* ---------------- output writer (fp32) ---------------- */

__global__ void k_out_ei(const int* __restrict__ ei, float* __restrict__ out) {
    int i = blockIdx.x * blockDim.x + threadIdx.x;
    if (i >= 2 * EP) return;
    int v;
    if (i < EP) {
        v = (i < E_EDGES) ? ei[i] : (i - E_EDGES);                 // src row
    } else {
        int jj = i - EP;
        v = (jj < E_EDGES) ? ei[E_EDGES + jj] : (jj - E_EDGES);    // dst row
    }
    out[i] = (float)v;
}

/* ---------------- launch ---------------- */

extern "C" void kernel_launch(void* const* d_in, const int* in_sizes, int n_in,
                              void* d_out, int out_size, void* d_ws, size_t ws_size,
                              hipStream_t stream) {
    const float* x      = (const float*)d_in[0];
    const int*   ei     = (const int*)d_in[1];
    const float* W0     = (const float*)d_in[2];
    const float* a_src0 = (const float*)d_in[3];
    const float* a_dst0 = (const float*)d_in[4];
    const float* b0     = (const float*)d_in[5];
    const float* W1     = (const float*)d_in[6];
    const float* a_src1 = (const float*)d_in[7];
    const float* a_dst1 = (const float*)d_in[8];
    const float* b1     = (const float*)d_in[9];
    const float* ln_g   = (const float*)d_in[10];
    const float* ln_b   = (const float*)d_in[11];
    const float* W_ih   = (const float*)d_in[12];
    const float* W_hh   = (const float*)d_in[13];
    const float* b_ih   = (const float*)d_in[14];
    const float* b_hh   = (const float*)d_in[15];
    float* out = (float*)d_out;

    char* w = (char*)d_ws;
    size_t off = 0;
    auto take = [&](size_t bytes) -> void* {
        void* p = w + off;
        off = (off + bytes + 255) & ~(size_t)255;
        return p;
    };
    int*   counts  = (int*)take(N_NODES * 4);
    int*   fill    = (int*)take(N_NODES * 4);
    int*   rowst   = (int*)take((N_NODES + 1) * 4);
    int*   csr_src = (int*)take((size_t)EP * 4);
    int*   csr_eid = (int*)take((size_t)EP * 4);
    bf16*  XW0b    = (bf16*)take((size_t)TN * 64 * 2);
    float* ALS0    = (float*)take((size_t)TN * 4 * 4);
    float* ALD0    = (float*)take((size_t)TN * 4 * 4);
    bf16*  H0b     = (bf16*)take((size_t)TN * 64 * 2);
    float* P1s     = (float*)take(256 * 4);
    float* P1d     = (float*)take(256 * 4);
    float* ALS1    = (float*)take((size_t)TN * 4 * 4);
    float* ALD1    = (float*)take((size_t)TN * 4 * 4);
    bf16*  AGG1b   = (bf16*)take((size_t)TN * 256 * 2);
    bf16*  HSb     = (bf16*)take((size_t)TN * 64 * 2);
    (void)ws_size; (void)in_sizes; (void)n_in; (void)out_size;

    const int B = 256;
    /* CSR build + prep */
    k_init<<<(N_NODES + B - 1) / B, B, 0, stream>>>(counts, fill);
    k_count<<<(EP + B - 1) / B, B, 0, stream>>>(ei, counts);
    k_scan<<<1, 1024, 0, stream>>>(counts, rowst);
    k_scatter<<<(EP + B - 1) / B, B, 0, stream>>>(ei, rowst, fill, csr_src, csr_eid);
    k_prep1<<<1, B, 0, stream>>>(W1, a_src1, a_dst1, P1s, P1d);

    const int GT = (NTILES + 3) / 4;   /* 938 blocks for 16-row-tile MFMA kernels */
    /* GAT layer 0 */
    k_gemm0<<<GT, B, 0, stream>>>(x, W0, a_src0, a_dst0, XW0b, ALS0, ALD0);
    k_fused0<<<TN / 4, B, 0, stream>>>(rowst, csr_src, XW0b, ALS0, ALD0, b0, H0b);
    k_logits1<<<GT, B, 0, stream>>>(H0b, P1s, P1d, ALS1, ALD1);

    /* GAT layer 1 */
    k_fused1<<<TN / 4, B, 0, stream>>>(rowst, csr_src, csr_eid, H0b, ALS1, ALD1,
                                       AGG1b, out + (size_t)N_NODES * HID);
    k_post1<<<GT, B, 0, stream>>>(AGG1b, W1, b1, ln_g, ln_b, HSb);

    /* GRU: one fused kernel, all 6 steps, writes hT to out */
    k_gru<<<(N_NODES / 16 + 3) / 4, B, 0, stream>>>(HSb, W_ih, b_ih, W_hh, b_hh, out);

    /* edge-index output */
    k_out_ei<<<(2 * EP + B - 1) / B, B, 0, stream>>>(ei, out + (size_t)N_NODES * HID + (size_t)EP * HEADS);
}